// Round 1
// baseline (2173.975 us; speedup 1.0000x reference)
//
#include <hip/hip_runtime.h>

#define NT 256
#define TM 32
#define AS 132

namespace {
constexpr int TI_[28] = {0,1,1,2,2,2,3,3,3,3,4,4,4,4,4,5,5,5,5,5,5,6,6,6,6,6,6,6};
constexpr int TJ_[28] = {0,0,1,0,1,2,0,1,2,3,0,1,2,3,4,0,1,2,3,4,5,0,1,2,3,4,5,6};
constexpr bool DG_[28] = {1,0,1,0,0,1,0,0,0,1,0,0,0,0,1,0,0,0,0,0,1,0,0,0,0,0,0,1};
}

struct Smem {
  float A1[TM*AS], A2[TM*AS], A3[TM*AS], G0[TM*AS], G1[TM*AS];
  float sW[64*AS];        // weight stage: 64 rows x 128 (stride 132), or flat arrays
  float sB[128];
  float sQ[TM*8], sQd[TM*8];
  float c[TM*28], dc[TM*28], uT[28*32], Lm[TM*28];
  float w7[TM*8], gq[TM*8], rhs[TM*8], sP[TM];
};
static_assert(sizeof(Smem) <= 160*1024, "LDS overflow");

__device__ __forceinline__ float sp_f(float z) {
  return fmaxf(z, 0.f) + log1pf(__expf(-fabsf(z)));
}
// sigma(z) from a = softplus(z):  sigma = 1 - exp(-a)
__device__ __forceinline__ float sig_a(float a) { return 1.f - __expf(-a); }

__device__ __forceinline__ void stage_rows(float* dst, const float* src, int nrows, int t) {
  const int n4 = nrows * 32;
  for (int p = t; p < n4; p += NT) {
    const int r = p >> 5, cc = p & 31;
    *(float4*)&dst[r*AS + cc*4] = ((const float4*)src)[p];
  }
}
__device__ __forceinline__ void stage_flat4(float* dst, const float* src, int n4, int t) {
  for (int p = t; p < n4; p += NT) ((float4*)dst)[p] = ((const float4*)src)[p];
}
__device__ __forceinline__ void stage_flat(float* dst, const float* src, int n, int t) {
  for (int p = t; p < n; p += NT) dst[p] = src[p];
}

// out[m][j] (j in 0..127) = act( sum_k Ain[m][k] * W[k][j] (+b[j]) )
// mode 0: softplus(z + b); mode 1: sigma(SigA[m][j]) * z  (no bias)
__device__ void mm128(const float* __restrict__ Wg, const float* __restrict__ bg,
                      const float* __restrict__ Ain, float* __restrict__ Aout,
                      const float* __restrict__ SigA, int mode, Smem& S, int t)
{
  const int jg = (t >> 2) & 15, mg = (t & 3) | ((t >> 6) << 2);
  const int m0 = mg * 2, o = (mg & 1) * 4;
  const int ja = jg*8 + o, jb = jg*8 + (4 - o);
  float acc[2][2][4];
  #pragma unroll
  for (int r=0;r<2;++r)
    #pragma unroll
    for (int p=0;p<2;++p)
      #pragma unroll
      for (int d=0;d<4;++d) acc[r][p][d] = 0.f;

  #pragma unroll
  for (int half = 0; half < 2; ++half) {
    __syncthreads();
    stage_rows(S.sW, Wg + half*64*128, 64, t);
    if (half == 0 && mode == 0) stage_flat(S.sB, bg, 128, t);
    __syncthreads();
    const float* Ah = Ain + half*64;
    #pragma unroll 8
    for (int k = 0; k < 64; ++k) {
      const float a0 = Ah[(m0+0)*AS + k];
      const float a1 = Ah[(m0+1)*AS + k];
      const float4 wA = *(const float4*)&S.sW[k*AS + ja];
      const float4 wB = *(const float4*)&S.sW[k*AS + jb];
      const float wa[4] = {wA.x, wA.y, wA.z, wA.w};
      const float wb[4] = {wB.x, wB.y, wB.z, wB.w};
      #pragma unroll
      for (int d=0;d<4;++d) {
        acc[0][0][d] += a0 * wa[d];
        acc[0][1][d] += a0 * wb[d];
        acc[1][0][d] += a1 * wa[d];
        acc[1][1][d] += a1 * wb[d];
      }
    }
  }
  __syncthreads();
  #pragma unroll
  for (int r=0;r<2;++r) {
    const int m = m0 + r;
    #pragma unroll
    for (int p=0;p<2;++p) {
      const int jx = p ? jb : ja;
      #pragma unroll
      for (int d=0;d<4;++d) {
        float z = acc[r][p][d];
        if (mode == 0) { z += S.sB[jx+d]; Aout[m*AS + jx+d] = sp_f(z); }
        else           { Aout[m*AS + jx+d] = sig_a(SigA[m*AS + jx+d]) * z; }
      }
    }
  }
  __syncthreads();
}

// K=7 layer: Ain stride 8 (sQ or sQd)
__device__ void mm7(const float* __restrict__ Wg, const float* __restrict__ bg,
                    const float* __restrict__ Ain8, float* __restrict__ Aout,
                    const float* __restrict__ SigA, int mode, Smem& S, int t)
{
  __syncthreads();
  stage_rows(S.sW, Wg, 7, t);
  if (mode == 0) stage_flat(S.sB, bg, 128, t);
  __syncthreads();
  const int jg = (t >> 2) & 15, mg = (t & 3) | ((t >> 6) << 2);
  const int m0 = mg * 2, o = (mg & 1) * 4;
  const int ja = jg*8 + o, jb = jg*8 + (4 - o);
  float acc[2][2][4];
  #pragma unroll
  for (int r=0;r<2;++r)
    #pragma unroll
    for (int p=0;p<2;++p)
      #pragma unroll
      for (int d=0;d<4;++d) acc[r][p][d] = 0.f;
  #pragma unroll
  for (int k = 0; k < 7; ++k) {
    const float a0 = Ain8[(m0+0)*8 + k];
    const float a1 = Ain8[(m0+1)*8 + k];
    const float4 wA = *(const float4*)&S.sW[k*AS + ja];
    const float4 wB = *(const float4*)&S.sW[k*AS + jb];
    const float wa[4] = {wA.x, wA.y, wA.z, wA.w};
    const float wb[4] = {wB.x, wB.y, wB.z, wB.w};
    #pragma unroll
    for (int d=0;d<4;++d) {
      acc[0][0][d] += a0 * wa[d];
      acc[0][1][d] += a0 * wb[d];
      acc[1][0][d] += a1 * wa[d];
      acc[1][1][d] += a1 * wb[d];
    }
  }
  __syncthreads();
  #pragma unroll
  for (int r=0;r<2;++r) {
    const int m = m0 + r;
    #pragma unroll
    for (int p=0;p<2;++p) {
      const int jx = p ? jb : ja;
      #pragma unroll
      for (int d=0;d<4;++d) {
        float z = acc[r][p][d];
        if (mode == 0) { z += S.sB[jx+d]; Aout[m*AS + jx+d] = sp_f(z); }
        else           { Aout[m*AS + jx+d] = sig_a(SigA[m*AS + jx+d]) * z; }
      }
    }
  }
  __syncthreads();
}

// Out[m][j] (j<28) = sum_k Ain[m][k]*W3[k][j] (+b).  Assumes sW holds W3 flat, sB bias.
__device__ void mm28out(const float* __restrict__ Ain, float* __restrict__ Out,
                        bool bias, Smem& S, int t)
{
  const int j = t & 31, mr = t >> 5;
  if (j < 28) {
    #pragma unroll
    for (int mi = 0; mi < 4; ++mi) {
      const int m = mr*4 + mi;
      float acc = bias ? S.sB[j] : 0.f;
      #pragma unroll 8
      for (int k = 0; k < 128; ++k) acc += Ain[m*AS + k] * S.sW[k*28 + j];
      Out[m*28 + j] = acc;
    }
  }
  __syncthreads();
}

// OutT[j][m] = sum_k W3[j][k] * UT[k][m]   (sW holds W3m flat [128*28])
__device__ void bwd28(const float* __restrict__ UT, float* __restrict__ OutT, Smem& S, int t)
{
  const int cg = t & 7, rg = t >> 3, c0 = cg*4;
  #pragma unroll
  for (int rb = 0; rb < 2; ++rb) {
    const int r0 = rb*64 + rg*2;
    float acc[2][4] = {{0,0,0,0},{0,0,0,0}};
    #pragma unroll
    for (int k = 0; k < 28; ++k) {
      const float w0 = S.sW[(r0+0)*28 + k];
      const float w1 = S.sW[(r0+1)*28 + k];
      const float4 g = *(const float4*)&UT[k*32 + c0];
      const float ga[4] = {g.x, g.y, g.z, g.w};
      #pragma unroll
      for (int cc=0;cc<4;++cc) { acc[0][cc] += w0*ga[cc]; acc[1][cc] += w1*ga[cc]; }
    }
    *(float4*)&OutT[(r0+0)*32 + c0] = float4{acc[0][0],acc[0][1],acc[0][2],acc[0][3]};
    *(float4*)&OutT[(r0+1)*32 + c0] = float4{acc[1][0],acc[1][1],acc[1][2],acc[1][3]};
  }
  __syncthreads();
}

// OutT[i][m] = sum_j W[i][j] * GsT[j][m]
__device__ void bwd128(const float* __restrict__ Wg, const float* __restrict__ GsT,
                       float* __restrict__ OutT, Smem& S, int t)
{
  const int cg = t & 7, rg = t >> 3, c0 = cg*4;
  #pragma unroll
  for (int half = 0; half < 2; ++half) {
    __syncthreads();
    stage_rows(S.sW, Wg + half*64*128, 64, t);
    __syncthreads();
    float acc[2][4] = {{0,0,0,0},{0,0,0,0}};
    #pragma unroll 4
    for (int j4q = 0; j4q < 32; ++j4q) {
      const int j4 = j4q*4;
      const float4 w0 = *(const float4*)&S.sW[(rg*2+0)*AS + j4];
      const float4 w1 = *(const float4*)&S.sW[(rg*2+1)*AS + j4];
      const float w0a[4] = {w0.x, w0.y, w0.z, w0.w};
      const float w1a[4] = {w1.x, w1.y, w1.z, w1.w};
      #pragma unroll
      for (int d=0;d<4;++d) {
        const float4 g = *(const float4*)&GsT[(j4+d)*32 + c0];
        const float ga[4] = {g.x, g.y, g.z, g.w};
        #pragma unroll
        for (int cc=0;cc<4;++cc) { acc[0][cc] += w0a[d]*ga[cc]; acc[1][cc] += w1a[d]*ga[cc]; }
      }
    }
    const int r0 = half*64 + rg*2;
    *(float4*)&OutT[(r0+0)*32 + c0] = float4{acc[0][0],acc[0][1],acc[0][2],acc[0][3]};
    *(float4*)&OutT[(r0+1)*32 + c0] = float4{acc[1][0],acc[1][1],acc[1][2],acc[1][3]};
  }
  __syncthreads();
}

// GT[j][m] *= sigma(A[m][j])
__device__ void mulsigT(float* __restrict__ GT, const float* __restrict__ A, int t)
{
  const int m = t & 31, jb = t >> 5;
  #pragma unroll
  for (int it = 0; it < 16; ++it) {
    const int j = jb + it*8;
    GT[j*32 + m] *= sig_a(A[m*AS + j]);
  }
  __syncthreads();
}

// gq[m][i] = sum_j W0[i][j]*GT[j][m] ; mode 0: write S.gq ; mode 1: rhs -= result
__device__ void gqT(const float* __restrict__ GT, Smem& S, int t, int mode)
{
  const int m = t & 31, i = t >> 5;
  if (i < 7) {
    float acc = 0.f;
    #pragma unroll 8
    for (int j = 0; j < 128; ++j) acc += S.sW[i*AS + j] * GT[j*32 + m];
    if (mode == 0) S.gq[m*8 + i] = acc;
    else           S.rhs[m*8 + i] -= acc;
  }
  __syncthreads();
}

__global__ __launch_bounds__(NT)
void delan_kernel(const float* __restrict__ q, const float* __restrict__ qd,
    const float* mW0, const float* mb0, const float* mW1, const float* mb1,
    const float* mW2, const float* mb2, const float* mW3, const float* mb3,
    const float* pW0, const float* pb0, const float* pW1, const float* pb1,
    const float* pW2, const float* pb2, const float* pW3, const float* pb3,
    const float* fW0, const float* fb0, const float* fW1, const float* fb1,
    const float* fW2, const float* fb2, const float* fW3, const float* fb3,
    float* __restrict__ out)
{
  __shared__ Smem S;
  const int t = threadIdx.x;
  const int s0 = blockIdx.x * TM;

  for (int p = t; p < TM*7; p += NT) {
    const int m = p / 7, k = p % 7;
    S.sQ [m*8 + k] = q [(s0+m)*7 + k];
    S.sQd[m*8 + k] = qd[(s0+m)*7 + k];
  }
  __syncthreads();

  // ================= MASS MLP =================
  mm7  (mW0, mb0, S.sQ, S.A1, nullptr, 0, S, t);
  mm128(mW1, mb1, S.A1, S.A2, nullptr, 0, S, t);
  mm128(mW2, mb2, S.A2, S.A3, nullptr, 0, S, t);
  __syncthreads();
  stage_flat4(S.sW, mW3, 896, t);
  stage_flat (S.sB, mb3, 28, t);
  __syncthreads();
  mm28out(S.A3, S.c, true, S, t);

  // P1: vals (L), w = L^T qd, cotangent uT
  if (t < TM) {
    const int m = t;
    float qdr[7];
    #pragma unroll
    for (int i = 0; i < 7; ++i) qdr[i] = S.sQd[m*8 + i];
    float vals[28];
    #pragma unroll
    for (int k = 0; k < 28; ++k) {
      const float cv = S.c[m*28 + k];
      vals[k] = DG_[k] ? __expf(cv) : cv;
      S.Lm[m*28 + k] = vals[k];
    }
    float wv[7] = {0,0,0,0,0,0,0};
    #pragma unroll
    for (int k = 0; k < 28; ++k) wv[TJ_[k]] += vals[k] * qdr[TI_[k]];
    #pragma unroll
    for (int i = 0; i < 7; ++i) S.w7[m*8 + i] = wv[i];
    #pragma unroll
    for (int k = 0; k < 28; ++k)
      S.uT[k*32 + m] = (DG_[k] ? vals[k] : 1.f) * qdr[TI_[k]] * wv[TJ_[k]];
  }
  __syncthreads();

  // mass backward (sW still holds mW3)
  bwd28(S.uT, S.G0, S, t);          // G0T = W3 @ uT
  mulsigT(S.G0, S.A3, t);
  bwd128(mW2, S.G0, S.G1, S, t);
  mulsigT(S.G1, S.A2, t);
  bwd128(mW1, S.G1, S.G0, S, t);
  mulsigT(S.G0, S.A1, t);
  __syncthreads();
  stage_rows(S.sW, mW0, 7, t);
  __syncthreads();
  gqT(S.G0, S, t, 0);               // gq = dq of 0.5 qd^T M qd

  // mass JVP (tangent qd)
  mm7  (mW0, nullptr, S.sQd, S.G1, S.A1, 1, S, t);   // d1
  mm128(mW1, nullptr, S.G1,  S.G0, S.A2, 1, S, t);   // d2
  mm128(mW2, nullptr, S.G0,  S.G1, S.A3, 1, S, t);   // d3
  __syncthreads();
  stage_flat4(S.sW, mW3, 896, t);
  __syncthreads();
  mm28out(S.G1, S.dc, false, S, t);                  // dc = J_m qd

  // P2: coriolis, rhs = gq - cor
  if (t < TM) {
    const int m = t;
    float qdr[7], wv[7];
    #pragma unroll
    for (int i = 0; i < 7; ++i) { qdr[i] = S.sQd[m*8+i]; wv[i] = S.w7[m*8+i]; }
    float cor[7] = {0,0,0,0,0,0,0}, t2[7] = {0,0,0,0,0,0,0};
    #pragma unroll
    for (int k = 0; k < 28; ++k) {
      const float lv = S.Lm[m*28 + k];
      const float dv = (DG_[k] ? lv : 1.f) * S.dc[m*28 + k];
      cor[TI_[k]] += dv * wv[TJ_[k]];
      t2 [TJ_[k]] += dv * qdr[TI_[k]];
    }
    #pragma unroll
    for (int k = 0; k < 28; ++k) cor[TI_[k]] += S.Lm[m*28 + k] * t2[TJ_[k]];
    #pragma unroll
    for (int i = 0; i < 7; ++i) S.rhs[m*8 + i] = S.gq[m*8 + i] - cor[i];
  }
  __syncthreads();

  // ================= POTENTIAL MLP =================
  mm7  (pW0, pb0, S.sQ, S.A1, nullptr, 0, S, t);
  mm128(pW1, pb1, S.A1, S.A2, nullptr, 0, S, t);
  mm128(pW2, pb2, S.A2, S.A3, nullptr, 0, S, t);
  __syncthreads();
  stage_flat(S.sW, pW3, 128, t);
  if (t == 0) S.sB[0] = pb3[0];
  __syncthreads();
  if (t < TM) {  // p_out and u_p = sigmoid(p_out)
    float acc = S.sB[0];
    #pragma unroll 8
    for (int k = 0; k < 128; ++k) acc += S.A3[t*AS + k] * S.sW[k];
    S.sP[t] = 1.f / (1.f + __expf(-acc));
  }
  __syncthreads();
  { // seed: G0T[j][m] = W3p[j] * u_p[m] * sigma(A3[m][j])
    const int m = t & 31, jb = t >> 5;
    #pragma unroll
    for (int it = 0; it < 16; ++it) {
      const int j = jb + it*8;
      S.G0[j*32 + m] = S.sW[j] * S.sP[m] * sig_a(S.A3[m*AS + j]);
    }
  }
  __syncthreads();
  bwd128(pW2, S.G0, S.G1, S, t);
  mulsigT(S.G1, S.A2, t);
  bwd128(pW1, S.G1, S.G0, S, t);
  mulsigT(S.G0, S.A1, t);
  __syncthreads();
  stage_rows(S.sW, pW0, 7, t);
  __syncthreads();
  gqT(S.G0, S, t, 1);               // rhs -= gradV

  // ================= FRICTION MLP =================
  mm7  (fW0, fb0, S.sQ, S.A1, nullptr, 0, S, t);
  mm128(fW1, fb1, S.A1, S.A2, nullptr, 0, S, t);
  mm128(fW2, fb2, S.A2, S.A3, nullptr, 0, S, t);
  __syncthreads();
  stage_flat4(S.sW, fW3, 896, t);
  stage_flat (S.sB, fb3, 28, t);
  __syncthreads();
  mm28out(S.A3, S.dc, true, S, t);  // cf reuses dc buffer

  // P3: friction, assemble rhs, build M, Cholesky solve, write out
  if (t < TM) {
    const int m = t;
    float qdr[7];
    #pragma unroll
    for (int i = 0; i < 7; ++i) qdr[i] = S.sQd[m*8 + i];
    float fv[28];
    #pragma unroll
    for (int k = 0; k < 28; ++k) {
      const float cv = S.dc[m*28 + k];
      fv[k] = DG_[k] ? __expf(cv) : cv;
    }
    float wf[7] = {0,0,0,0,0,0,0};
    #pragma unroll
    for (int k = 0; k < 28; ++k) wf[TJ_[k]] += fv[k] * qdr[TI_[k]];
    float fric[7];
    #pragma unroll
    for (int i = 0; i < 7; ++i) fric[i] = 1e-3f * qdr[i];
    #pragma unroll
    for (int k = 0; k < 28; ++k) fric[TI_[k]] += fv[k] * wf[TJ_[k]];
    float r7[7];
    #pragma unroll
    for (int i = 0; i < 7; ++i) r7[i] = S.rhs[m*8 + i] - fric[i];

    float L[7][7];
    #pragma unroll
    for (int i = 0; i < 7; ++i)
      #pragma unroll
      for (int j = 0; j < 7; ++j) L[i][j] = 0.f;
    #pragma unroll
    for (int k = 0; k < 28; ++k) L[TI_[k]][TJ_[k]] = S.Lm[m*28 + k];

    // M = L L^T + (EPS_M + EPS_SOLVE) I  (lower part only)
    float M[7][7];
    #pragma unroll
    for (int i = 0; i < 7; ++i) {
      #pragma unroll
      for (int j = 0; j < 7; ++j) {
        if (j <= i) {
          float s = (i == j) ? 1.1e-3f : 0.f;
          #pragma unroll
          for (int k = 0; k < 7; ++k) if (k <= j) s += L[i][k] * L[j][k];
          M[i][j] = s;
        }
      }
    }
    // Cholesky
    float C[7][7];
    #pragma unroll
    for (int i = 0; i < 7; ++i) {
      #pragma unroll
      for (int j = 0; j < 7; ++j) {
        if (j <= i) {
          float s = M[i][j];
          #pragma unroll
          for (int k = 0; k < 7; ++k) if (k < j) s -= C[i][k] * C[j][k];
          if (j == i) C[i][j] = sqrtf(fmaxf(s, 1e-12f));
          else        C[i][j] = s / C[j][j];
        }
      }
    }
    float y[7];
    #pragma unroll
    for (int i = 0; i < 7; ++i) {
      float s = r7[i];
      #pragma unroll
      for (int k = 0; k < 7; ++k) if (k < i) s -= C[i][k] * y[k];
      y[i] = s / C[i][i];
    }
    float x[7];
    #pragma unroll
    for (int i = 6; i >= 0; --i) {
      float s = y[i];
      #pragma unroll
      for (int k = 0; k < 7; ++k) if (k > i) s -= C[k][i] * x[k];
      x[i] = s / C[i][i];
    }
    #pragma unroll
    for (int i = 0; i < 7; ++i) out[(s0 + m)*7 + i] = x[i];
  }
}

extern "C" void kernel_launch(void* const* d_in, const int* in_sizes, int n_in,
                              void* d_out, int out_size, void* d_ws, size_t ws_size,
                              hipStream_t stream) {
  (void)in_sizes; (void)n_in; (void)out_size; (void)d_ws; (void)ws_size;
  const float* q   = (const float*)d_in[0];
  const float* qd  = (const float*)d_in[1];
  const float* mW0 = (const float*)d_in[2];  const float* mb0 = (const float*)d_in[3];
  const float* mW1 = (const float*)d_in[4];  const float* mb1 = (const float*)d_in[5];
  const float* mW2 = (const float*)d_in[6];  const float* mb2 = (const float*)d_in[7];
  const float* mW3 = (const float*)d_in[8];  const float* mb3 = (const float*)d_in[9];
  const float* pW0 = (const float*)d_in[10]; const float* pb0 = (const float*)d_in[11];
  const float* pW1 = (const float*)d_in[12]; const float* pb1 = (const float*)d_in[13];
  const float* pW2 = (const float*)d_in[14]; const float* pb2 = (const float*)d_in[15];
  const float* pW3 = (const float*)d_in[16]; const float* pb3 = (const float*)d_in[17];
  const float* fW0 = (const float*)d_in[18]; const float* fb0 = (const float*)d_in[19];
  const float* fW1 = (const float*)d_in[20]; const float* fb1 = (const float*)d_in[21];
  const float* fW2 = (const float*)d_in[22]; const float* fb2 = (const float*)d_in[23];
  const float* fW3 = (const float*)d_in[24]; const float* fb3 = (const float*)d_in[25];
  float* out = (float*)d_out;

  delan_kernel<<<dim3(65536 / TM), dim3(NT), 0, stream>>>(
      q, qd,
      mW0, mb0, mW1, mb1, mW2, mb2, mW3, mb3,
      pW0, pb0, pW1, pb1, pW2, pb2, pW3, pb3,
      fW0, fb0, fW1, fb1, fW2, fb2, fW3, fb3,
      out);
}

// Round 2
// 814.152 us; speedup vs baseline: 2.6702x; 2.6702x over previous
//
#include <hip/hip_runtime.h>

#define NT 512          // 8 waves
#define TM 64           // samples per block = lanes per wave
#define NBLK (65536/TM) // 1024

namespace {
constexpr int TI_[28] = {0,1,1,2,2,2,3,3,3,3,4,4,4,4,4,5,5,5,5,5,5,6,6,6,6,6,6,6};
constexpr int TJ_[28] = {0,0,1,0,1,2,0,1,2,3,0,1,2,3,4,0,1,2,3,4,5,0,1,2,3,4,5,6};
constexpr bool DG_[28] = {1,0,1,0,0,1,0,0,0,1,0,0,0,0,1,0,0,0,0,0,1,0,0,0,0,0,0,1};

// LDS float offsets
constexpr int A2_OFF  = 0;          // [64][128] pair layout: [k2][2m+p]
constexpr int A3_OFF  = 8192;
constexpr int X_OFF   = 16384;
constexpr int Y_OFF   = 24576;
constexpr int CT_OFF  = 32768;      // [28][64]  (cT, later cfT)
constexpr int DCT_OFF = 34560;      // [28][64]
constexpr int R14_OFF = 36352;      // 3584 floats: uT[28][64] / pp[8][7][64] / pph[8][64]
constexpr int LDS_FLOATS = 39936;   // 159744 B

// ws float offsets (packed transposes, built by pack_kernel)
constexpr int WS_MW1T = 0;          // [128][128]
constexpr int WS_MW2T = 16384;      // [128][128]
constexpr int WS_MW3T = 32768;      // [28][128]
constexpr int WS_MW0T = 36352;      // [128][8] (col 7 zero)
constexpr int WS_PW1T = 37376;      // [128][128]
constexpr int WS_PW2T = 53760;      // [128][128]
constexpr int WS_PW0T = 70144;      // [128][8]
constexpr int WS_FLOATS = 71168;    // 284672 B needed in d_ws
}

__device__ __forceinline__ float sp_f(float z) {
  return fmaxf(z, 0.f) + log1pf(__expf(-fabsf(z)));
}
__device__ __forceinline__ float sig_a(float a) { return 1.f - __expf(-a); } // sigma from softplus value
__device__ __forceinline__ float sigm(float z)  { return 1.f / (1.f + __expf(-z)); }

// ---- inner loop: acc[16] += sum_k IN[k][m] * W[k][jc..jc+15], K=128, IN in LDS pairs ----
__device__ __forceinline__ void mmloop128(const float* IN, const float* __restrict__ W,
                                          int ldw, int jc, int m, float acc[16]) {
  #pragma unroll
  for (int jj = 0; jj < 16; ++jj) acc[jj] = 0.f;
  #pragma unroll 2
  for (int k2 = 0; k2 < 64; ++k2) {
    const float2 a = *(const float2*)&IN[k2*128 + 2*m];
    const float* w0 = W + (2*k2)*ldw + jc;
    const float* w1 = w0 + ldw;
    #pragma unroll
    for (int jj = 0; jj < 16; ++jj)
      acc[jj] = fmaf(a.x, w0[jj], fmaf(a.y, w1[jj], acc[jj]));
  }
}

// ---- epilogues ----
__device__ __forceinline__ void epi_sp(const float acc[16], const float* __restrict__ B,
                                       int jc, float* OUT, int m) {
  #pragma unroll
  for (int jj2 = 0; jj2 < 8; ++jj2) {
    const float z0 = acc[2*jj2]   + B[jc + 2*jj2];
    const float z1 = acc[2*jj2+1] + B[jc + 2*jj2+1];
    *(float2*)&OUT[(jc/2 + jj2)*128 + 2*m] = float2{sp_f(z0), sp_f(z1)};
  }
}
__device__ __forceinline__ void epi_sig(const float acc[16], const float* SIG,
                                        int jc, float* OUT, int m) {
  #pragma unroll
  for (int jj2 = 0; jj2 < 8; ++jj2) {
    const float2 s = *(const float2*)&SIG[(jc/2 + jj2)*128 + 2*m];
    *(float2*)&OUT[(jc/2 + jj2)*128 + 2*m] =
        float2{sig_a(s.x)*acc[2*jj2], sig_a(s.y)*acc[2*jj2+1]};
  }
}
__device__ __forceinline__ void epi_sigz1(const float acc[16], const float q[7],
                                          const float* __restrict__ W0, const float* __restrict__ b0,
                                          int jc, float* OUT, int m) {
  float z[16];
  #pragma unroll
  for (int jj = 0; jj < 16; ++jj) z[jj] = b0[jc + jj];
  #pragma unroll
  for (int k = 0; k < 7; ++k) {
    const float* wr = W0 + k*128 + jc;
    #pragma unroll
    for (int jj = 0; jj < 16; ++jj) z[jj] = fmaf(q[k], wr[jj], z[jj]);
  }
  #pragma unroll
  for (int jj2 = 0; jj2 < 8; ++jj2) {
    *(float2*)&OUT[(jc/2 + jj2)*128 + 2*m] =
        float2{sigm(z[2*jj2])*acc[2*jj2], sigm(z[2*jj2+1])*acc[2*jj2+1]};
  }
}

// ---- layer wrappers ----
__device__ __forceinline__ void layer_fwd(const float* IN, float* OUT,
    const float* __restrict__ W, const float* __restrict__ B, int jc, int m) {
  float acc[16]; mmloop128(IN, W, 128, jc, m, acc); epi_sp(acc, B, jc, OUT, m);
}
__device__ __forceinline__ void layer_sig(const float* IN, float* OUT,
    const float* __restrict__ W, const float* SIG, int jc, int m) {
  float acc[16]; mmloop128(IN, W, 128, jc, m, acc); epi_sig(acc, SIG, jc, OUT, m);
}
__device__ __forceinline__ void layer_sigz1(const float* IN, float* OUT,
    const float* __restrict__ W, const float q[7],
    const float* __restrict__ W0, const float* __restrict__ b0, int jc, int m) {
  float acc[16]; mmloop128(IN, W, 128, jc, m, acc); epi_sigz1(acc, q, W0, b0, jc, OUT, m);
}

// ---- first layer (K=7) from per-lane q regs ----
__device__ __forceinline__ void l0_fwd(const float q[7], const float* __restrict__ W0,
                                       const float* __restrict__ b0, int jc, int m, float* OUT) {
  float z[16];
  #pragma unroll
  for (int jj = 0; jj < 16; ++jj) z[jj] = b0[jc + jj];
  #pragma unroll
  for (int k = 0; k < 7; ++k) {
    const float* wr = W0 + k*128 + jc;
    #pragma unroll
    for (int jj = 0; jj < 16; ++jj) z[jj] = fmaf(q[k], wr[jj], z[jj]);
  }
  #pragma unroll
  for (int jj2 = 0; jj2 < 8; ++jj2)
    *(float2*)&OUT[(jc/2 + jj2)*128 + 2*m] = float2{sp_f(z[2*jj2]), sp_f(z[2*jj2+1])};
}
__device__ __forceinline__ void l0_jvp(const float q[7], const float qd[7],
                                       const float* __restrict__ W0, const float* __restrict__ b0,
                                       int jc, int m, float* OUT) {
  float z[16], zd[16];
  #pragma unroll
  for (int jj = 0; jj < 16; ++jj) { z[jj] = b0[jc + jj]; zd[jj] = 0.f; }
  #pragma unroll
  for (int k = 0; k < 7; ++k) {
    const float* wr = W0 + k*128 + jc;
    #pragma unroll
    for (int jj = 0; jj < 16; ++jj) {
      z[jj]  = fmaf(q[k],  wr[jj], z[jj]);
      zd[jj] = fmaf(qd[k], wr[jj], zd[jj]);
    }
  }
  #pragma unroll
  for (int jj2 = 0; jj2 < 8; ++jj2)
    *(float2*)&OUT[(jc/2 + jj2)*128 + 2*m] =
        float2{sigm(z[2*jj2])*zd[2*jj2], sigm(z[2*jj2+1])*zd[2*jj2+1]};
}

// ---- K=128 -> 28 output pass (waves 0..6, 4 cols each), writes OUTT[28][64] ----
__device__ __forceinline__ void l3_pass(const float* IN, const float* __restrict__ W3,
                                        const float* __restrict__ b3, float* OUTT,
                                        int w, int m, bool bias) {
  if (w < 7) {
    float acc[4] = {0.f, 0.f, 0.f, 0.f};
    const int c0 = w*4;
    #pragma unroll 4
    for (int k2 = 0; k2 < 64; ++k2) {
      const float2 a = *(const float2*)&IN[k2*128 + 2*m];
      const float* r0 = W3 + (2*k2)*28 + c0;
      const float* r1 = r0 + 28;
      #pragma unroll
      for (int d = 0; d < 4; ++d) acc[d] = fmaf(a.x, r0[d], fmaf(a.y, r1[d], acc[d]));
    }
    #pragma unroll
    for (int d = 0; d < 4; ++d) OUTT[(c0+d)*64 + m] = acc[d] + (bias ? b3[c0+d] : 0.f);
  }
}

// ---- 28 -> 128 backward seed: OUT = sig_a(A3) ⊙ (W3t · uT) ----
__device__ __forceinline__ void bwd28_pass(const float* UT, const float* __restrict__ W3t,
                                           const float* A3, int jc, int m, float* OUT) {
  float acc[16];
  #pragma unroll
  for (int jj = 0; jj < 16; ++jj) acc[jj] = 0.f;
  #pragma unroll 4
  for (int u = 0; u < 28; ++u) {
    const float uv = UT[u*64 + m];
    const float* wr = W3t + u*128 + jc;
    #pragma unroll
    for (int jj = 0; jj < 16; ++jj) acc[jj] = fmaf(uv, wr[jj], acc[jj]);
  }
  epi_sig(acc, A3, jc, OUT, m);
}

// ---- gq partial: pp[w][i][m] = sum_{j in chunk} G[j][m] * W0t[j][i] ----
__device__ __forceinline__ void gq_partial(const float* G, const float* __restrict__ W0t,
                                           int w, int m, float* pp) {
  float acc[7] = {0.f,0.f,0.f,0.f,0.f,0.f,0.f};
  const int j20 = w*8;
  #pragma unroll
  for (int j2 = 0; j2 < 8; ++j2) {
    const float2 g = *(const float2*)&G[(j20 + j2)*128 + 2*m];
    const float* r0 = W0t + (2*(j20 + j2))*8;
    const float* r1 = r0 + 8;
    #pragma unroll
    for (int i = 0; i < 7; ++i) acc[i] = fmaf(g.x, r0[i], fmaf(g.y, r1[i], acc[i]));
  }
  #pragma unroll
  for (int i = 0; i < 7; ++i) pp[(w*7 + i)*64 + m] = acc[i];
}

// ---- potential head ----
__device__ __forceinline__ void head_partial(const float* A3p, const float* __restrict__ W3p,
                                             int w, int m, float* pph) {
  float acc = 0.f;
  const int k20 = w*8;
  #pragma unroll
  for (int k2 = 0; k2 < 8; ++k2) {
    const float2 a = *(const float2*)&A3p[(k20 + k2)*128 + 2*m];
    acc = fmaf(a.x, W3p[2*(k20+k2)], fmaf(a.y, W3p[2*(k20+k2)+1], acc));
  }
  pph[w*64 + m] = acc;
}
__device__ __forceinline__ void pot_seed(const float* A3p, const float* __restrict__ W3p,
                                         const float* __restrict__ pb3, const float* pph,
                                         int jc, int m, float* OUT) {
  float s = pb3[0];
  #pragma unroll
  for (int ww = 0; ww < 8; ++ww) s += pph[ww*64 + m];
  const float up = sigm(s);
  #pragma unroll
  for (int jj2 = 0; jj2 < 8; ++jj2) {
    const float2 a = *(const float2*)&A3p[(jc/2 + jj2)*128 + 2*m];
    const float w0 = W3p[jc + 2*jj2], w1 = W3p[jc + 2*jj2 + 1];
    *(float2*)&OUT[(jc/2 + jj2)*128 + 2*m] = float2{sig_a(a.x)*w0*up, sig_a(a.y)*w1*up};
  }
}

// ================= pack kernel: build W^T tables in ws =================
__global__ void pack_kernel(const float* __restrict__ mW0, const float* __restrict__ mW1,
                            const float* __restrict__ mW2, const float* __restrict__ mW3,
                            const float* __restrict__ pW0, const float* __restrict__ pW1,
                            const float* __restrict__ pW2, float* __restrict__ ws) {
  int idx = blockIdx.x * 256 + threadIdx.x;
  if (idx >= WS_FLOATS) return;
  if (idx < 16384) { int j = idx >> 7, i = idx & 127; ws[WS_MW1T + idx] = mW1[i*128 + j]; return; }
  idx -= 16384;
  if (idx < 16384) { int j = idx >> 7, i = idx & 127; ws[WS_MW2T + idx] = mW2[i*128 + j]; return; }
  idx -= 16384;
  if (idx < 3584)  { int u = idx >> 7, j = idx & 127; ws[WS_MW3T + idx] = mW3[j*28 + u]; return; }
  idx -= 3584;
  if (idx < 1024)  { int j = idx >> 3, i = idx & 7;  ws[WS_MW0T + idx] = (i < 7) ? mW0[i*128 + j] : 0.f; return; }
  idx -= 1024;
  if (idx < 16384) { int j = idx >> 7, i = idx & 127; ws[WS_PW1T + idx] = pW1[i*128 + j]; return; }
  idx -= 16384;
  if (idx < 16384) { int j = idx >> 7, i = idx & 127; ws[WS_PW2T + idx] = pW2[i*128 + j]; return; }
  idx -= 16384;
  { int j = idx >> 3, i = idx & 7;  ws[WS_PW0T + idx] = (i < 7) ? pW0[i*128 + j] : 0.f; }
}

// ================= main kernel =================
__global__ __launch_bounds__(NT)
void delan_kernel(const float* __restrict__ qg, const float* __restrict__ qdg,
    const float* __restrict__ mW0, const float* __restrict__ mb0,
    const float* __restrict__ mW1, const float* __restrict__ mb1,
    const float* __restrict__ mW2, const float* __restrict__ mb2,
    const float* __restrict__ mW3, const float* __restrict__ mb3,
    const float* __restrict__ pW0, const float* __restrict__ pb0,
    const float* __restrict__ pW1, const float* __restrict__ pb1,
    const float* __restrict__ pW2, const float* __restrict__ pb2,
    const float* __restrict__ pW3, const float* __restrict__ pb3,
    const float* __restrict__ fW0, const float* __restrict__ fb0,
    const float* __restrict__ fW1, const float* __restrict__ fb1,
    const float* __restrict__ fW2, const float* __restrict__ fb2,
    const float* __restrict__ fW3, const float* __restrict__ fb3,
    const float* __restrict__ ws, float* __restrict__ out)
{
  __shared__ float S[LDS_FLOATS];
  const int tid = threadIdx.x;
  const int m = tid & 63;                                        // lane = sample
  const int w = __builtin_amdgcn_readfirstlane(tid >> 6);        // wave id 0..7
  const int jc = w * 16;
  const int s = blockIdx.x * TM + m;

  float q[7], qd[7];
  #pragma unroll
  for (int i = 0; i < 7; ++i) { q[i] = qg[s*7 + i]; qd[i] = qdg[s*7 + i]; }

  // persistent per-sample state (written by wave 0 only)
  float valsv[28], wv[7], rhsv[7];

  float* A2 = &S[A2_OFF];  float* A3 = &S[A3_OFF];
  float* X  = &S[X_OFF];   float* Y  = &S[Y_OFF];
  float* cT = &S[CT_OFF];  float* dcT = &S[DCT_OFF];
  float* R14 = &S[R14_OFF];

  // ================= MASS =================
  l0_fwd(q, mW0, mb0, jc, m, X);                 __syncthreads();   // A1 -> X
  layer_fwd(X,  A2, mW1, mb1, jc, m);            __syncthreads();   // A2
  layer_fwd(A2, A3, mW2, mb2, jc, m);            __syncthreads();   // A3
  l3_pass(A3, mW3, mb3, cT, w, m, true);         __syncthreads();   // c -> cT

  if (w == 0) {  // P1: L entries, w = L^T qd, cotangent uT
    float cv[28];
    #pragma unroll
    for (int u = 0; u < 28; ++u) cv[u] = cT[u*64 + m];
    #pragma unroll
    for (int u = 0; u < 28; ++u) valsv[u] = DG_[u] ? __expf(cv[u]) : cv[u];
    #pragma unroll
    for (int i = 0; i < 7; ++i) wv[i] = 0.f;
    #pragma unroll
    for (int u = 0; u < 28; ++u) wv[TJ_[u]] = fmaf(valsv[u], qd[TI_[u]], wv[TJ_[u]]);
    #pragma unroll
    for (int u = 0; u < 28; ++u)
      R14[u*64 + m] = (DG_[u] ? valsv[u] : 1.f) * qd[TI_[u]] * wv[TJ_[u]];
  }
  __syncthreads();

  bwd28_pass(R14, ws + WS_MW3T, A3, jc, m, Y);   __syncthreads();   // G3 -> Y
  layer_sig(Y, X, ws + WS_MW2T, A2, jc, m);      __syncthreads();   // G2 -> X
  layer_sigz1(X, Y, ws + WS_MW1T, q, mW0, mb0, jc, m); __syncthreads(); // G1 -> Y
  gq_partial(Y, ws + WS_MW0T, w, m, R14);        __syncthreads();   // pp (mass)

  // JVP (tangent qd)
  l0_jvp(q, qd, mW0, mb0, jc, m, X);             __syncthreads();   // d1 -> X
  layer_sig(X, Y, mW1, A2, jc, m);               __syncthreads();   // d2 -> Y
  layer_sig(Y, X, mW2, A3, jc, m);               __syncthreads();   // d3 -> X
  l3_pass(X, mW3, nullptr, dcT, w, m, false);    __syncthreads();   // dc -> dcT

  if (w == 0) {  // P2: gq reduce, coriolis, rhs = gq - cor
    float gq[7];
    #pragma unroll
    for (int i = 0; i < 7; ++i) {
      float sum = 0.f;
      #pragma unroll
      for (int ww = 0; ww < 8; ++ww) sum += R14[(ww*7 + i)*64 + m];
      gq[i] = sum;
    }
    float dc[28];
    #pragma unroll
    for (int u = 0; u < 28; ++u) dc[u] = dcT[u*64 + m];
    float cor[7] = {0,0,0,0,0,0,0}, t2[7] = {0,0,0,0,0,0,0};
    #pragma unroll
    for (int u = 0; u < 28; ++u) {
      const float lv = valsv[u];
      const float dv = (DG_[u] ? lv : 1.f) * dc[u];
      cor[TI_[u]] = fmaf(dv, wv[TJ_[u]], cor[TI_[u]]);
      t2[TJ_[u]]  = fmaf(dv, qd[TI_[u]], t2[TJ_[u]]);
    }
    #pragma unroll
    for (int u = 0; u < 28; ++u) cor[TI_[u]] = fmaf(valsv[u], t2[TJ_[u]], cor[TI_[u]]);
    #pragma unroll
    for (int i = 0; i < 7; ++i) rhsv[i] = gq[i] - cor[i];
  }
  __syncthreads();

  // ================= POTENTIAL =================
  l0_fwd(q, pW0, pb0, jc, m, Y);                 __syncthreads();   // pA1 -> Y
  layer_fwd(Y, X, pW1, pb1, jc, m);              __syncthreads();   // pA2 -> X
  layer_fwd(X, A2, pW2, pb2, jc, m);             __syncthreads();   // pA3 -> A2
  head_partial(A2, pW3, w, m, R14);              __syncthreads();   // pph
  pot_seed(A2, pW3, pb3, R14, jc, m, A3);        __syncthreads();   // G3p -> A3
  layer_sig(A3, Y, ws + WS_PW2T, X, jc, m);      __syncthreads();   // G2p -> Y
  layer_sigz1(Y, X, ws + WS_PW1T, q, pW0, pb0, jc, m); __syncthreads(); // G1p -> X
  gq_partial(X, ws + WS_PW0T, w, m, R14);        __syncthreads();   // pp (pot)

  if (w == 0) {  // rhs -= gradV
    #pragma unroll
    for (int i = 0; i < 7; ++i) {
      float sum = 0.f;
      #pragma unroll
      for (int ww = 0; ww < 8; ++ww) sum += R14[(ww*7 + i)*64 + m];
      rhsv[i] -= sum;
    }
  }
  __syncthreads();

  // ================= FRICTION =================
  l0_fwd(q, fW0, fb0, jc, m, Y);                 __syncthreads();   // fA1 -> Y
  layer_fwd(Y, X, fW1, fb1, jc, m);              __syncthreads();   // fA2 -> X
  layer_fwd(X, Y, fW2, fb2, jc, m);              __syncthreads();   // fA3 -> Y
  l3_pass(Y, fW3, fb3, cT, w, m, true);          __syncthreads();   // cf -> cT

  if (w == 0) {  // P3: friction, Cholesky solve, output
    float fv[28];
    #pragma unroll
    for (int u = 0; u < 28; ++u) {
      const float cv = cT[u*64 + m];
      fv[u] = DG_[u] ? __expf(cv) : cv;
    }
    float wf[7] = {0,0,0,0,0,0,0};
    #pragma unroll
    for (int u = 0; u < 28; ++u) wf[TJ_[u]] = fmaf(fv[u], qd[TI_[u]], wf[TJ_[u]]);
    float fric[7];
    #pragma unroll
    for (int i = 0; i < 7; ++i) fric[i] = 1e-3f * qd[i];
    #pragma unroll
    for (int u = 0; u < 28; ++u) fric[TI_[u]] = fmaf(fv[u], wf[TJ_[u]], fric[TI_[u]]);
    float r7[7];
    #pragma unroll
    for (int i = 0; i < 7; ++i) r7[i] = rhsv[i] - fric[i];

    float L[7][7];
    #pragma unroll
    for (int i = 0; i < 7; ++i)
      #pragma unroll
      for (int j = 0; j < 7; ++j) L[i][j] = 0.f;
    #pragma unroll
    for (int u = 0; u < 28; ++u) L[TI_[u]][TJ_[u]] = valsv[u];

    float M[7][7];
    #pragma unroll
    for (int i = 0; i < 7; ++i)
      #pragma unroll
      for (int j = 0; j < 7; ++j)
        if (j <= i) {
          float sum = (i == j) ? 1.1e-3f : 0.f;
          #pragma unroll
          for (int k = 0; k < 7; ++k) if (k <= j) sum = fmaf(L[i][k], L[j][k], sum);
          M[i][j] = sum;
        }
    float C[7][7];
    #pragma unroll
    for (int i = 0; i < 7; ++i)
      #pragma unroll
      for (int j = 0; j < 7; ++j)
        if (j <= i) {
          float sum = M[i][j];
          #pragma unroll
          for (int k = 0; k < 7; ++k) if (k < j) sum -= C[i][k] * C[j][k];
          if (j == i) C[i][j] = sqrtf(fmaxf(sum, 1e-12f));
          else        C[i][j] = sum / C[j][j];
        }
    float y[7];
    #pragma unroll
    for (int i = 0; i < 7; ++i) {
      float sum = r7[i];
      #pragma unroll
      for (int k = 0; k < 7; ++k) if (k < i) sum -= C[i][k] * y[k];
      y[i] = sum / C[i][i];
    }
    float x[7];
    #pragma unroll
    for (int i = 6; i >= 0; --i) {
      float sum = y[i];
      #pragma unroll
      for (int k = 0; k < 7; ++k) if (k > i) sum -= C[k][i] * x[k];
      x[i] = sum / C[i][i];
    }
    #pragma unroll
    for (int i = 0; i < 7; ++i) out[s*7 + i] = x[i];
  }
}

extern "C" void kernel_launch(void* const* d_in, const int* in_sizes, int n_in,
                              void* d_out, int out_size, void* d_ws, size_t ws_size,
                              hipStream_t stream) {
  (void)in_sizes; (void)n_in; (void)out_size; (void)ws_size;
  const float* q   = (const float*)d_in[0];
  const float* qd  = (const float*)d_in[1];
  const float* mW0 = (const float*)d_in[2];  const float* mb0 = (const float*)d_in[3];
  const float* mW1 = (const float*)d_in[4];  const float* mb1 = (const float*)d_in[5];
  const float* mW2 = (const float*)d_in[6];  const float* mb2 = (const float*)d_in[7];
  const float* mW3 = (const float*)d_in[8];  const float* mb3 = (const float*)d_in[9];
  const float* pW0 = (const float*)d_in[10]; const float* pb0 = (const float*)d_in[11];
  const float* pW1 = (const float*)d_in[12]; const float* pb1 = (const float*)d_in[13];
  const float* pW2 = (const float*)d_in[14]; const float* pb2 = (const float*)d_in[15];
  const float* pW3 = (const float*)d_in[16]; const float* pb3 = (const float*)d_in[17];
  const float* fW0 = (const float*)d_in[18]; const float* fb0 = (const float*)d_in[19];
  const float* fW1 = (const float*)d_in[20]; const float* fb1 = (const float*)d_in[21];
  const float* fW2 = (const float*)d_in[22]; const float* fb2 = (const float*)d_in[23];
  const float* fW3 = (const float*)d_in[24]; const float* fb3 = (const float*)d_in[25];
  float* out = (float*)d_out;
  float* ws  = (float*)d_ws;

  pack_kernel<<<dim3((WS_FLOATS + 255)/256), dim3(256), 0, stream>>>(
      mW0, mW1, mW2, mW3, pW0, pW1, pW2, ws);

  delan_kernel<<<dim3(NBLK), dim3(NT), 0, stream>>>(
      q, qd,
      mW0, mb0, mW1, mb1, mW2, mb2, mW3, mb3,
      pW0, pb0, pW1, pb1, pW2, pb2, pW3, pb3,
      fW0, fb0, fW1, fb1, fW2, fb2, fW3, fb3,
      ws, out);
}

// Round 3
// 393.973 us; speedup vs baseline: 5.5181x; 2.0665x over previous
//
#include <hip/hip_runtime.h>

#define NT 512
#define NBLK 1024

typedef unsigned int u32;
typedef __attribute__((ext_vector_type(4))) float f32x4;
typedef __attribute__((ext_vector_type(4))) u32 u32x4;
typedef __attribute__((ext_vector_type(8))) _Float16 f16x8;

namespace {
constexpr int TI_[28] = {0,1,1,2,2,2,3,3,3,3,4,4,4,4,4,5,5,5,5,5,5,6,6,6,6,6,6,6};
constexpr int TJ_[28] = {0,0,1,0,1,2,0,1,2,3,0,1,2,3,4,0,1,2,3,4,5,0,1,2,3,4,5,6};
constexpr bool DG_[28] = {1,0,1,0,0,1,0,0,0,1,0,0,0,0,1,0,0,0,0,0,1,0,0,0,0,0,0,1};

// weight images in ws: element counts (cumulative). Each element = 2B hi + 2B lo.
constexpr int ECUM[20] = {0,4096,20480,36864,40960,45056,61440,77824,79872,83968,
                          100352,116736,118784,135168,151552,153600,157696,174080,190464,194560};
constexpr int TOTE = 194560;
constexpr int BO(int i)  { return ECUM[i]*4; }                    // byte offset of image
constexpr int HB(int i)  { return (ECUM[i+1]-ECUM[i])*2; }        // bytes of hi half
constexpr int KBc(int i) { return (ECUM[i+1]-ECUM[i])/256; }      // 1KB chunks
}

__device__ __forceinline__ float sp_f(float z) {
  return fmaxf(z, 0.f) + log1pf(__expf(-fabsf(z)));
}
__device__ __forceinline__ float sig_a(float a) { return 1.f - __expf(-a); } // sigmoid(z) from softplus(z)
__device__ __forceinline__ float sigm(float z)  { return 1.f / (1.f + __expf(-z)); }

// f32 -> packed u32: low16 = f16(x), high16 = f16((x - hi)*4096)
__device__ __forceinline__ u32 pack_hl(float x) {
  _Float16 h = (_Float16)x;
  _Float16 lo = (_Float16)((x - (float)h) * 4096.f);
  union { _Float16 f[2]; u32 u; } r;
  r.f[0] = h; r.f[1] = lo;
  return r.u;
}

__device__ __forceinline__ void unpack8(const u32x4 a, const u32x4 b, f16x8& h, f16x8& l) {
  union U { u32 u[4]; f16x8 v; };
  U H, L;
  H.u[0] = __builtin_amdgcn_perm(a[1], a[0], 0x05040100u);
  H.u[1] = __builtin_amdgcn_perm(a[3], a[2], 0x05040100u);
  H.u[2] = __builtin_amdgcn_perm(b[1], b[0], 0x05040100u);
  H.u[3] = __builtin_amdgcn_perm(b[3], b[2], 0x05040100u);
  L.u[0] = __builtin_amdgcn_perm(a[1], a[0], 0x07060302u);
  L.u[1] = __builtin_amdgcn_perm(a[3], a[2], 0x07060302u);
  L.u[2] = __builtin_amdgcn_perm(b[1], b[0], 0x07060302u);
  L.u[3] = __builtin_amdgcn_perm(b[3], b[2], 0x07060302u);
  h = H.v; l = L.v;
}

// A-buffer: logical [64 m][128 c] packed u32; 16B-slot s=c>>2 swizzled: phys u32 idx =
//   m*128 + ((s ^ (m&7))<<2) + (c&3)
__device__ __forceinline__ void a_frag(const u32* Ab, int m, int ks, int lq, f16x8& h, f16x8& l) {
  const int s0 = ks*8 + lq*2;
  const u32* rb = Ab + m*128;
  u32x4 p0 = *(const u32x4*)(rb + (((s0    ) ^ (m & 7)) << 2));
  u32x4 p1 = *(const u32x4*)(rb + (((s0 + 1) ^ (m & 7)) << 2));
  unpack8(p0, p1, h, l);
}

// B image: hi bf/f16 array [N][K], row = RSS slots of 16B, swizzled; lo at +half
template<int RSS>
__device__ __forceinline__ void b_frag(const char* imgp, int half, int n, int sk, f16x8& h, f16x8& l) {
  constexpr int MS = (RSS == 16) ? 7 : 3;
  const char* p = imgp + n*(RSS*16) + ((sk ^ (n & MS)) << 4);
  h = *(const f16x8*)p;
  l = *(const f16x8*)(p + half);
}

__device__ __forceinline__ f32x4 mm(f16x8 a, f16x8 b, f32x4 c) {
  return __builtin_amdgcn_mfma_f32_16x16x32_f16(a, b, c, 0, 0, 0);
}

// ---- main GEMM: C[64][128] = A[64][Kpad] * W, 2x2 16x16 tiles per wave ----
// EPI 0: out = softplus(acc + bias[n]), store to sp[]; EPI 1: out = sig_a(sp[]) * acc
template<int KSTEPS, int RSS, int EPI>
__device__ __forceinline__ void gemmW(const u32* Ain, u32* Aout, const char* imgp, int half,
                                      const float* __restrict__ bias, float* sp, int w, int l) {
  const int lr = l & 15, lq = l >> 4;
  const int mtg = w & 1, ntg = w >> 1;
  f32x4 aH[2][2], aX[2][2];
  #pragma unroll
  for (int i = 0; i < 2; ++i)
    #pragma unroll
    for (int j = 0; j < 2; ++j) {
      aH[i][j] = (f32x4){0.f,0.f,0.f,0.f};
      aX[i][j] = (f32x4){0.f,0.f,0.f,0.f};
    }
  #pragma unroll
  for (int ks = 0; ks < KSTEPS; ++ks) {
    f16x8 ah[2], al[2];
    #pragma unroll
    for (int i = 0; i < 2; ++i)
      a_frag(Ain, (mtg*2 + i)*16 + lr, ks, lq, ah[i], al[i]);
    #pragma unroll
    for (int j = 0; j < 2; ++j) {
      const int n = (ntg*2 + j)*16 + lr;
      f16x8 bh, bl;
      b_frag<RSS>(imgp, half, n, ks*4 + lq, bh, bl);
      #pragma unroll
      for (int i = 0; i < 2; ++i) {
        aH[i][j] = mm(ah[i], bh, aH[i][j]);
        aX[i][j] = mm(ah[i], bl, aX[i][j]);
        aX[i][j] = mm(al[i], bh, aX[i][j]);
      }
    }
  }
  #pragma unroll
  for (int i = 0; i < 2; ++i)
    #pragma unroll
    for (int j = 0; j < 2; ++j) {
      const int n = (ntg*2 + j)*16 + lr;
      const float bv = (EPI == 0) ? bias[n] : 0.f;
      #pragma unroll
      for (int r = 0; r < 4; ++r) {
        const int m = (mtg*2 + i)*16 + lq*4 + r;
        const float v = aH[i][j][r] + aX[i][j][r] * (1.f/4096.f);
        float o;
        if (EPI == 0) { o = sp_f(v + bv); sp[(i*2 + j)*4 + r] = o; }
        else          { o = sig_a(sp[(i*2 + j)*4 + r]) * v; }
        Aout[m*128 + (((n >> 2) ^ (m & 7)) << 2) + (n & 3)] = pack_hl(o);
      }
    }
}

// ---- l3: C[64][28] (N padded 32) -> cT fp32 [64][29]; 1 tile/wave ----
template<bool BIAS>
__device__ __forceinline__ void gemmL3(const u32* Ain, const char* imgp, int half,
                                       const float* __restrict__ b3, float* cTo, int w, int l) {
  const int lr = l & 15, lq = l >> 4;
  const int mt = w & 3, nt = w >> 2;
  f32x4 aH = {0.f,0.f,0.f,0.f}, aX = {0.f,0.f,0.f,0.f};
  #pragma unroll
  for (int ks = 0; ks < 4; ++ks) {
    f16x8 ah, al, bh, bl;
    a_frag(Ain, mt*16 + lr, ks, lq, ah, al);
    b_frag<16>(imgp, half, nt*16 + lr, ks*4 + lq, bh, bl);
    aH = mm(ah, bh, aH); aX = mm(ah, bl, aX); aX = mm(al, bh, aX);
  }
  const int n = nt*16 + lr;
  if (n < 28) {
    const float bv = BIAS ? b3[n] : 0.f;
    #pragma unroll
    for (int r = 0; r < 4; ++r)
      cTo[(mt*16 + lq*4 + r)*29 + n] = aH[r] + aX[r]*(1.f/4096.f) + bv;
  }
}

// ---- N=16 GEMM (gq / potential head), waves 0-3 ----
template<bool HEAD>
__device__ __forceinline__ void gemmN16(const u32* Ain, const char* imgp, int half,
                                        float* GQ, float* V, int w, int l) {
  if (w >= 4) return;
  const int lr = l & 15, lq = l >> 4;
  f32x4 aH = {0.f,0.f,0.f,0.f}, aX = {0.f,0.f,0.f,0.f};
  #pragma unroll
  for (int ks = 0; ks < 4; ++ks) {
    f16x8 ah, al, bh, bl;
    a_frag(Ain, w*16 + lr, ks, lq, ah, al);
    b_frag<16>(imgp, half, lr, ks*4 + lq, bh, bl);
    aH = mm(ah, bh, aH); aX = mm(ah, bl, aX); aX = mm(al, bh, aX);
  }
  #pragma unroll
  for (int r = 0; r < 4; ++r) {
    const float v = aH[r] + aX[r]*(1.f/4096.f);
    const int m = w*16 + lq*4 + r;
    if (HEAD) { if (lr == 0) V[m] = v; }
    else      GQ[m*17 + lr] = v;
  }
}

// ---- async global->LDS staging of one image (linear, pre-swizzled in ws) ----
typedef u32 __attribute__((address_space(1))) gu32_t;
typedef u32 __attribute__((address_space(3))) lu32_t;
__device__ __forceinline__ void stageKB(const char* ws, int boff, int kb, u32* wb, int w, int l) {
  const u32* g = (const u32*)(ws + boff);
  for (int c = w; c < kb; c += 8) {
    __builtin_amdgcn_global_load_lds((const gu32_t*)(g + c*256 + l*4),
                                     (lu32_t*)(wb + c*256), 16, 0, 0);
  }
}

// ---- build Q/Qd matrix [64][32pad] packed into an A-buffer ----
__device__ __forceinline__ void buildQmat(u32* buf, const float* __restrict__ src, int s0, int t) {
  const int m = t >> 3, sl = t & 7;
  u32x4 v;
  #pragma unroll
  for (int cc = 0; cc < 4; ++cc) {
    const int c = sl*4 + cc;
    v[cc] = (c < 7) ? pack_hl(src[(s0 + m)*7 + c]) : 0u;
  }
  *(u32x4*)(buf + m*128 + ((sl ^ (m & 7)) << 2)) = v;
}

struct __align__(16) Smem {
  u32 b0[8192];     // 32KB activation ping
  u32 b1[8192];     // 32KB activation pong
  u32 wb[16384];    // 64KB weight image
  float cT[64*29];
  float dcT[64*29];
  float GQ[64*17];
  float V[64];
};
static_assert(sizeof(Smem) <= 160*1024, "LDS overflow");

// ================= pack kernel: build swizzled f16 hi/lo weight images =================
__global__ __launch_bounds__(256)
void pack_kernel(const float* __restrict__ mW0, const float* __restrict__ mW1,
                 const float* __restrict__ mW2, const float* __restrict__ mW3,
                 const float* __restrict__ pW0, const float* __restrict__ pW1,
                 const float* __restrict__ pW2, const float* __restrict__ pW3,
                 const float* __restrict__ fW0, const float* __restrict__ fW1,
                 const float* __restrict__ fW2, const float* __restrict__ fW3,
                 char* __restrict__ ws)
{
  const int idx = blockIdx.x*256 + threadIdx.x;
  if (idx >= TOTE) return;
  int img = 0, ebase = 0, esz = ECUM[1];
  #pragma unroll
  for (int i = 1; i < 19; ++i)
    if (idx >= ECUM[i]) { img = i; ebase = ECUM[i]; esz = ECUM[i+1] - ECUM[i]; }
  const int e = idx - ebase;
  const float* src; int type;
  switch (img) {
    case 0:  src = mW0; type = 0; break;
    case 1:  src = mW1; type = 1; break;
    case 2:  src = mW2; type = 1; break;
    case 3:  src = mW3; type = 2; break;
    case 4:  src = mW3; type = 3; break;
    case 5:  src = mW2; type = 4; break;
    case 6:  src = mW1; type = 4; break;
    case 7:  src = mW0; type = 5; break;
    case 8:  src = pW0; type = 0; break;
    case 9:  src = pW1; type = 1; break;
    case 10: src = pW2; type = 1; break;
    case 11: src = pW3; type = 6; break;
    case 12: src = pW2; type = 4; break;
    case 13: src = pW1; type = 4; break;
    case 14: src = pW0; type = 5; break;
    case 15: src = fW0; type = 0; break;
    case 16: src = fW1; type = 1; break;
    case 17: src = fW2; type = 1; break;
    default: src = fW3; type = 2; break;
  }
  int n, k, kdim;
  if (type == 0 || type == 3) { k = e & 31;  n = e >> 5; kdim = 32; }
  else                        { k = e & 127; n = e >> 7; kdim = 128; }
  float v;
  switch (type) {
    case 0: v = (k < 7)  ? src[k*128 + n] : 0.f; break;  // fwd-T of [7][128]
    case 1: v = src[k*128 + n]; break;                   // fwd-T of [128][128]
    case 2: v = (n < 28) ? src[k*28 + n] : 0.f; break;   // l3 (W3 fwd), N-pad
    case 3: v = (k < 28) ? src[n*28 + k] : 0.f; break;   // bwd28 (W3 as-is), K-pad
    case 4: v = src[n*128 + k]; break;                   // bwd (W as-is)
    case 5: v = (n < 7)  ? src[n*128 + k] : 0.f; break;  // gq (W0 as-is), N-pad16
    default: v = (n == 0) ? src[k] : 0.f; break;         // head (pW3), N-pad16
  }
  const int SLOTS = kdim >> 3;
  const int MS = (SLOTS == 16) ? 7 : 3;
  const int ah = ebase*4 + n*(SLOTS*16) + (((k >> 3) ^ (n & MS)) << 4) + (k & 7)*2;
  _Float16 h = (_Float16)v;
  _Float16 lo = (_Float16)((v - (float)h) * 4096.f);
  union { _Float16 f; unsigned short s; } ch, cl;
  ch.f = h; cl.f = lo;
  *(unsigned short*)(ws + ah) = ch.s;
  *(unsigned short*)(ws + ah + esz*2) = cl.s;
}

// ================= main kernel =================
__global__ __launch_bounds__(NT, 2)
void delan_kernel(const float* __restrict__ qg, const float* __restrict__ qdg,
    const float* __restrict__ mb0, const float* __restrict__ mb1,
    const float* __restrict__ mb2, const float* __restrict__ mb3,
    const float* __restrict__ pb0, const float* __restrict__ pb1,
    const float* __restrict__ pb2, const float* __restrict__ pb3,
    const float* __restrict__ pW3,
    const float* __restrict__ fb0, const float* __restrict__ fb1,
    const float* __restrict__ fb2, const float* __restrict__ fb3,
    const char* __restrict__ ws, float* __restrict__ out)
{
  __shared__ Smem S;
  const int t = threadIdx.x;
  const int l = t & 63;
  const int w = __builtin_amdgcn_readfirstlane(t >> 6);
  const int s0 = blockIdx.x * 64;
  const char* WI = (const char*)S.wb;

  float q[7], qd[7];
  #pragma unroll
  for (int i = 0; i < 7; ++i) { q[i] = qg[(s0+l)*7 + i]; qd[i] = qdg[(s0+l)*7 + i]; }

  float sp1[16], sp2[16], sp3[16];
  float valsv[28], wv[7], rhsv[7];

  // ===================== MASS =====================
  buildQmat(S.b0, qg, s0, t);
  stageKB(ws, BO(0), KBc(0), S.wb, w, l);
  __syncthreads();
  gemmW<1,4,0>(S.b0, S.b1, WI, HB(0), mb0, sp1, w, l);            // A1
  __syncthreads();
  stageKB(ws, BO(1), KBc(1), S.wb, w, l); __syncthreads();
  gemmW<4,16,0>(S.b1, S.b0, WI, HB(1), mb1, sp2, w, l);           // A2
  __syncthreads();
  stageKB(ws, BO(2), KBc(2), S.wb, w, l); __syncthreads();
  gemmW<4,16,0>(S.b0, S.b1, WI, HB(2), mb2, sp3, w, l);           // A3
  __syncthreads();
  stageKB(ws, BO(3), KBc(3), S.wb, w, l); __syncthreads();
  gemmL3<true>(S.b1, WI, HB(3), mb3, S.cT, w, l);                 // c -> cT
  __syncthreads();
  stageKB(ws, BO(4), KBc(4), S.wb, w, l);
  if (w == 0) {  // P1: L values, w = L^T qd, cotangent U -> b0
    #pragma unroll
    for (int u = 0; u < 28; ++u) {
      const float c = S.cT[l*29 + u];
      valsv[u] = DG_[u] ? __expf(c) : c;
    }
    #pragma unroll
    for (int i = 0; i < 7; ++i) wv[i] = 0.f;
    #pragma unroll
    for (int u = 0; u < 28; ++u) wv[TJ_[u]] = fmaf(valsv[u], qd[TI_[u]], wv[TJ_[u]]);
    #pragma unroll
    for (int u = 0; u < 28; ++u) {
      const float uval = (DG_[u] ? valsv[u] : 1.f) * qd[TI_[u]] * wv[TJ_[u]];
      S.b0[l*128 + (((u >> 2) ^ (l & 7)) << 2) + (u & 3)] = pack_hl(uval);
    }
    #pragma unroll
    for (int u = 28; u < 32; ++u)
      S.b0[l*128 + (((u >> 2) ^ (l & 7)) << 2) + (u & 3)] = 0u;
  }
  __syncthreads();
  gemmW<1,4,1>(S.b0, S.b1, WI, HB(4), nullptr, sp3, w, l);        // G3
  __syncthreads();
  stageKB(ws, BO(5), KBc(5), S.wb, w, l); __syncthreads();
  gemmW<4,16,1>(S.b1, S.b0, WI, HB(5), nullptr, sp2, w, l);       // G2
  __syncthreads();
  stageKB(ws, BO(6), KBc(6), S.wb, w, l); __syncthreads();
  gemmW<4,16,1>(S.b0, S.b1, WI, HB(6), nullptr, sp1, w, l);       // G1
  __syncthreads();
  stageKB(ws, BO(7), KBc(7), S.wb, w, l); __syncthreads();
  gemmN16<false>(S.b1, WI, HB(7), S.GQ, S.V, w, l);               // gq(mass)
  __syncthreads();

  // ===================== JVP =====================
  buildQmat(S.b0, qdg, s0, t);
  stageKB(ws, BO(0), KBc(0), S.wb, w, l); __syncthreads();
  gemmW<1,4,1>(S.b0, S.b1, WI, HB(0), nullptr, sp1, w, l);        // d1
  __syncthreads();
  stageKB(ws, BO(1), KBc(1), S.wb, w, l); __syncthreads();
  gemmW<4,16,1>(S.b1, S.b0, WI, HB(1), nullptr, sp2, w, l);       // d2
  __syncthreads();
  stageKB(ws, BO(2), KBc(2), S.wb, w, l); __syncthreads();
  gemmW<4,16,1>(S.b0, S.b1, WI, HB(2), nullptr, sp3, w, l);       // d3
  __syncthreads();
  stageKB(ws, BO(3), KBc(3), S.wb, w, l); __syncthreads();
  gemmL3<false>(S.b1, WI, HB(3), nullptr, S.dcT, w, l);           // dc -> dcT
  __syncthreads();

  // P2 + potential start
  stageKB(ws, BO(8), KBc(8), S.wb, w, l);
  buildQmat(S.b0, qg, s0, t);
  if (w == 0) {
    float gq7[7];
    #pragma unroll
    for (int i = 0; i < 7; ++i) gq7[i] = S.GQ[l*17 + i];
    float cor[7] = {0,0,0,0,0,0,0}, t2[7] = {0,0,0,0,0,0,0};
    #pragma unroll
    for (int u = 0; u < 28; ++u) {
      const float dv = (DG_[u] ? valsv[u] : 1.f) * S.dcT[l*29 + u];
      cor[TI_[u]] = fmaf(dv, wv[TJ_[u]], cor[TI_[u]]);
      t2[TJ_[u]]  = fmaf(dv, qd[TI_[u]], t2[TJ_[u]]);
    }
    #pragma unroll
    for (int u = 0; u < 28; ++u) cor[TI_[u]] = fmaf(valsv[u], t2[TJ_[u]], cor[TI_[u]]);
    #pragma unroll
    for (int i = 0; i < 7; ++i) rhsv[i] = gq7[i] - cor[i];
  }
  __syncthreads();

  // ===================== POTENTIAL =====================
  gemmW<1,4,0>(S.b0, S.b1, WI, HB(8), pb0, sp1, w, l);            // A1p
  __syncthreads();
  stageKB(ws, BO(9), KBc(9), S.wb, w, l); __syncthreads();
  gemmW<4,16,0>(S.b1, S.b0, WI, HB(9), pb1, sp2, w, l);           // A2p
  __syncthreads();
  stageKB(ws, BO(10), KBc(10), S.wb, w, l); __syncthreads();
  gemmW<4,16,0>(S.b0, S.b1, WI, HB(10), pb2, sp3, w, l);          // A3p
  __syncthreads();
  stageKB(ws, BO(11), KBc(11), S.wb, w, l); __syncthreads();
  gemmN16<true>(S.b1, WI, HB(11), S.GQ, S.V, w, l);               // head -> V
  __syncthreads();
  stageKB(ws, BO(12), KBc(12), S.wb, w, l);
  {  // seed: G3p = sigmoid(V+pb3) * sig(z3p) * pW3[n]  -> b0
    const int lr = l & 15, lq = l >> 4;
    const int mtg = w & 1, ntg = w >> 1;
    const float pb3v = pb3[0];
    float up[2][4];
    #pragma unroll
    for (int i = 0; i < 2; ++i)
      #pragma unroll
      for (int r = 0; r < 4; ++r)
        up[i][r] = sigm(S.V[(mtg*2 + i)*16 + lq*4 + r] + pb3v);
    #pragma unroll
    for (int j = 0; j < 2; ++j) {
      const int n = (ntg*2 + j)*16 + lr;
      const float w3 = pW3[n];
      #pragma unroll
      for (int i = 0; i < 2; ++i)
        #pragma unroll
        for (int r = 0; r < 4; ++r) {
          const int m = (mtg*2 + i)*16 + lq*4 + r;
          const float v2 = up[i][r] * sig_a(sp3[(i*2 + j)*4 + r]) * w3;
          S.b0[m*128 + (((n >> 2) ^ (m & 7)) << 2) + (n & 3)] = pack_hl(v2);
        }
    }
  }
  __syncthreads();
  gemmW<4,16,1>(S.b0, S.b1, WI, HB(12), nullptr, sp2, w, l);      // G2p
  __syncthreads();
  stageKB(ws, BO(13), KBc(13), S.wb, w, l); __syncthreads();
  gemmW<4,16,1>(S.b1, S.b0, WI, HB(13), nullptr, sp1, w, l);      // G1p
  __syncthreads();
  stageKB(ws, BO(14), KBc(14), S.wb, w, l); __syncthreads();
  gemmN16<false>(S.b0, WI, HB(14), S.GQ, S.V, w, l);              // gq(pot)
  __syncthreads();

  // ===================== FRICTION =====================
  stageKB(ws, BO(15), KBc(15), S.wb, w, l);
  buildQmat(S.b1, qg, s0, t);
  if (w == 0) {  // P2b: rhs -= gradV
    #pragma unroll
    for (int i = 0; i < 7; ++i) rhsv[i] -= S.GQ[l*17 + i];
  }
  __syncthreads();
  gemmW<1,4,0>(S.b1, S.b0, WI, HB(15), fb0, sp1, w, l);           // F1
  __syncthreads();
  stageKB(ws, BO(16), KBc(16), S.wb, w, l); __syncthreads();
  gemmW<4,16,0>(S.b0, S.b1, WI, HB(16), fb1, sp2, w, l);          // F2
  __syncthreads();
  stageKB(ws, BO(17), KBc(17), S.wb, w, l); __syncthreads();
  gemmW<4,16,0>(S.b1, S.b0, WI, HB(17), fb2, sp3, w, l);          // F3
  __syncthreads();
  stageKB(ws, BO(18), KBc(18), S.wb, w, l); __syncthreads();
  gemmL3<true>(S.b0, WI, HB(18), fb3, S.cT, w, l);                // cf -> cT
  __syncthreads();

  // ===================== P3: friction, Cholesky solve, output =====================
  if (w == 0) {
    float fv[28];
    #pragma unroll
    for (int u = 0; u < 28; ++u) {
      const float c = S.cT[l*29 + u];
      fv[u] = DG_[u] ? __expf(c) : c;
    }
    float wf[7] = {0,0,0,0,0,0,0};
    #pragma unroll
    for (int u = 0; u < 28; ++u) wf[TJ_[u]] = fmaf(fv[u], qd[TI_[u]], wf[TJ_[u]]);
    float fric[7];
    #pragma unroll
    for (int i = 0; i < 7; ++i) fric[i] = 1e-3f * qd[i];
    #pragma unroll
    for (int u = 0; u < 28; ++u) fric[TI_[u]] = fmaf(fv[u], wf[TJ_[u]], fric[TI_[u]]);
    float r7[7];
    #pragma unroll
    for (int i = 0; i < 7; ++i) r7[i] = rhsv[i] - fric[i];

    float L[7][7];
    #pragma unroll
    for (int i = 0; i < 7; ++i)
      #pragma unroll
      for (int j = 0; j < 7; ++j) L[i][j] = 0.f;
    #pragma unroll
    for (int u = 0; u < 28; ++u) L[TI_[u]][TJ_[u]] = valsv[u];

    float M[7][7];
    #pragma unroll
    for (int i = 0; i < 7; ++i)
      #pragma unroll
      for (int j = 0; j < 7; ++j)
        if (j <= i) {
          float sum = (i == j) ? 1.1e-3f : 0.f;
          #pragma unroll
          for (int k = 0; k < 7; ++k) if (k <= j) sum = fmaf(L[i][k], L[j][k], sum);
          M[i][j] = sum;
        }
    float C[7][7];
    #pragma unroll
    for (int i = 0; i < 7; ++i)
      #pragma unroll
      for (int j = 0; j < 7; ++j)
        if (j <= i) {
          float sum = M[i][j];
          #pragma unroll
          for (int k = 0; k < 7; ++k) if (k < j) sum -= C[i][k] * C[j][k];
          if (j == i) C[i][j] = sqrtf(fmaxf(sum, 1e-12f));
          else        C[i][j] = sum / C[j][j];
        }
    float y[7];
    #pragma unroll
    for (int i = 0; i < 7; ++i) {
      float sum = r7[i];
      #pragma unroll
      for (int k = 0; k < 7; ++k) if (k < i) sum -= C[i][k] * y[k];
      y[i] = sum / C[i][i];
    }
    float x[7];
    #pragma unroll
    for (int i = 6; i >= 0; --i) {
      float sum = y[i];
      #pragma unroll
      for (int k = 0; k < 7; ++k) if (k > i) sum -= C[k][i] * x[k];
      x[i] = sum / C[i][i];
    }
    #pragma unroll
    for (int i = 0; i < 7; ++i) out[(s0 + l)*7 + i] = x[i];
  }
}

extern "C" void kernel_launch(void* const* d_in, const int* in_sizes, int n_in,
                              void* d_out, int out_size, void* d_ws, size_t ws_size,
                              hipStream_t stream) {
  (void)in_sizes; (void)n_in; (void)out_size; (void)ws_size;
  const float* q   = (const float*)d_in[0];
  const float* qd  = (const float*)d_in[1];
  const float* mW0 = (const float*)d_in[2];  const float* mb0 = (const float*)d_in[3];
  const float* mW1 = (const float*)d_in[4];  const float* mb1 = (const float*)d_in[5];
  const float* mW2 = (const float*)d_in[6];  const float* mb2 = (const float*)d_in[7];
  const float* mW3 = (const float*)d_in[8];  const float* mb3 = (const float*)d_in[9];
  const float* pW0 = (const float*)d_in[10]; const float* pb0 = (const float*)d_in[11];
  const float* pW1 = (const float*)d_in[12]; const float* pb1 = (const float*)d_in[13];
  const float* pW2 = (const float*)d_in[14]; const float* pb2 = (const float*)d_in[15];
  const float* pW3 = (const float*)d_in[16]; const float* pb3 = (const float*)d_in[17];
  const float* fW0 = (const float*)d_in[18]; const float* fb0 = (const float*)d_in[19];
  const float* fW1 = (const float*)d_in[20]; const float* fb1 = (const float*)d_in[21];
  const float* fW2 = (const float*)d_in[22]; const float* fb2 = (const float*)d_in[23];
  const float* fW3 = (const float*)d_in[24]; const float* fb3 = (const float*)d_in[25];
  float* out = (float*)d_out;
  char* ws = (char*)d_ws;

  pack_kernel<<<dim3((TOTE + 255)/256), dim3(256), 0, stream>>>(
      mW0, mW1, mW2, mW3, pW0, pW1, pW2, pW3, fW0, fW1, fW2, fW3, ws);

  delan_kernel<<<dim3(NBLK), dim3(NT), 0, stream>>>(
      q, qd,
      mb0, mb1, mb2, mb3,
      pb0, pb1, pb2, pb3, pW3,
      fb0, fb1, fb2, fb3,
      ws, out);
}

// Round 4
// 279.251 us; speedup vs baseline: 7.7850x; 1.4108x over previous
//
#include <hip/hip_runtime.h>

#define NT 512
#define TM 32
#define NBLK (65536/TM)

typedef unsigned int u32;
typedef unsigned short u16;
typedef __attribute__((ext_vector_type(4))) float f32x4;
typedef __attribute__((ext_vector_type(4))) u32 u32x4;
typedef __attribute__((ext_vector_type(8))) _Float16 f16x8;

namespace {
constexpr int TI_[28] = {0,1,1,2,2,2,3,3,3,3,4,4,4,4,4,5,5,5,5,5,5,6,6,6,6,6,6,6};
constexpr int TJ_[28] = {0,0,1,0,1,2,0,1,2,3,0,1,2,3,4,0,1,2,3,4,5,0,1,2,3,4,5,6};
constexpr bool DG_[28] = {1,0,1,0,0,1,0,0,0,1,0,0,0,0,1,0,0,0,0,0,1,0,0,0,0,0,0,1};

// 19 weight images in ws. Layout per image: [K-chunk][8 slots: hi 0-3, lo 4-7][N][16B]
// byte offsets (cumulative):
constexpr int IB[20] = {0,16384,81920,147456,163840,180224,245760,311296,319488,
                        335872,401408,466944,475136,540672,606208,614400,630784,
                        696320,761856,778240};
constexpr int IN_[19]  = {128,128,128,32,128,128,128,16,128,128,128,16,128,128,16,128,128,128,32};
constexpr int ITY_[19] = {0,1,1,2,3,4,4,5,0,1,1,6,4,4,5,0,1,1,2};
constexpr int TOTF16 = 778240/2;
}

__device__ __forceinline__ float sp_f(float z) {
  float t = exp2f(-fabsf(z)*1.44269504f);
  return fmaxf(z, 0.f) + 0.69314718f*__log2f(1.f + t);
}
__device__ __forceinline__ float sigm_f(float z) {         // sigmoid(z)
  float t = exp2f(-z*1.44269504f);
  return __builtin_amdgcn_rcpf(1.f + t);
}
__device__ __forceinline__ float sig_a(float a) {          // sigmoid(z) from a=softplus(z)
  return 1.f - exp2f(-a*1.44269504f);
}

// f32 -> packed u32: low16 = f16(x), high16 = f16((x - hi)*4096)
__device__ __forceinline__ u32 pack_hl(float x) {
  _Float16 h = (_Float16)x;
  _Float16 lo = (_Float16)((x - (float)h) * 4096.f);
  union { _Float16 f[2]; u32 u; } r;
  r.f[0] = h; r.f[1] = lo;
  return r.u;
}
__device__ __forceinline__ float unpack_val(u32 pv) {
  union { u32 u; _Float16 f[2]; } c; c.u = pv;
  return (float)c.f[0] + (float)c.f[1]*(1.f/4096.f);
}
__device__ __forceinline__ u16 f16b(float x) {
  union { _Float16 f; u16 u; } c; c.f = (_Float16)x; return c.u;
}
__device__ __forceinline__ float f16v(u16 b) {
  union { u16 u; _Float16 f; } c; c.u = b; return (float)c.f;
}

__device__ __forceinline__ void unpack8(const u32x4 a, const u32x4 b, f16x8& h, f16x8& l) {
  union U { u32 u[4]; f16x8 v; };
  U H, L;
  H.u[0] = __builtin_amdgcn_perm(a[1], a[0], 0x05040100u);
  H.u[1] = __builtin_amdgcn_perm(a[3], a[2], 0x05040100u);
  H.u[2] = __builtin_amdgcn_perm(b[1], b[0], 0x05040100u);
  H.u[3] = __builtin_amdgcn_perm(b[3], b[2], 0x05040100u);
  L.u[0] = __builtin_amdgcn_perm(a[1], a[0], 0x07060302u);
  L.u[1] = __builtin_amdgcn_perm(a[3], a[2], 0x07060302u);
  L.u[2] = __builtin_amdgcn_perm(b[1], b[2-2], 0x07060302u);
  L.u[2] = __builtin_amdgcn_perm(b[1], b[0], 0x07060302u);
  L.u[3] = __builtin_amdgcn_perm(b[3], b[2], 0x07060302u);
  h = H.v; l = L.v;
}

__device__ __forceinline__ f32x4 mm(f16x8 a, f16x8 b, f32x4 c) {
  return __builtin_amdgcn_mfma_f32_16x16x32_f16(a, b, c, 0, 0, 0);
}

// B-fragment from global (ws): hi at slot sk, lo at slot sk+4
__device__ __forceinline__ void bfrag(const char* __restrict__ img, int N, int chunk, int sk,
                                      int n, f16x8& h, f16x8& l) {
  const char* p = img + (((chunk*8 + sk)*N + n) << 4);
  h = *(const f16x8*)p;
  l = *(const f16x8*)(p + (N << 6));
}

// packed A-frag from [32][128]-u32 buffer (32 slots, XOR m&7)
__device__ __forceinline__ void afragP(const u32* __restrict__ Ab, int m, int s0,
                                       f16x8& h, f16x8& l) {
  const u32* rb = Ab + m*128;
  u32x4 p0 = *(const u32x4*)(rb + (((s0    ) ^ (m & 7)) << 2));
  u32x4 p1 = *(const u32x4*)(rb + (((s0 + 1) ^ (m & 7)) << 2));
  unpack8(p0, p1, h, l);
}
// packed A-frag from Qmat [32][32]-u32 (8 slots, XOR m&7)
__device__ __forceinline__ void afragQ(const u32* __restrict__ Ab, int m, int lq,
                                       f16x8& h, f16x8& l) {
  const u32* rb = Ab + m*32;
  u32x4 p0 = *(const u32x4*)(rb + (((lq*2    ) ^ (m & 7)) << 2));
  u32x4 p1 = *(const u32x4*)(rb + (((lq*2 + 1) ^ (m & 7)) << 2));
  unpack8(p0, p1, h, l);
}
// f16 A-frag from [32][128]-f16 buffer (16 slots, XOR m&7)
__device__ __forceinline__ f16x8 afragH(const u16* __restrict__ Gb, int m, int s) {
  return *(const f16x8*)(Gb + m*128 + ((s ^ (m & 7)) << 3));
}
// f16 A-frag from [32][32]-f16 buffer (4 slots, XOR m&3)
__device__ __forceinline__ f16x8 afragU(const u16* __restrict__ Ub, int m, int lq) {
  return *(const f16x8*)(Ub + m*32 + ((lq ^ (m & 3)) << 3));
}

// swizzled [28][32] f32 (c/vals): slot = m>>2 XOR (u&7)
__device__ __forceinline__ float ctread(const float* __restrict__ cT, int u, int m) {
  return cT[u*32 + (((m >> 2) ^ (u & 7)) << 2) + (m & 3)];
}
__device__ __forceinline__ void ctwrite(float* __restrict__ cT, int u, int m, float v) {
  cT[u*32 + (((m >> 2) ^ (u & 7)) << 2) + (m & 3)] = v;
}

struct __align__(16) Smem {
  u32 b0[TM*128];     // 16384 B packed fwd activations
  u32 b1[TM*128];     // 16384
  u16 g0[TM*128];     // 8192  f16 grad/JVP
  u16 g1[TM*128];     // 8192
  u16 sig1[TM*128];   // 8192  sigma of layer-1 preact
  u32 qm[TM*32];      // 4096  packed Q matrix (k=7 -> 1.0 for bias)
  u16 ub[TM*32];      // 2048  U cotangent (f16)
  u16 qdb[TM*32];     // 2048  Qd matrix (f16)
  float cT[28*32];    // 3584  c / dc / cf (swizzled)
  float vls[28*32];   // 3584  L values
  float GQ[TM*17];    // 2176
  float wv8[TM*8];    // 1024
  float rh8[TM*8];    // 1024
  float V[TM];        // 128
};
static_assert(sizeof(Smem) <= 80*1024, "need 2 blocks/CU");

// ---- fwd layer: C[32][128] = A*W (+bias), softplus, -> packed; optional sigma-plane ----
template<int KSTEPS, bool QSRC, bool SIGW>
__device__ __forceinline__ void gemm_fwd(const u32* __restrict__ Ain, u32* __restrict__ Bout,
                                         u16* __restrict__ sigp, const char* __restrict__ img,
                                         const float* __restrict__ bias, int w, int l) {
  const int lr = l & 15, lq = l >> 4;
  const int mt = w & 1, ng = w >> 1;
  const int mrow = mt*16 + lr;
  f32x4 aH0 = {0,0,0,0}, aH1 = {0,0,0,0}, aX0 = {0,0,0,0}, aX1 = {0,0,0,0};
  #pragma unroll
  for (int ks = 0; ks < KSTEPS; ++ks) {
    f16x8 ah, al;
    if (QSRC) afragQ(Ain, mrow, lq, ah, al);
    else      afragP(Ain, mrow, ks*8 + lq*2, ah, al);
    f16x8 bh, bl;
    bfrag(img, 128, ks, lq, ng*16 + lr, bh, bl);
    aH0 = mm(ah, bh, aH0); aX0 = mm(ah, bl, aX0); aX0 = mm(al, bh, aX0);
    bfrag(img, 128, ks, lq, (ng+4)*16 + lr, bh, bl);
    aH1 = mm(ah, bh, aH1); aX1 = mm(ah, bl, aX1); aX1 = mm(al, bh, aX1);
  }
  #pragma unroll
  for (int j = 0; j < 2; ++j) {
    const f32x4 vh = j ? aH1 : aH0, vx = j ? aX1 : aX0;
    const int n = (ng + j*4)*16 + lr;
    const float bv = bias ? bias[n] : 0.f;
    #pragma unroll
    for (int r = 0; r < 4; ++r) {
      const int m = mt*16 + lq*4 + r;
      const float z = vh[r] + vx[r]*(1.f/4096.f) + bv;
      Bout[m*128 + (((n>>2) ^ (m&7)) << 2) + (n&3)] = pack_hl(sp_f(z));
      if (SIGW) sigp[m*128 + n] = f16b(sigm_f(z));
    }
  }
}

// ---- grad/JVP layer: C = sigma .* (A*W), f16 in/out ----
template<int KSTEPS, bool KQ, bool SEXACT>
__device__ __forceinline__ void gemm_grad(const u16* __restrict__ Ain, u16* __restrict__ Gout,
                                          const u32* __restrict__ sP, const u16* __restrict__ sigp,
                                          const char* __restrict__ img, int w, int l) {
  const int lr = l & 15, lq = l >> 4;
  const int mt = w & 1, ng = w >> 1;
  const int mrow = mt*16 + lr;
  f32x4 aH0 = {0,0,0,0}, aH1 = {0,0,0,0}, aX0 = {0,0,0,0}, aX1 = {0,0,0,0};
  #pragma unroll
  for (int ks = 0; ks < KSTEPS; ++ks) {
    f16x8 ah = KQ ? afragU(Ain, mrow, lq) : afragH(Ain, mrow, ks*4 + lq);
    f16x8 bh, bl;
    bfrag(img, 128, ks, lq, ng*16 + lr, bh, bl);
    aH0 = mm(ah, bh, aH0); aX0 = mm(ah, bl, aX0);
    bfrag(img, 128, ks, lq, (ng+4)*16 + lr, bh, bl);
    aH1 = mm(ah, bh, aH1); aX1 = mm(ah, bl, aX1);
  }
  #pragma unroll
  for (int j = 0; j < 2; ++j) {
    const f32x4 vh = j ? aH1 : aH0, vx = j ? aX1 : aX0;
    const int n = (ng + j*4)*16 + lr;
    #pragma unroll
    for (int r = 0; r < 4; ++r) {
      const int m = mt*16 + lq*4 + r;
      const float v = vh[r] + vx[r]*(1.f/4096.f);
      float s;
      if (SEXACT) s = sig_a(unpack_val(sP[m*128 + (((n>>2) ^ (m&7)) << 2) + (n&3)]));
      else        s = f16v(sigp[m*128 + n]);
      Gout[m*128 + (((n>>3) ^ (m&7)) << 3) + (n&7)] = f16b(s * v);
    }
  }
}

// ---- l3: C[32][28] -> cT (swizzled f32) ----
template<bool APACK, bool BIAS>
__device__ __forceinline__ void gemm_l3(const u32* __restrict__ AP, const u16* __restrict__ AH,
                                        float* __restrict__ cT, const char* __restrict__ img,
                                        const float* __restrict__ b3, int w, int l) {
  if (w >= 4) return;
  const int lr = l & 15, lq = l >> 4;
  const int mt = w & 1, nt = w >> 1;
  const int mrow = mt*16 + lr;
  f32x4 aHa = {0,0,0,0}, aXa = {0,0,0,0};
  #pragma unroll
  for (int ks = 0; ks < 4; ++ks) {
    f16x8 ah, al, bh, bl;
    if (APACK) afragP(AP, mrow, ks*8 + lq*2, ah, al);
    else       ah = afragH(AH, mrow, ks*4 + lq);
    bfrag(img, 32, ks, lq, nt*16 + lr, bh, bl);
    aHa = mm(ah, bh, aHa); aXa = mm(ah, bl, aXa);
    if (APACK) aXa = mm(al, bh, aXa);
  }
  const int n = nt*16 + lr;
  if (n < 28) {
    const float bv = BIAS ? b3[n] : 0.f;
    f32x4 v;
    #pragma unroll
    for (int r = 0; r < 4; ++r) v[r] = aHa[r] + aXa[r]*(1.f/4096.f) + bv;
    const int m0 = mt*16 + lq*4;
    *(f32x4*)&cT[n*32 + (((m0 >> 2) ^ (n & 7)) << 2)] = v;
  }
}

// ---- N=16 gemm: gq (GQ) or potential head (V) ----
template<bool APACK, bool HEAD>
__device__ __forceinline__ void gemm_n16(const u32* __restrict__ AP, const u16* __restrict__ AH,
                                         float* __restrict__ GQ, float* __restrict__ V,
                                         const char* __restrict__ img, int w, int l) {
  if (w >= 2) return;
  const int lr = l & 15, lq = l >> 4;
  const int mrow = w*16 + lr;
  f32x4 aHa = {0,0,0,0}, aXa = {0,0,0,0};
  #pragma unroll
  for (int ks = 0; ks < 4; ++ks) {
    f16x8 ah, al, bh, bl;
    if (APACK) afragP(AP, mrow, ks*8 + lq*2, ah, al);
    else       ah = afragH(AH, mrow, ks*4 + lq);
    bfrag(img, 16, ks, lq, lr, bh, bl);
    aHa = mm(ah, bh, aHa); aXa = mm(ah, bl, aXa);
    if (APACK) aXa = mm(al, bh, aXa);
  }
  #pragma unroll
  for (int r = 0; r < 4; ++r) {
    const float v = aHa[r] + aXa[r]*(1.f/4096.f);
    const int m = w*16 + lq*4 + r;
    if (HEAD) { if (lr == 0) V[m] = v; }
    else      GQ[m*17 + lr] = v;
  }
}

// ================= pack kernel =================
__global__ __launch_bounds__(256)
void pack_kernel(const float* __restrict__ mW0, const float* __restrict__ mb0,
                 const float* __restrict__ mW1, const float* __restrict__ mW2,
                 const float* __restrict__ mW3,
                 const float* __restrict__ pW0, const float* __restrict__ pb0,
                 const float* __restrict__ pW1, const float* __restrict__ pW2,
                 const float* __restrict__ pW3,
                 const float* __restrict__ fW0, const float* __restrict__ fb0,
                 const float* __restrict__ fW1, const float* __restrict__ fW2,
                 const float* __restrict__ fW3,
                 u16* __restrict__ ws)
{
  const int idx = blockIdx.x*256 + threadIdx.x;
  if (idx >= TOTF16) return;
  int img = 0;
  #pragma unroll
  for (int i = 1; i < 19; ++i) if (idx*2 >= IB[i]) img = i;
  const int rem = idx - IB[img]/2;
  const int N = IN_[img];
  const int cf = N*64;
  const int chunk = rem / cf;  const int r1 = rem - chunk*cf;
  const int slot = r1 / (N*8); const int r2 = r1 - slot*(N*8);
  const int n = r2 >> 3, e = r2 & 7;
  const int k = chunk*32 + (slot & 3)*8 + e;
  const int plane = slot >> 2;

  const float* W = nullptr; const float* B = nullptr;
  switch (img) {
    case 0:  W = mW0; B = mb0; break;
    case 1:  W = mW1; break;   case 2:  W = mW2; break;
    case 3:  W = mW3; break;   case 4:  W = mW3; break;
    case 5:  W = mW2; break;   case 6:  W = mW1; break;
    case 7:  W = mW0; break;
    case 8:  W = pW0; B = pb0; break;
    case 9:  W = pW1; break;   case 10: W = pW2; break;
    case 11: W = pW3; break;   case 12: W = pW2; break;
    case 13: W = pW1; break;   case 14: W = pW0; break;
    case 15: W = fW0; B = fb0; break;
    case 16: W = fW1; break;   case 17: W = fW2; break;
    default: W = fW3; break;
  }
  float v = 0.f;
  switch (ITY_[img]) {
    case 0: v = (k < 7) ? W[k*128 + n] : (k == 7 ? B[n] : 0.f); break;
    case 1: v = W[k*128 + n]; break;
    case 2: v = (n < 28) ? W[k*28 + n] : 0.f; break;
    case 3: v = (k < 28) ? W[n*28 + k] : 0.f; break;
    case 4: v = W[n*128 + k]; break;
    case 5: v = (n < 7) ? W[n*128 + k] : 0.f; break;
    default: v = (n == 0) ? W[k] : 0.f; break;
  }
  _Float16 h = (_Float16)v;
  _Float16 o = plane ? (_Float16)((v - (float)h) * 4096.f) : h;
  union { _Float16 f; u16 u; } c; c.f = o;
  ws[idx] = c.u;
}

// ================= main kernel =================
__global__ __launch_bounds__(NT, 2)
void delan_kernel(const float* __restrict__ qg, const float* __restrict__ qdg,
    const float* __restrict__ mb1, const float* __restrict__ mb2, const float* __restrict__ mb3,
    const float* __restrict__ pb1, const float* __restrict__ pb2, const float* __restrict__ pb3,
    const float* __restrict__ pW3,
    const float* __restrict__ fb1, const float* __restrict__ fb2, const float* __restrict__ fb3,
    const char* __restrict__ ws, float* __restrict__ out)
{
  __shared__ Smem S;
  const int t = threadIdx.x;
  const int l = t & 63;
  const int w = __builtin_amdgcn_readfirstlane(t >> 6);
  const int s0 = blockIdx.x * TM;

  // build packed Q matrix (k=7 column = 1.0 -> picks up bias row of fwd W0 images)
  #pragma unroll
  for (int p = 0; p < 2; ++p) {
    const int ii = t + p*NT;
    const int m = ii >> 5, c = ii & 31;
    u32 val = 0u;
    if (c < 7)       val = pack_hl(qg[(s0 + m)*7 + c]);
    else if (c == 7) val = pack_hl(1.f);
    S.qm[m*32 + (((c >> 2) ^ (m & 7)) << 2) + (c & 3)] = val;
  }
  __syncthreads();

  // ===================== MASS =====================
  gemm_fwd<1, true, true >(S.qm, S.b0, S.sig1, ws + IB[0], nullptr, w, l); __syncthreads();
  gemm_fwd<4, false, false>(S.b0, S.b1, nullptr, ws + IB[1], mb1, w, l);   __syncthreads();
  gemm_fwd<4, false, false>(S.b1, S.b0, nullptr, ws + IB[2], mb2, w, l);   __syncthreads();
  gemm_l3<true, true>(S.b0, nullptr, S.cT, ws + IB[3], mb3, w, l);         __syncthreads();

  if (w == 0) {  // P1: L values, w = L^T qd, U cotangent
    const int ml = l & 31;
    float qdv[7];
    #pragma unroll
    for (int i = 0; i < 7; ++i) qdv[i] = qdg[(s0 + ml)*7 + i];
    float vals[28], wvv[7] = {0,0,0,0,0,0,0};
    #pragma unroll
    for (int u = 0; u < 28; ++u) {
      const float cv = ctread(S.cT, u, ml);
      vals[u] = DG_[u] ? __expf(cv) : cv;
    }
    #pragma unroll
    for (int u = 0; u < 28; ++u) wvv[TJ_[u]] = fmaf(vals[u], qdv[TI_[u]], wvv[TJ_[u]]);
    if (l < 32) {
      #pragma unroll
      for (int u = 0; u < 28; ++u) ctwrite(S.vls, u, ml, vals[u]);
      #pragma unroll
      for (int i = 0; i < 7; ++i) S.wv8[ml*8 + i] = wvv[i];
      #pragma unroll
      for (int u = 0; u < 28; ++u) {
        const float uval = (DG_[u] ? vals[u] : 1.f) * qdv[TI_[u]] * wvv[TJ_[u]];
        S.ub[ml*32 + (((u >> 3) ^ (ml & 3)) << 3) + (u & 7)] = f16b(uval);
      }
      #pragma unroll
      for (int u = 28; u < 32; ++u)
        S.ub[ml*32 + (((u >> 3) ^ (ml & 3)) << 3) + (u & 7)] = 0;
    }
  } else if (w == 1) {  // build Qd matrix (f16, k>=7 zero)
    #pragma unroll
    for (int p = 0; p < 16; ++p) {
      const int ii = l + p*64;
      const int m = ii >> 5, c = ii & 31;
      S.qdb[m*32 + (((c >> 3) ^ (m & 3)) << 3) + (c & 7)] =
          (c < 7) ? f16b(qdg[(s0 + m)*7 + c]) : (u16)0;
    }
  }
  __syncthreads();

  gemm_grad<1, true, true >(S.ub,  S.g0, S.b0, nullptr, ws + IB[4], w, l); __syncthreads(); // G3
  gemm_grad<4, false, true >(S.g0, S.g1, S.b1, nullptr, ws + IB[5], w, l); __syncthreads(); // G2
  gemm_grad<4, false, false>(S.g1, S.g0, nullptr, S.sig1, ws + IB[6], w, l); __syncthreads(); // G1
  gemm_n16<false, false>(nullptr, S.g0, S.GQ, nullptr, ws + IB[7], w, l);  __syncthreads(); // gq
  gemm_grad<1, true, false>(S.qdb, S.g0, nullptr, S.sig1, ws + IB[0], w, l); __syncthreads(); // d1
  gemm_grad<4, false, true >(S.g0, S.g1, S.b1, nullptr, ws + IB[1], w, l); __syncthreads(); // d2
  gemm_grad<4, false, true >(S.g1, S.g0, S.b0, nullptr, ws + IB[2], w, l); __syncthreads(); // d3
  gemm_l3<false, false>(nullptr, S.g0, S.cT, ws + IB[3], nullptr, w, l);   __syncthreads(); // dc

  if (w == 0) {  // P2: rhs = gq - coriolis
    const int ml = l & 31;
    float qdv[7], wvv[7], gq7[7];
    #pragma unroll
    for (int i = 0; i < 7; ++i) {
      qdv[i] = qdg[(s0 + ml)*7 + i];
      wvv[i] = S.wv8[ml*8 + i];
      gq7[i] = S.GQ[ml*17 + i];
    }
    float cor[7] = {0,0,0,0,0,0,0}, t2[7] = {0,0,0,0,0,0,0};
    float lv[28];
    #pragma unroll
    for (int u = 0; u < 28; ++u) lv[u] = ctread(S.vls, u, ml);
    #pragma unroll
    for (int u = 0; u < 28; ++u) {
      const float dv = (DG_[u] ? lv[u] : 1.f) * ctread(S.cT, u, ml);
      cor[TI_[u]] = fmaf(dv, wvv[TJ_[u]], cor[TI_[u]]);
      t2[TJ_[u]]  = fmaf(dv, qdv[TI_[u]], t2[TJ_[u]]);
    }
    #pragma unroll
    for (int u = 0; u < 28; ++u) cor[TI_[u]] = fmaf(lv[u], t2[TJ_[u]], cor[TI_[u]]);
    if (l < 32) {
      #pragma unroll
      for (int i = 0; i < 7; ++i) S.rh8[ml*8 + i] = gq7[i] - cor[i];
    }
  }
  __syncthreads();

  // ===================== POTENTIAL =====================
  gemm_fwd<1, true, true >(S.qm, S.b0, S.sig1, ws + IB[8], nullptr, w, l); __syncthreads();
  gemm_fwd<4, false, false>(S.b0, S.b1, nullptr, ws + IB[9], pb1, w, l);   __syncthreads();
  gemm_fwd<4, false, false>(S.b1, S.b0, nullptr, ws + IB[10], pb2, w, l);  __syncthreads();
  gemm_n16<true, true>(S.b0, nullptr, nullptr, S.V, ws + IB[11], w, l);    __syncthreads(); // head
  {  // seed: g0 = sigmoid(V+pb3) * sigma(A3p) * pW3[n]
    const float pb3v = pb3[0];
    #pragma unroll
    for (int p = 0; p < 8; ++p) {
      const int idx = t + p*NT;
      const int m = idx >> 7, n = idx & 127;
      const float a3 = unpack_val(S.b0[m*128 + (((n>>2) ^ (m&7)) << 2) + (n&3)]);
      const float up = sigm_f(S.V[m] + pb3v);
      S.g0[m*128 + (((n>>3) ^ (m&7)) << 3) + (n&7)] = f16b(up * sig_a(a3) * pW3[n]);
    }
  }
  __syncthreads();
  gemm_grad<4, false, true >(S.g0, S.g1, S.b1, nullptr, ws + IB[12], w, l); __syncthreads(); // G2p
  gemm_grad<4, false, false>(S.g1, S.g0, nullptr, S.sig1, ws + IB[13], w, l); __syncthreads(); // G1p
  gemm_n16<false, false>(nullptr, S.g0, S.GQ, nullptr, ws + IB[14], w, l); __syncthreads(); // gqp

  // ===================== FRICTION =====================
  gemm_fwd<1, true, false>(S.qm, S.b0, nullptr, ws + IB[15], nullptr, w, l); __syncthreads();
  gemm_fwd<4, false, false>(S.b0, S.b1, nullptr, ws + IB[16], fb1, w, l);  __syncthreads();
  gemm_fwd<4, false, false>(S.b1, S.b0, nullptr, ws + IB[17], fb2, w, l);  __syncthreads();
  gemm_l3<true, true>(S.b0, nullptr, S.cT, ws + IB[18], fb3, w, l);        __syncthreads();

  // ===================== P3: friction, Cholesky solve, output =====================
  if (w == 0) {
    const int ml = l & 31;
    float qdv[7];
    #pragma unroll
    for (int i = 0; i < 7; ++i) qdv[i] = qdg[(s0 + ml)*7 + i];
    float fv[28];
    #pragma unroll
    for (int u = 0; u < 28; ++u) {
      const float cv = ctread(S.cT, u, ml);
      fv[u] = DG_[u] ? __expf(cv) : cv;
    }
    float wf[7] = {0,0,0,0,0,0,0};
    #pragma unroll
    for (int u = 0; u < 28; ++u) wf[TJ_[u]] = fmaf(fv[u], qdv[TI_[u]], wf[TJ_[u]]);
    float fric[7];
    #pragma unroll
    for (int i = 0; i < 7; ++i) fric[i] = 1e-3f * qdv[i];
    #pragma unroll
    for (int u = 0; u < 28; ++u) fric[TI_[u]] = fmaf(fv[u], wf[TJ_[u]], fric[TI_[u]]);
    float r7[7];
    #pragma unroll
    for (int i = 0; i < 7; ++i) r7[i] = S.rh8[ml*8 + i] - S.GQ[ml*17 + i] - fric[i];

    float L[7][7];
    #pragma unroll
    for (int i = 0; i < 7; ++i)
      #pragma unroll
      for (int j = 0; j < 7; ++j) L[i][j] = 0.f;
    #pragma unroll
    for (int u = 0; u < 28; ++u) L[TI_[u]][TJ_[u]] = ctread(S.vls, u, ml);

    float M[7][7];
    #pragma unroll
    for (int i = 0; i < 7; ++i)
      #pragma unroll
      for (int j = 0; j < 7; ++j)
        if (j <= i) {
          float sum = (i == j) ? 1.1e-3f : 0.f;
          #pragma unroll
          for (int k = 0; k < 7; ++k) if (k <= j) sum = fmaf(L[i][k], L[j][k], sum);
          M[i][j] = sum;
        }
    float C[7][7];
    #pragma unroll
    for (int i = 0; i < 7; ++i)
      #pragma unroll
      for (int j = 0; j < 7; ++j)
        if (j <= i) {
          float sum = M[i][j];
          #pragma unroll
          for (int k = 0; k < 7; ++k) if (k < j) sum -= C[i][k] * C[j][k];
          if (j == i) C[i][j] = sqrtf(fmaxf(sum, 1e-12f));
          else        C[i][j] = sum / C[j][j];
        }
    float y[7];
    #pragma unroll
    for (int i = 0; i < 7; ++i) {
      float sum = r7[i];
      #pragma unroll
      for (int k = 0; k < 7; ++k) if (k < i) sum -= C[i][k] * y[k];
      y[i] = sum / C[i][i];
    }
    float x[7];
    #pragma unroll
    for (int i = 6; i >= 0; --i) {
      float sum = y[i];
      #pragma unroll
      for (int k = 0; k < 7; ++k) if (k > i) sum -= C[k][i] * x[k];
      x[i] = sum / C[i][i];
    }
    if (l < 32) {
      #pragma unroll
      for (int i = 0; i < 7; ++i) out[(s0 + ml)*7 + i] = x[i];
    }
  }
}

extern "C" void kernel_launch(void* const* d_in, const int* in_sizes, int n_in,
                              void* d_out, int out_size, void* d_ws, size_t ws_size,
                              hipStream_t stream) {
  (void)in_sizes; (void)n_in; (void)out_size; (void)ws_size;
  const float* q   = (const float*)d_in[0];
  const float* qd  = (const float*)d_in[1];
  const float* mW0 = (const float*)d_in[2];  const float* mb0 = (const float*)d_in[3];
  const float* mW1 = (const float*)d_in[4];  const float* mb1 = (const float*)d_in[5];
  const float* mW2 = (const float*)d_in[6];  const float* mb2 = (const float*)d_in[7];
  const float* mW3 = (const float*)d_in[8];  const float* mb3 = (const float*)d_in[9];
  const float* pW0 = (const float*)d_in[10]; const float* pb0 = (const float*)d_in[11];
  const float* pW1 = (const float*)d_in[12]; const float* pb1 = (const float*)d_in[13];
  const float* pW2 = (const float*)d_in[14]; const float* pb2 = (const float*)d_in[15];
  const float* pW3 = (const float*)d_in[16]; const float* pb3 = (const float*)d_in[17];
  const float* fW0 = (const float*)d_in[18]; const float* fb0 = (const float*)d_in[19];
  const float* fW1 = (const float*)d_in[20]; const float* fb1 = (const float*)d_in[21];
  const float* fW2 = (const float*)d_in[22]; const float* fb2 = (const float*)d_in[23];
  const float* fW3 = (const float*)d_in[24]; const float* fb3 = (const float*)d_in[25];
  float* out = (float*)d_out;
  u16* ws = (u16*)d_ws;

  pack_kernel<<<dim3((TOTF16 + 255)/256), dim3(256), 0, stream>>>(
      mW0, mb0, mW1, mW2, mW3, pW0, pb0, pW1, pW2, pW3, fW0, fb0, fW1, fW2, fW3, ws);

  delan_kernel<<<dim3(NBLK), dim3(NT), 0, stream>>>(
      q, qd, mb1, mb2, mb3, pb1, pb2, pb3, pW3, fb1, fb2, fb3,
      (const char*)ws, out);
}

// Round 5
// 148.993 us; speedup vs baseline: 14.5912x; 1.8743x over previous
//
#include <hip/hip_runtime.h>

#define NT 512
#define TM 32
#define NBLK (65536/TM)

typedef unsigned int u32;
typedef unsigned short u16;
typedef __attribute__((ext_vector_type(4))) float f32x4;
typedef __attribute__((ext_vector_type(8))) _Float16 f16x8;

namespace {
constexpr int TI_[28] = {0,1,1,2,2,2,3,3,3,3,4,4,4,4,4,5,5,5,5,5,5,6,6,6,6,6,6,6};
constexpr int TJ_[28] = {0,0,1,0,1,2,0,1,2,3,0,1,2,3,4,0,1,2,3,4,5,0,1,2,3,4,5,6};
constexpr bool DG_[28] = {1,0,1,0,0,1,0,0,0,1,0,0,0,0,1,0,0,0,0,0,1,0,0,0,0,0,0,1};

// 19 weight images in ws, byte offsets. Per image: [hi plane][lo plane],
// each plane = [K/8 slots][N][8 f16].
constexpr int IB[20] = {0,16384,81920,147456,163840,180224,245760,311296,319488,
                        335872,401408,466944,475136,540672,606208,614400,630784,
                        696320,761856,778240};
constexpr int IN_[19]  = {128,128,128,32,128,128,128,16,128,128,128,16,128,128,16,128,128,128,32};
constexpr int ITY_[19] = {0,1,1,2,3,4,4,5,0,1,1,6,4,4,5,0,1,1,2};
constexpr int TOTF16 = 778240/2;
}

__device__ __forceinline__ float sp_f(float z) {
  float t = exp2f(-fabsf(z)*1.44269504f);
  return fmaxf(z, 0.f) + 0.69314718f*__log2f(1.f + t);
}
__device__ __forceinline__ float sigm_f(float z) {
  float t = exp2f(-z*1.44269504f);
  return __builtin_amdgcn_rcpf(1.f + t);
}
__device__ __forceinline__ float sig_a(float a) {  // sigmoid(z) from a=softplus(z)
  return 1.f - exp2f(-a*1.44269504f);
}

__device__ __forceinline__ u16 h2b(_Float16 h) { union{_Float16 f; u16 u;} c; c.f = h; return c.u; }
__device__ __forceinline__ u16 f16b(float x)   { return h2b((_Float16)x); }
__device__ __forceinline__ float b2f(u16 b)    { union{u16 u; _Float16 f;} c; c.u = b; return (float)c.f; }

__device__ __forceinline__ f32x4 mm(f16x8 a, f16x8 b, f32x4 c) {
  return __builtin_amdgcn_mfma_f32_16x16x32_f16(a, b, c, 0, 0, 0);
}

// ---- f16 plane [32][128], row 256B = 16 slots of 16B, slot XOR (row&7) ----
__device__ __forceinline__ f16x8 aread(const u16* __restrict__ P, int row, int s) {
  return *(const f16x8*)(P + row*128 + ((s ^ (row & 7)) << 3));
}
__device__ __forceinline__ void awrite(u16* __restrict__ P, int m, int n, u16 v) {
  P[m*128 + ((((n >> 3) ^ (m & 7))) << 3) + (n & 7)] = v;
}
__device__ __forceinline__ float sread(const u16* __restrict__ P, int m, int n) {
  return b2f(P[m*128 + ((((n >> 3) ^ (m & 7))) << 3) + (n & 7)]);
}
// ---- f16 plane [32][32], 4 slots/row, slot XOR (row&3) ----
__device__ __forceinline__ f16x8 aread32(const u16* __restrict__ P, int row, int lq) {
  return *(const f16x8*)(P + row*32 + ((lq ^ (row & 3)) << 3));
}
// ---- B fragment from global image plane ----
__device__ __forceinline__ f16x8 bread(const char* __restrict__ img, int N, int sk, int n) {
  return *(const f16x8*)(img + ((sk*N + n) << 4));
}
// ---- swizzled [28][32] f32 ----
__device__ __forceinline__ float ctread(const float* __restrict__ cT, int u, int m) {
  return cT[u*32 + (((m >> 2) ^ (u & 7)) << 2) + (m & 3)];
}
__device__ __forceinline__ void ctwrite(float* __restrict__ cT, int u, int m, float v) {
  cT[u*32 + (((m >> 2) ^ (u & 7)) << 2) + (m & 3)] = v;
}

struct __align__(16) Smem {
  u16 a0h[4096], a0l[4096];   // A1 hi/lo
  u16 a1h[4096], g0a[4096];   // A2 hi ; g0 aliases A2-lo
  u16 a2h[4096], g1a[4096];   // A3 hi ; g1 aliases A3-lo
  u16 qmh[1024], qml[1024];   // Q matrix [32][32] hi/lo (col7 = 1.0 bias hook)
  u16 ub[1024], qdb[1024];    // U cotangent / Qd matrix (f16)
  float cT[896], vls[896];    // [28][32] swizzled
  float GQ[256], wv8[256], rh8[256], V[32];
};
static_assert(sizeof(Smem) <= 80*1024, "need 2 blocks/CU");

// ---- fwd layer: full hi/lo, out = softplus(A*W + b) -> hi/lo planes ----
template<int KSTEPS, bool K32A>
__device__ __forceinline__ void gemm_fwd(const u16* __restrict__ Ah, const u16* __restrict__ Al,
                                         u16* __restrict__ Oh, u16* __restrict__ Ol,
                                         const char* __restrict__ img, int hb,
                                         const float* __restrict__ bias, int w, int l) {
  const int lr = l & 15, lq = l >> 4;
  const int n = w*16 + lr;
  const float bv = bias ? bias[n] : 0.f;
  f32x4 aH[2], aX[2];
  #pragma unroll
  for (int mt = 0; mt < 2; ++mt) { aH[mt] = (f32x4){0,0,0,0}; aX[mt] = (f32x4){0,0,0,0}; }
  #pragma unroll
  for (int ks = 0; ks < KSTEPS; ++ks) {
    const int sk = ks*4 + lq;
    const f16x8 bh = bread(img, 128, sk, n);
    const f16x8 bl = bread(img + hb, 128, sk, n);
    #pragma unroll
    for (int mt = 0; mt < 2; ++mt) {
      const int row = mt*16 + lr;
      const f16x8 ah = K32A ? aread32(Ah, row, lq) : aread(Ah, row, sk);
      const f16x8 al = K32A ? aread32(Al, row, lq) : aread(Al, row, sk);
      aH[mt] = mm(ah, bh, aH[mt]);
      aX[mt] = mm(ah, bl, aX[mt]);
      aX[mt] = mm(al, bh, aX[mt]);
    }
  }
  #pragma unroll
  for (int mt = 0; mt < 2; ++mt)
    #pragma unroll
    for (int r = 0; r < 4; ++r) {
      const int m = mt*16 + lq*4 + r;
      const float z = aH[mt][r] + aX[mt][r]*(1.f/4096.f) + bv;
      const float o = sp_f(z);
      const _Float16 hh = (_Float16)o;
      awrite(Oh, m, n, h2b(hh));
      awrite(Ol, m, n, f16b((o - (float)hh) * 4096.f));
    }
}

// ---- grad/JVP layer: hi-only B, f16 A; out = sig_a(sigH) .* (A*W) ----
template<int KSTEPS, bool K32A>
__device__ __forceinline__ void gemm_grad(const u16* __restrict__ Ain, u16* __restrict__ Gout,
                                          const u16* __restrict__ sigH,
                                          const char* __restrict__ img, int w, int l) {
  const int lr = l & 15, lq = l >> 4;
  const int n = w*16 + lr;
  f32x4 acc[2];
  #pragma unroll
  for (int mt = 0; mt < 2; ++mt) acc[mt] = (f32x4){0,0,0,0};
  #pragma unroll
  for (int ks = 0; ks < KSTEPS; ++ks) {
    const int sk = ks*4 + lq;
    const f16x8 bh = bread(img, 128, sk, n);
    #pragma unroll
    for (int mt = 0; mt < 2; ++mt) {
      const int row = mt*16 + lr;
      const f16x8 ah = K32A ? aread32(Ain, row, lq) : aread(Ain, row, sk);
      acc[mt] = mm(ah, bh, acc[mt]);
    }
  }
  #pragma unroll
  for (int mt = 0; mt < 2; ++mt)
    #pragma unroll
    for (int r = 0; r < 4; ++r) {
      const int m = mt*16 + lq*4 + r;
      const float s = sig_a(sread(sigH, m, n));
      awrite(Gout, m, n, f16b(s * acc[mt][r]));
    }
}

// ---- l3: C[32][28] -> cT (swizzled f32); FULL = hi/lo A and B ----
template<bool FULL>
__device__ __forceinline__ void gemm_l3(const u16* __restrict__ Ah, const u16* __restrict__ Al,
                                        const char* __restrict__ img, int hb,
                                        const float* __restrict__ b3, float* __restrict__ cT,
                                        int w, int l) {
  if (w >= 4) return;
  const int lr = l & 15, lq = l >> 4;
  const int mt = w & 1, nt = w >> 1;
  const int n = nt*16 + lr;
  f32x4 aH = {0,0,0,0}, aX = {0,0,0,0};
  #pragma unroll
  for (int ks = 0; ks < 4; ++ks) {
    const int sk = ks*4 + lq;
    const int row = mt*16 + lr;
    const f16x8 bh = bread(img, 32, sk, n);
    const f16x8 ah = aread(Ah, row, sk);
    aH = mm(ah, bh, aH);
    if (FULL) {
      const f16x8 bl = bread(img + hb, 32, sk, n);
      const f16x8 al = aread(Al, row, sk);
      aX = mm(ah, bl, aX);
      aX = mm(al, bh, aX);
    }
  }
  if (n < 28) {
    const float bv = b3 ? b3[n] : 0.f;
    f32x4 v;
    #pragma unroll
    for (int r = 0; r < 4; ++r)
      v[r] = aH[r] + (FULL ? aX[r]*(1.f/4096.f) : 0.f) + bv;
    const int m0 = mt*16 + lq*4;
    *(f32x4*)&cT[n*32 + (((m0 >> 2) ^ (n & 7)) << 2)] = v;
  }
}

// ---- N=16 gemm: gq (-> GQ[32][8]) or potential head (-> V[32]); hi-only ----
template<bool HEAD>
__device__ __forceinline__ void gemm_n16(const u16* __restrict__ Ain,
                                         const char* __restrict__ img,
                                         float* __restrict__ GQ, float* __restrict__ V,
                                         int w, int l) {
  if (w >= 2) return;
  const int lr = l & 15, lq = l >> 4;
  f32x4 acc = {0,0,0,0};
  #pragma unroll
  for (int ks = 0; ks < 4; ++ks) {
    const int sk = ks*4 + lq;
    const f16x8 bh = bread(img, 16, sk, lr);
    const f16x8 ah = aread(Ain, w*16 + lr, sk);
    acc = mm(ah, bh, acc);
  }
  #pragma unroll
  for (int r = 0; r < 4; ++r) {
    const int m = w*16 + lq*4 + r;
    if (HEAD) { if (lr == 0) V[m] = acc[r]; }
    else      { if (lr < 8)  GQ[m*8 + lr] = acc[r]; }
  }
}

// ================= pack kernel: plane-separated hi/lo images =================
__global__ __launch_bounds__(256)
void pack_kernel(const float* __restrict__ mW0, const float* __restrict__ mb0,
                 const float* __restrict__ mW1, const float* __restrict__ mW2,
                 const float* __restrict__ mW3,
                 const float* __restrict__ pW0, const float* __restrict__ pb0,
                 const float* __restrict__ pW1, const float* __restrict__ pW2,
                 const float* __restrict__ pW3,
                 const float* __restrict__ fW0, const float* __restrict__ fb0,
                 const float* __restrict__ fW1, const float* __restrict__ fW2,
                 const float* __restrict__ fW3,
                 u16* __restrict__ ws)
{
  const int idx = blockIdx.x*256 + threadIdx.x;
  if (idx >= TOTF16) return;
  int img = 0;
  #pragma unroll
  for (int i = 1; i < 19; ++i) if (idx >= IB[i]/2) img = i;
  const int rem = idx - IB[img]/2;
  const int N = IN_[img];
  const int psz = (IB[img+1] - IB[img]) / 4;   // f16 per plane = K*N
  const int plane = rem >= psz;
  const int e = plane ? rem - psz : rem;
  const int slot = e / (N*8);
  const int r1 = e - slot*(N*8);
  const int n = r1 >> 3, ee = r1 & 7;
  const int k = slot*8 + ee;

  const float* W = nullptr; const float* B = nullptr;
  switch (img) {
    case 0:  W = mW0; B = mb0; break;
    case 1:  W = mW1; break;   case 2:  W = mW2; break;
    case 3:  W = mW3; break;   case 4:  W = mW3; break;
    case 5:  W = mW2; break;   case 6:  W = mW1; break;
    case 7:  W = mW0; break;
    case 8:  W = pW0; B = pb0; break;
    case 9:  W = pW1; break;   case 10: W = pW2; break;
    case 11: W = pW3; break;   case 12: W = pW2; break;
    case 13: W = pW1; break;   case 14: W = pW0; break;
    case 15: W = fW0; B = fb0; break;
    case 16: W = fW1; break;   case 17: W = fW2; break;
    default: W = fW3; break;
  }
  float v = 0.f;
  switch (ITY_[img]) {
    case 0: v = (k < 7) ? W[k*128 + n] : (k == 7 ? B[n] : 0.f); break;
    case 1: v = W[k*128 + n]; break;
    case 2: v = (n < 28) ? W[k*28 + n] : 0.f; break;
    case 3: v = (k < 28) ? W[n*28 + k] : 0.f; break;
    case 4: v = W[n*128 + k]; break;
    case 5: v = (n < 7) ? W[n*128 + k] : 0.f; break;
    default: v = (n == 0) ? W[k] : 0.f; break;
  }
  const _Float16 h = (_Float16)v;
  union { _Float16 f; u16 u; } c;
  c.f = plane ? (_Float16)((v - (float)h) * 4096.f) : h;
  ws[idx] = c.u;
}

// ================= main kernel =================
__global__ __launch_bounds__(NT, 4)
void delan_kernel(const float* __restrict__ qg, const float* __restrict__ qdg,
    const float* __restrict__ mb1, const float* __restrict__ mb2, const float* __restrict__ mb3,
    const float* __restrict__ pb1, const float* __restrict__ pb2, const float* __restrict__ pb3,
    const float* __restrict__ pW3,
    const float* __restrict__ fb1, const float* __restrict__ fb2, const float* __restrict__ fb3,
    const char* __restrict__ ws, float* __restrict__ out)
{
  __shared__ Smem S;
  const int t = threadIdx.x;
  const int l = t & 63;
  const int w = __builtin_amdgcn_readfirstlane(t >> 6);
  const int s0 = blockIdx.x * TM;

  u16* a1l = S.g0a;  u16* a2l = S.g1a;   // aliases

  // build packed Q matrix planes (col 7 = 1.0 -> bias row of W0 images)
  #pragma unroll
  for (int p = 0; p < 2; ++p) {
    const int ii = t + p*NT;
    const int m = ii >> 5, c = ii & 31;
    float v = 0.f;
    if (c < 7)       v = qg[(s0 + m)*7 + c];
    else if (c == 7) v = 1.f;
    const _Float16 hh = (_Float16)v;
    const int off = m*32 + ((((c >> 3) ^ (m & 3))) << 3) + (c & 7);
    S.qmh[off] = h2b(hh);
    S.qml[off] = f16b((v - (float)hh) * 4096.f);
  }
  __syncthreads();

  // ===================== MASS forward =====================
  gemm_fwd<1,true >(S.qmh, S.qml, S.a0h, S.a0l, ws + IB[0], (IB[1]-IB[0])/2, nullptr, w, l); __syncthreads();
  gemm_fwd<4,false>(S.a0h, S.a0l, S.a1h, a1l,   ws + IB[1], (IB[2]-IB[1])/2, mb1, w, l);     __syncthreads();
  gemm_fwd<4,false>(S.a1h, a1l,   S.a2h, a2l,   ws + IB[2], (IB[3]-IB[2])/2, mb2, w, l);     __syncthreads();
  gemm_l3<true>(S.a2h, a2l, ws + IB[3], (IB[4]-IB[3])/2, mb3, S.cT, w, l);                   __syncthreads();

  if (w == 0 && l < 32) {  // P1: L values, w = L^T qd, cotangent U
    const int ml = l;
    float qdv[7];
    #pragma unroll
    for (int i = 0; i < 7; ++i) qdv[i] = qdg[(s0 + ml)*7 + i];
    float vals[28], wvv[7] = {0,0,0,0,0,0,0};
    #pragma unroll
    for (int u = 0; u < 28; ++u) {
      const float cv = ctread(S.cT, u, ml);
      vals[u] = DG_[u] ? __expf(cv) : cv;
    }
    #pragma unroll
    for (int u = 0; u < 28; ++u) wvv[TJ_[u]] = fmaf(vals[u], qdv[TI_[u]], wvv[TJ_[u]]);
    #pragma unroll
    for (int u = 0; u < 28; ++u) ctwrite(S.vls, u, ml, vals[u]);
    #pragma unroll
    for (int i = 0; i < 7; ++i) S.wv8[ml*8 + i] = wvv[i];
    #pragma unroll
    for (int u = 0; u < 28; ++u) {
      const float uval = (DG_[u] ? vals[u] : 1.f) * qdv[TI_[u]] * wvv[TJ_[u]];
      S.ub[ml*32 + ((((u >> 3) ^ (ml & 3))) << 3) + (u & 7)] = f16b(uval);
    }
    #pragma unroll
    for (int u = 28; u < 32; ++u)
      S.ub[ml*32 + ((((u >> 3) ^ (ml & 3))) << 3) + (u & 7)] = 0;
  }
  __syncthreads();

  // ===================== MASS backward =====================
  gemm_grad<1,true >(S.ub,  S.g0a, S.a2h, ws + IB[4], w, l); __syncthreads();  // G3
  gemm_grad<4,false>(S.g0a, S.g1a, S.a1h, ws + IB[5], w, l); __syncthreads();  // G2
  gemm_grad<4,false>(S.g1a, S.g0a, S.a0h, ws + IB[6], w, l); __syncthreads();  // G1
  {
    gemm_n16<false>(S.g0a, ws + IB[7], S.GQ, S.V, w, l);                       // gq(mass)
    if (w == 2) {  // build Qd matrix while waves 0-1 do gq
      #pragma unroll
      for (int p = 0; p < 16; ++p) {
        const int ii = l + p*64;
        const int m = ii >> 5, c = ii & 31;
        S.qdb[m*32 + ((((c >> 3) ^ (m & 3))) << 3) + (c & 7)] =
            (c < 7) ? f16b(qdg[(s0 + m)*7 + c]) : (u16)0;
      }
    }
  }
  __syncthreads();

  // ===================== JVP =====================
  gemm_grad<1,true >(S.qdb, S.g0a, S.a0h, ws + IB[0], w, l); __syncthreads();  // d1
  gemm_grad<4,false>(S.g0a, S.g1a, S.a1h, ws + IB[1], w, l); __syncthreads();  // d2
  gemm_grad<4,false>(S.g1a, S.g0a, S.a2h, ws + IB[2], w, l); __syncthreads();  // d3
  gemm_l3<false>(S.g0a, nullptr, ws + IB[3], (IB[4]-IB[3])/2, nullptr, S.cT, w, l); __syncthreads(); // dc

  // ===================== POTENTIAL fwd (+ P2 on wave 0) =====================
  {
    gemm_fwd<1,true>(S.qmh, S.qml, S.a0h, S.a0l, ws + IB[8], (IB[9]-IB[8])/2, nullptr, w, l);
    if (w == 0 && l < 32) {  // P2: rhs = gq - coriolis
      const int ml = l;
      float qdv[7], wvv[7], gq7[7];
      #pragma unroll
      for (int i = 0; i < 7; ++i) {
        qdv[i] = qdg[(s0 + ml)*7 + i];
        wvv[i] = S.wv8[ml*8 + i];
        gq7[i] = S.GQ[ml*8 + i];
      }
      float lv[28];
      #pragma unroll
      for (int u = 0; u < 28; ++u) lv[u] = ctread(S.vls, u, ml);
      float cor[7] = {0,0,0,0,0,0,0}, t2[7] = {0,0,0,0,0,0,0};
      #pragma unroll
      for (int u = 0; u < 28; ++u) {
        const float dv = (DG_[u] ? lv[u] : 1.f) * ctread(S.cT, u, ml);
        cor[TI_[u]] = fmaf(dv, wvv[TJ_[u]], cor[TI_[u]]);
        t2[TJ_[u]]  = fmaf(dv, qdv[TI_[u]], t2[TJ_[u]]);
      }
      #pragma unroll
      for (int u = 0; u < 28; ++u) cor[TI_[u]] = fmaf(lv[u], t2[TJ_[u]], cor[TI_[u]]);
      #pragma unroll
      for (int i = 0; i < 7; ++i) S.rh8[ml*8 + i] = gq7[i] - cor[i];
    }
  }
  __syncthreads();
  gemm_fwd<4,false>(S.a0h, S.a0l, S.a1h, a1l, ws + IB[9],  (IB[10]-IB[9])/2,  pb1, w, l); __syncthreads();
  gemm_fwd<4,false>(S.a1h, a1l,   S.a2h, a2l, ws + IB[10], (IB[11]-IB[10])/2, pb2, w, l); __syncthreads();
  gemm_n16<true>(S.a2h, ws + IB[11], S.GQ, S.V, w, l); __syncthreads();        // head -> V
  {  // seed: g0 = sigmoid(V+pb3) * sigma(A3p) * pW3[n]
    const float pb3v = pb3[0];
    #pragma unroll
    for (int p = 0; p < 8; ++p) {
      const int idx = t + p*NT;
      const int m = idx >> 7, n = idx & 127;
      const float up = sigm_f(S.V[m] + pb3v);
      const float sg = sig_a(sread(S.a2h, m, n));
      awrite(S.g0a, m, n, f16b(up * sg * pW3[n]));
    }
  }
  __syncthreads();
  gemm_grad<4,false>(S.g0a, S.g1a, S.a1h, ws + IB[12], w, l); __syncthreads(); // G2p
  gemm_grad<4,false>(S.g1a, S.g0a, S.a0h, ws + IB[13], w, l); __syncthreads(); // G1p
  gemm_n16<false>(S.g0a, ws + IB[14], S.GQ, S.V, w, l); __syncthreads();       // gradV -> GQ

  // ===================== FRICTION =====================
  gemm_fwd<1,true >(S.qmh, S.qml, S.a0h, S.a0l, ws + IB[15], (IB[16]-IB[15])/2, nullptr, w, l); __syncthreads();
  gemm_fwd<4,false>(S.a0h, S.a0l, S.a1h, a1l,   ws + IB[16], (IB[17]-IB[16])/2, fb1, w, l);     __syncthreads();
  gemm_fwd<4,false>(S.a1h, a1l,   S.a2h, a2l,   ws + IB[17], (IB[18]-IB[17])/2, fb2, w, l);     __syncthreads();
  gemm_l3<true>(S.a2h, a2l, ws + IB[18], (IB[19]-IB[18])/2, fb3, S.cT, w, l);                   __syncthreads();

  // ===================== P3: friction, Cholesky solve, output =====================
  if (w == 0 && l < 32) {
    const int ml = l;
    float qdv[7];
    #pragma unroll
    for (int i = 0; i < 7; ++i) qdv[i] = qdg[(s0 + ml)*7 + i];
    float fv[28];
    #pragma unroll
    for (int u = 0; u < 28; ++u) {
      const float cv = ctread(S.cT, u, ml);
      fv[u] = DG_[u] ? __expf(cv) : cv;
    }
    float wf[7] = {0,0,0,0,0,0,0};
    #pragma unroll
    for (int u = 0; u < 28; ++u) wf[TJ_[u]] = fmaf(fv[u], qdv[TI_[u]], wf[TJ_[u]]);
    float fric[7];
    #pragma unroll
    for (int i = 0; i < 7; ++i) fric[i] = 1e-3f * qdv[i];
    #pragma unroll
    for (int u = 0; u < 28; ++u) fric[TI_[u]] = fmaf(fv[u], wf[TJ_[u]], fric[TI_[u]]);
    float r7[7];
    #pragma unroll
    for (int i = 0; i < 7; ++i) r7[i] = S.rh8[ml*8 + i] - S.GQ[ml*8 + i] - fric[i];

    float L[7][7];
    #pragma unroll
    for (int i = 0; i < 7; ++i)
      #pragma unroll
      for (int j = 0; j < 7; ++j) L[i][j] = 0.f;
    #pragma unroll
    for (int u = 0; u < 28; ++u) L[TI_[u]][TJ_[u]] = ctread(S.vls, u, ml);

    float M[7][7];
    #pragma unroll
    for (int i = 0; i < 7; ++i)
      #pragma unroll
      for (int j = 0; j < 7; ++j)
        if (j <= i) {
          float sum = (i == j) ? 1.1e-3f : 0.f;
          #pragma unroll
          for (int k = 0; k < 7; ++k) if (k <= j) sum = fmaf(L[i][k], L[j][k], sum);
          M[i][j] = sum;
        }
    float C[7][7];
    #pragma unroll
    for (int i = 0; i < 7; ++i)
      #pragma unroll
      for (int j = 0; j < 7; ++j)
        if (j <= i) {
          float sum = M[i][j];
          #pragma unroll
          for (int k = 0; k < 7; ++k) if (k < j) sum -= C[i][k] * C[j][k];
          if (j == i) C[i][j] = sqrtf(fmaxf(sum, 1e-12f));
          else        C[i][j] = sum / C[j][j];
        }
    float y[7];
    #pragma unroll
    for (int i = 0; i < 7; ++i) {
      float sum = r7[i];
      #pragma unroll
      for (int k = 0; k < 7; ++k) if (k < i) sum -= C[i][k] * y[k];
      y[i] = sum / C[i][i];
    }
    float x[7];
    #pragma unroll
    for (int i = 6; i >= 0; --i) {
      float sum = y[i];
      #pragma unroll
      for (int k = 0; k < 7; ++k) if (k > i) sum -= C[k][i] * x[k];
      x[i] = sum / C[i][i];
    }
    #pragma unroll
    for (int i = 0; i < 7; ++i) out[(s0 + ml)*7 + i] = x[i];
  }
}

extern "C" void kernel_launch(void* const* d_in, const int* in_sizes, int n_in,
                              void* d_out, int out_size, void* d_ws, size_t ws_size,
                              hipStream_t stream) {
  (void)in_sizes; (void)n_in; (void)out_size; (void)ws_size;
  const float* q   = (const float*)d_in[0];
  const float* qd  = (const float*)d_in[1];
  const float* mW0 = (const float*)d_in[2];  const float* mb0 = (const float*)d_in[3];
  const float* mW1 = (const float*)d_in[4];  const float* mb1 = (const float*)d_in[5];
  const float* mW2 = (const float*)d_in[6];  const float* mb2 = (const float*)d_in[7];
  const float* mW3 = (const float*)d_in[8];  const float* mb3 = (const float*)d_in[9];
  const float* pW0 = (const float*)d_in[10]; const float* pb0 = (const float*)d_in[11];
  const float* pW1 = (const float*)d_in[12]; const float* pb1 = (const float*)d_in[13];
  const float* pW2 = (const float*)d_in[14]; const float* pb2 = (const float*)d_in[15];
  const float* pW3 = (const float*)d_in[16]; const float* pb3 = (const float*)d_in[17];
  const float* fW0 = (const float*)d_in[18]; const float* fb0 = (const float*)d_in[19];
  const float* fW1 = (const float*)d_in[20]; const float* fb1 = (const float*)d_in[21];
  const float* fW2 = (const float*)d_in[22]; const float* fb2 = (const float*)d_in[23];
  const float* fW3 = (const float*)d_in[24]; const float* fb3 = (const float*)d_in[25];
  float* out = (float*)d_out;
  u16* ws = (u16*)d_ws;

  pack_kernel<<<dim3((TOTF16 + 255)/256), dim3(256), 0, stream>>>(
      mW0, mb0, mW1, mW2, mW3, pW0, pb0, pW1, pW2, pW3, fW0, fb0, fW1, fW2, fW3, ws);

  delan_kernel<<<dim3(NBLK), dim3(NT), 0, stream>>>(
      q, qd, mb1, mb2, mb3, pb1, pb2, pb3, pW3, fb1, fb2, fb3,
      (const char*)ws, out);
}

// Round 6
// 133.642 us; speedup vs baseline: 16.2671x; 1.1149x over previous
//
#include <hip/hip_runtime.h>

#define NT 512
#define TM 32
#define NBLK (65536/TM)

typedef unsigned int u32;
typedef unsigned short u16;
typedef __attribute__((ext_vector_type(4))) float f32x4;
typedef __attribute__((ext_vector_type(8))) _Float16 f16x8;

namespace {
constexpr int TI_[28] = {0,1,1,2,2,2,3,3,3,3,4,4,4,4,4,5,5,5,5,5,5,6,6,6,6,6,6,6};
constexpr int TJ_[28] = {0,0,1,0,1,2,0,1,2,3,0,1,2,3,4,0,1,2,3,4,5,0,1,2,3,4,5,6};
constexpr bool DG_[28] = {1,0,1,0,0,1,0,0,0,1,0,0,0,0,1,0,0,0,0,0,1,0,0,0,0,0,0,1};

// 19 weight images in ws, byte offsets. Per image: [hi plane][lo plane],
// each plane = [K/8 slots][N][8 f16].
constexpr int IB[20] = {0,16384,81920,147456,163840,180224,245760,311296,319488,
                        335872,401408,466944,475136,540672,606208,614400,630784,
                        696320,761856,778240};
constexpr int IN_[19]  = {128,128,128,32,128,128,128,16,128,128,128,16,128,128,16,128,128,128,32};
constexpr int ITY_[19] = {0,1,1,2,3,4,4,5,0,1,1,6,4,4,5,0,1,1,2};
constexpr int TOTF16 = 778240/2;
}

__device__ __forceinline__ float sp_f(float z) {
  float t = exp2f(-fabsf(z)*1.44269504f);
  return fmaxf(z, 0.f) + 0.69314718f*__log2f(1.f + t);
}
__device__ __forceinline__ float sigm_f(float z) {
  float t = exp2f(-z*1.44269504f);
  return __builtin_amdgcn_rcpf(1.f + t);
}
__device__ __forceinline__ float sig_a(float a) {  // sigmoid(z) from a=softplus(z)
  return 1.f - exp2f(-a*1.44269504f);
}

__device__ __forceinline__ u16 h2b(_Float16 h) { union{_Float16 f; u16 u;} c; c.f = h; return c.u; }
__device__ __forceinline__ u16 f16b(float x)   { return h2b((_Float16)x); }
__device__ __forceinline__ float b2f(u16 b)    { union{u16 u; _Float16 f;} c; c.u = b; return (float)c.f; }
__device__ __forceinline__ f16x8 fz8()         { return (f16x8)(_Float16)0.f; }

__device__ __forceinline__ f32x4 mm(f16x8 a, f16x8 b, f32x4 c) {
  return __builtin_amdgcn_mfma_f32_16x16x32_f16(a, b, c, 0, 0, 0);
}

// ---- f16 plane [32][128], 16 slots/row of 16B, slot XOR (row&7) ----
__device__ __forceinline__ f16x8 aread(const u16* P, int row, int s) {
  return *(const f16x8*)(P + row*128 + ((s ^ (row & 7)) << 3));
}
__device__ __forceinline__ void awrite(u16* P, int m, int n, u16 v) {
  P[m*128 + (((n >> 3) ^ (m & 7)) << 3) + (n & 7)] = v;
}
__device__ __forceinline__ float sread(const u16* P, int m, int n) {
  return b2f(P[m*128 + (((n >> 3) ^ (m & 7)) << 3) + (n & 7)]);
}
// ---- [32][8] q-matrix plane: only k-chunk 0 real, others zero ----
__device__ __forceinline__ f16x8 aq8(const u16* P, int row, int lq) {
  f16x8 v = *(const f16x8*)(P + row*8);
  return lq ? fz8() : v;
}
// ---- [32][32] ub plane: 4 slots, XOR (row&3) ----
__device__ __forceinline__ f16x8 ubread(const u16* P, int row, int lq) {
  return *(const f16x8*)(P + row*32 + ((lq ^ (row & 3)) << 3));
}
// ---- B fragment from global image plane ----
__device__ __forceinline__ f16x8 bread(const char* img, int N, int sk, int n) {
  return *(const f16x8*)(img + ((sk*N + n) << 4));
}
// ---- swizzled [28][32] f32 ----
__device__ __forceinline__ float ctread(const float* cT, int u, int m) {
  return cT[u*32 + (((m >> 2) ^ (u & 7)) << 2) + (m & 3)];
}
__device__ __forceinline__ void ctwrite(float* cT, int u, int m, float v) {
  cT[u*32 + (((m >> 2) ^ (u & 7)) << 2) + (m & 3)] = v;
}

struct __align__(16) Smem {
  u16 mh1[4096], mh2[4096], mh3[4096];   // mass act hi (sigma sources)
  u16 gA[4096], gB[4096];                // mass lo ping-pong / grad ping-pong / friction
  u16 pH1[4096], pH2[4096], pH3[4096];   // pot act hi / pot grads / jvp ping-pong
  u16 qmh[256], qml[256], qdb[256];      // [32][8]
  u16 ub[1024];                          // [32][32] cotangent
  float cTm[896];                        // c then vals (swizzled [28][32])
  u16 dcH[896], cfH[896];                // [28][32] plain f16
  float GQ1[384], GQp[384];              // [32][12]
  float V[32];
};
static_assert(sizeof(Smem) <= 81920, "need 2 blocks/CU");

// ---------- fwd hi/lo (mass): 2 tiles {wg, wg+4} ----------
template<int KS, bool QSRC>
__device__ __forceinline__ void fwd_hl(const u16* Ah, const u16* Al, u16* Oh, u16* Ol,
                                       const char* img, int hb, const float* bias,
                                       int wg, int l) {
  const int lr = l & 15, lq = l >> 4;
  f32x4 H[2][2], X[2][2];
  #pragma unroll
  for (int j=0;j<2;++j)
    #pragma unroll
    for (int mt=0;mt<2;++mt) { H[j][mt]=(f32x4){0,0,0,0}; X[j][mt]=(f32x4){0,0,0,0}; }
  #pragma unroll
  for (int ks=0; ks<KS; ++ks) {
    const int sk = ks*4 + lq;
    f16x8 ah[2], al[2];
    #pragma unroll
    for (int mt=0;mt<2;++mt) {
      const int row = mt*16+lr;
      ah[mt] = QSRC ? aq8(Ah,row,lq) : aread(Ah,row,sk);
      al[mt] = QSRC ? aq8(Al,row,lq) : aread(Al,row,sk);
    }
    #pragma unroll
    for (int j=0;j<2;++j) {
      const int n = (wg + j*4)*16 + lr;
      const f16x8 bh = bread(img,128,sk,n);
      const f16x8 bl = bread(img+hb,128,sk,n);
      #pragma unroll
      for (int mt=0;mt<2;++mt) {
        H[j][mt]=mm(ah[mt],bh,H[j][mt]);
        X[j][mt]=mm(ah[mt],bl,X[j][mt]);
        X[j][mt]=mm(al[mt],bh,X[j][mt]);
      }
    }
  }
  #pragma unroll
  for (int j=0;j<2;++j) {
    const int n = (wg + j*4)*16 + lr;
    const float bv = bias ? bias[n] : 0.f;
    #pragma unroll
    for (int mt=0;mt<2;++mt)
      #pragma unroll
      for (int r=0;r<4;++r) {
        const int m = mt*16 + lq*4 + r;
        const float o = sp_f(H[j][mt][r] + X[j][mt][r]*(1.f/4096.f) + bv);
        const _Float16 hh = (_Float16)o;
        awrite(Oh, m, n, h2b(hh));
        awrite(Ol, m, n, f16b((o - (float)hh)*4096.f));
      }
  }
}

// ---------- fwd hi-only (pot/fric): TC tiles {tile0 + j*tstep} ----------
template<int KS, bool QSRC, int TC>
__device__ __forceinline__ void fwd_h(const u16* Ah, u16* Oh, const char* img,
                                      const float* bias, int tile0, int tstep, int l) {
  const int lr = l & 15, lq = l >> 4;
  f32x4 H[TC][2];
  #pragma unroll
  for (int j=0;j<TC;++j)
    #pragma unroll
    for (int mt=0;mt<2;++mt) H[j][mt]=(f32x4){0,0,0,0};
  #pragma unroll
  for (int ks=0; ks<KS; ++ks) {
    const int sk = ks*4 + lq;
    f16x8 ah[2];
    #pragma unroll
    for (int mt=0;mt<2;++mt) {
      const int row = mt*16+lr;
      ah[mt] = QSRC ? aq8(Ah,row,lq) : aread(Ah,row,sk);
    }
    #pragma unroll
    for (int j=0;j<TC;++j) {
      const int n = (tile0 + j*tstep)*16 + lr;
      const f16x8 bh = bread(img,128,sk,n);
      #pragma unroll
      for (int mt=0;mt<2;++mt) H[j][mt]=mm(ah[mt],bh,H[j][mt]);
    }
  }
  #pragma unroll
  for (int j=0;j<TC;++j) {
    const int n = (tile0 + j*tstep)*16 + lr;
    const float bv = bias ? bias[n] : 0.f;
    #pragma unroll
    for (int mt=0;mt<2;++mt)
      #pragma unroll
      for (int r=0;r<4;++r) {
        const int m = mt*16 + lq*4 + r;
        awrite(Oh, m, n, f16b(sp_f(H[j][mt][r] + bv)));
      }
  }
}

// ---------- grad K=128: out = sig_a(Sig) .* (A*W); Out may == Sig (in-place) ----------
__device__ __forceinline__ void grad128(const u16* Ain, const u16* Sig, u16* Out,
                                        const char* img, int wg, int l) {
  const int lr = l & 15, lq = l >> 4;
  f32x4 acc[2][2];
  #pragma unroll
  for (int j=0;j<2;++j)
    #pragma unroll
    for (int mt=0;mt<2;++mt) acc[j][mt]=(f32x4){0,0,0,0};
  #pragma unroll
  for (int ks=0; ks<4; ++ks) {
    const int sk = ks*4 + lq;
    f16x8 ah[2];
    #pragma unroll
    for (int mt=0;mt<2;++mt) ah[mt] = aread(Ain, mt*16+lr, sk);
    #pragma unroll
    for (int j=0;j<2;++j) {
      const int n = (wg + j*4)*16 + lr;
      const f16x8 bh = bread(img,128,sk,n);
      #pragma unroll
      for (int mt=0;mt<2;++mt) acc[j][mt]=mm(ah[mt],bh,acc[j][mt]);
    }
  }
  #pragma unroll
  for (int j=0;j<2;++j) {
    const int n = (wg + j*4)*16 + lr;
    #pragma unroll
    for (int mt=0;mt<2;++mt)
      #pragma unroll
      for (int r=0;r<4;++r) {
        const int m = mt*16 + lq*4 + r;
        const float s = sig_a(sread(Sig, m, n));
        awrite(Out, m, n, f16b(s * acc[j][mt][r]));
      }
  }
}

// ---------- grad K=32: A from ub (ASRC=0) or q8 (ASRC=1) ----------
template<int ASRC>
__device__ __forceinline__ void grad32(const u16* Ain, const u16* Sig, u16* Out,
                                       const char* img, int wg, int l) {
  const int lr = l & 15, lq = l >> 4;
  f32x4 acc[2][2];
  #pragma unroll
  for (int j=0;j<2;++j)
    #pragma unroll
    for (int mt=0;mt<2;++mt) acc[j][mt]=(f32x4){0,0,0,0};
  {
    f16x8 ah[2];
    #pragma unroll
    for (int mt=0;mt<2;++mt) {
      const int row = mt*16+lr;
      ah[mt] = (ASRC==0) ? ubread(Ain,row,lq) : aq8(Ain,row,lq);
    }
    #pragma unroll
    for (int j=0;j<2;++j) {
      const int n = (wg + j*4)*16 + lr;
      const f16x8 bh = bread(img,128,lq,n);
      #pragma unroll
      for (int mt=0;mt<2;++mt) acc[j][mt]=mm(ah[mt],bh,acc[j][mt]);
    }
  }
  #pragma unroll
  for (int j=0;j<2;++j) {
    const int n = (wg + j*4)*16 + lr;
    #pragma unroll
    for (int mt=0;mt<2;++mt)
      #pragma unroll
      for (int r=0;r<4;++r) {
        const int m = mt*16 + lq*4 + r;
        const float s = sig_a(sread(Sig, m, n));
        awrite(Out, m, n, f16b(s * acc[j][mt][r]));
      }
  }
}

// ---------- G2p with on-the-fly A = up[m]*sigma(a3p); B image pre-scaled by W3p ----------
__device__ __forceinline__ void gradPotF(const u16* A3p, const float* V, float pb3v,
                                         const u16* Sig, u16* Out, const char* img,
                                         int wg, int l) {
  const int lr = l & 15, lq = l >> 4;
  float up[2];
  #pragma unroll
  for (int mt=0;mt<2;++mt) up[mt] = sigm_f(V[mt*16+lr] + pb3v);
  f32x4 acc[2][2];
  #pragma unroll
  for (int j=0;j<2;++j)
    #pragma unroll
    for (int mt=0;mt<2;++mt) acc[j][mt]=(f32x4){0,0,0,0};
  #pragma unroll
  for (int ks=0; ks<4; ++ks) {
    const int sk = ks*4 + lq;
    f16x8 af[2];
    #pragma unroll
    for (int mt=0;mt<2;++mt) {
      const f16x8 a3 = aread(A3p, mt*16+lr, sk);
      f16x8 t;
      #pragma unroll
      for (int e=0;e<8;++e) t[e] = (_Float16)(up[mt]*sig_a((float)a3[e]));
      af[mt] = t;
    }
    #pragma unroll
    for (int j=0;j<2;++j) {
      const int n = (wg + j*4)*16 + lr;
      const f16x8 bh = bread(img,128,sk,n);
      #pragma unroll
      for (int mt=0;mt<2;++mt) acc[j][mt]=mm(af[mt],bh,acc[j][mt]);
    }
  }
  #pragma unroll
  for (int j=0;j<2;++j) {
    const int n = (wg + j*4)*16 + lr;
    #pragma unroll
    for (int mt=0;mt<2;++mt)
      #pragma unroll
      for (int r=0;r<4;++r) {
        const int m = mt*16 + lq*4 + r;
        const float s = sig_a(sread(Sig, m, n));
        awrite(Out, m, n, f16b(s * acc[j][mt][r]));
      }
  }
}

// ---------- l3 (N=28): quadrant per wave; HL -> f32 cT, else f16 plain [28][32] ----------
template<bool HL>
__device__ __forceinline__ void l3(const u16* Ah, const u16* Al, const char* img, int hb,
                                   const float* b3, float* cT, u16* cH, int wg, int l) {
  const int lr = l & 15, lq = l >> 4;
  const int mt = wg & 1, ntl = wg >> 1;
  const int n = ntl*16 + lr;
  f32x4 H = {0,0,0,0}, X = {0,0,0,0};
  #pragma unroll
  for (int ks=0; ks<4; ++ks) {
    const int sk = ks*4 + lq;
    const int row = mt*16+lr;
    const f16x8 bh = bread(img,32,sk,n);
    const f16x8 ah = aread(Ah,row,sk);
    H = mm(ah,bh,H);
    if (HL) {
      const f16x8 bl = bread(img+hb,32,sk,n);
      const f16x8 al = aread(Al,row,sk);
      X = mm(ah,bl,X);
      X = mm(al,bh,X);
    }
  }
  if (n < 28) {
    const float bv = b3 ? b3[n] : 0.f;
    if (HL) {
      f32x4 v;
      #pragma unroll
      for (int r=0;r<4;++r) v[r] = H[r] + X[r]*(1.f/4096.f) + bv;
      const int m0 = mt*16 + lq*4;
      *(f32x4*)&cT[n*32 + (((m0 >> 2) ^ (n & 7)) << 2)] = v;
    } else {
      #pragma unroll
      for (int r=0;r<4;++r) cH[n*32 + mt*16 + lq*4 + r] = f16b(H[r] + bv);
    }
  }
}

// ---------- n16: head (-> V) or gq (-> GQ[32][12]) ; g = m-tile ----------
template<bool HEAD>
__device__ __forceinline__ void n16(const u16* Ain, const char* img,
                                    float* GQ, float* V, int g, int l) {
  const int lr = l & 15, lq = l >> 4;
  f32x4 acc = {0,0,0,0};
  #pragma unroll
  for (int ks=0; ks<4; ++ks) {
    const int sk = ks*4 + lq;
    const f16x8 bh = bread(img,16,sk,lr);
    const f16x8 ah = aread(Ain, g*16+lr, sk);
    acc = mm(ah,bh,acc);
  }
  #pragma unroll
  for (int r=0;r<4;++r) {
    const int m = g*16 + lq*4 + r;
    if (HEAD) { if (lr == 0) V[m] = acc[r]; }
    else      { if (lr < 8)  GQ[m*12 + lr] = acc[r]; }
  }
}

// ================= pack kernel: plane-separated hi/lo images =================
__global__ __launch_bounds__(256)
void pack_kernel(const float* __restrict__ mW0, const float* __restrict__ mb0,
                 const float* __restrict__ mW1, const float* __restrict__ mW2,
                 const float* __restrict__ mW3,
                 const float* __restrict__ pW0, const float* __restrict__ pb0,
                 const float* __restrict__ pW1, const float* __restrict__ pW2,
                 const float* __restrict__ pW3,
                 const float* __restrict__ fW0, const float* __restrict__ fb0,
                 const float* __restrict__ fW1, const float* __restrict__ fW2,
                 const float* __restrict__ fW3,
                 u16* __restrict__ ws)
{
  const int idx = blockIdx.x*256 + threadIdx.x;
  if (idx >= TOTF16) return;
  int img = 0;
  #pragma unroll
  for (int i = 1; i < 19; ++i) if (idx >= IB[i]/2) img = i;
  const int rem = idx - IB[img]/2;
  const int N = IN_[img];
  const int psz = (IB[img+1] - IB[img]) / 4;   // f16 per plane = K*N
  const int plane = rem >= psz;
  const int e = plane ? rem - psz : rem;
  const int slot = e / (N*8);
  const int r1 = e - slot*(N*8);
  const int n = r1 >> 3, ee = r1 & 7;
  const int k = slot*8 + ee;

  const float* W = nullptr; const float* B = nullptr;
  switch (img) {
    case 0:  W = mW0; B = mb0; break;
    case 1:  W = mW1; break;   case 2:  W = mW2; break;
    case 3:  W = mW3; break;   case 4:  W = mW3; break;
    case 5:  W = mW2; break;   case 6:  W = mW1; break;
    case 7:  W = mW0; break;
    case 8:  W = pW0; B = pb0; break;
    case 9:  W = pW1; break;   case 10: W = pW2; break;
    case 11: W = pW3; break;   case 12: W = pW2; break;
    case 13: W = pW1; break;   case 14: W = pW0; break;
    case 15: W = fW0; B = fb0; break;
    case 16: W = fW1; break;   case 17: W = fW2; break;
    default: W = fW3; break;
  }
  float v = 0.f;
  switch (ITY_[img]) {
    case 0: v = (k < 7) ? W[k*128 + n] : (k == 7 ? B[n] : 0.f); break;
    case 1: v = W[k*128 + n]; break;
    case 2: v = (n < 28) ? W[k*28 + n] : 0.f; break;
    case 3: v = (k < 28) ? W[n*28 + k] : 0.f; break;
    case 4: v = W[n*128 + k]; break;
    case 5: v = (n < 7) ? W[n*128 + k] : 0.f; break;
    default: v = (n == 0) ? W[k] : 0.f; break;
  }
  if (img == 12) v *= pW3[k];   // fold diag(W3p) into G2p's B image
  const _Float16 h = (_Float16)v;
  union { _Float16 f; u16 u; } c;
  c.f = plane ? (_Float16)((v - (float)h) * 4096.f) : h;
  ws[idx] = c.u;
}

// ================= main kernel =================
__global__ __launch_bounds__(NT, 4)
void delan_kernel(const float* __restrict__ qg, const float* __restrict__ qdg,
    const float* __restrict__ mb1, const float* __restrict__ mb2, const float* __restrict__ mb3,
    const float* __restrict__ pb1, const float* __restrict__ pb2, const float* __restrict__ pb3,
    const float* __restrict__ fb1, const float* __restrict__ fb2, const float* __restrict__ fb3,
    const char* __restrict__ ws, float* __restrict__ out)
{
  __shared__ Smem S;
  const int t = threadIdx.x;
  const int l = t & 63;
  const int w = __builtin_amdgcn_readfirstlane(t >> 6);
  const int wg = w & 3;
  const int s0 = blockIdx.x * TM;

  // ---- ph0: build q / qd matrices ----
  if (t < 256) {
    const int m = t >> 3, c = t & 7;
    const float v = (c < 7) ? qg[(s0 + m)*7 + c] : 1.f;   // col 7 = 1.0 bias hook
    const _Float16 hh = (_Float16)v;
    S.qmh[t] = h2b(hh);
    S.qml[t] = f16b((v - (float)hh)*4096.f);
  } else {
    const int idx = t - 256;
    const int m = idx >> 3, c = idx & 7;
    S.qdb[idx] = (c < 7) ? f16b(qdg[(s0 + m)*7 + c]) : (u16)0;
  }
  __syncthreads();

  // ph1: L0m | L0p
  if (w < 4) fwd_hl<1,true>(S.qmh,S.qml,S.mh1,S.gA, ws+IB[0],(IB[1]-IB[0])/2, nullptr, wg, l);
  else       fwd_h<1,true,2>(S.qmh, S.pH1, ws+IB[8], nullptr, wg, 4, l);
  __syncthreads();
  // ph2: L1m | L1p
  if (w < 4) fwd_hl<4,false>(S.mh1,S.gA,S.mh2,S.gB, ws+IB[1],(IB[2]-IB[1])/2, mb1, wg, l);
  else       fwd_h<4,false,2>(S.pH1, S.pH2, ws+IB[9], pb1, wg, 4, l);
  __syncthreads();
  // ph3: L2m | L2p
  if (w < 4) fwd_hl<4,false>(S.mh2,S.gB,S.mh3,S.gA, ws+IB[2],(IB[3]-IB[2])/2, mb2, wg, l);
  else       fwd_h<4,false,2>(S.pH2, S.pH3, ws+IB[10], pb2, wg, 4, l);
  __syncthreads();
  // ph4: L3m | head
  if (w < 4)      l3<true>(S.mh3, S.gA, ws+IB[3],(IB[4]-IB[3])/2, mb3, S.cTm, nullptr, wg, l);
  else if (w < 6) n16<true>(S.pH3, ws+IB[11], nullptr, S.V, w-4, l);
  __syncthreads();
  // ph5: P1 | G2p (in-place into pH2)
  if (w == 0 && l < 32) {
    const int ml = l;
    float qdv[7];
    #pragma unroll
    for (int i = 0; i < 7; ++i) qdv[i] = qdg[(s0 + ml)*7 + i];
    float vals[28], wvv[7] = {0,0,0,0,0,0,0};
    #pragma unroll
    for (int u = 0; u < 28; ++u) {
      const float cv = ctread(S.cTm, u, ml);
      vals[u] = DG_[u] ? __expf(cv) : cv;
    }
    #pragma unroll
    for (int u = 0; u < 28; ++u) wvv[TJ_[u]] = fmaf(vals[u], qdv[TI_[u]], wvv[TJ_[u]]);
    #pragma unroll
    for (int u = 0; u < 28; ++u) ctwrite(S.cTm, u, ml, vals[u]);   // c -> vals in place
    #pragma unroll
    for (int u = 0; u < 28; ++u) {
      const float uval = (DG_[u] ? vals[u] : 1.f) * qdv[TI_[u]] * wvv[TJ_[u]];
      S.ub[ml*32 + (((u >> 3) ^ (ml & 3)) << 3) + (u & 7)] = f16b(uval);
    }
    #pragma unroll
    for (int u = 28; u < 32; ++u)
      S.ub[ml*32 + (((u >> 3) ^ (ml & 3)) << 3) + (u & 7)] = 0;
  } else if (w >= 4) {
    gradPotF(S.pH3, S.V, pb3[0], S.pH2, S.pH2, ws+IB[12], wg, l);
  }
  __syncthreads();
  // ph6: G3 | G1p (in-place into pH1)
  if (w < 4) grad32<0>(S.ub, S.mh3, S.gB, ws+IB[4], wg, l);
  else       grad128(S.pH2, S.pH1, S.pH1, ws+IB[13], wg, l);
  __syncthreads();
  // ph7: G2 | gqp
  if (w < 4)      grad128(S.gB, S.mh2, S.gA, ws+IB[5], wg, l);
  else if (w < 6) n16<false>(S.pH1, ws+IB[14], S.GQp, nullptr, w-4, l);
  __syncthreads();
  // ph8: G1 | d1
  if (w < 4) grad128(S.gA, S.mh1, S.gB, ws+IB[6], wg, l);
  else       grad32<1>(S.qdb, S.mh1, S.pH2, ws+IB[0], wg, l);
  __syncthreads();
  // ph9: gq + L0f | d2
  if (w < 2)      n16<false>(S.gB, ws+IB[7], S.GQ1, nullptr, w, l);
  else if (w < 4) fwd_h<1,true,4>(S.qmh, S.gA, ws+IB[15], nullptr, w-2, 2, l);
  else            grad128(S.pH2, S.mh2, S.pH3, ws+IB[1], wg, l);
  __syncthreads();
  // ph10: L1f | d3
  if (w < 4) fwd_h<4,false,2>(S.gA, S.gB, ws+IB[16], fb1, wg, 4, l);
  else       grad128(S.pH3, S.mh3, S.pH2, ws+IB[2], wg, l);
  __syncthreads();
  // ph11: L2f | dc
  if (w < 4) fwd_h<4,false,2>(S.gB, S.gA, ws+IB[17], fb2, wg, 4, l);
  else       l3<false>(S.pH2, nullptr, ws+IB[3], 0, nullptr, nullptr, S.dcH, wg, l);
  __syncthreads();
  // ph12: L3f
  if (w < 4) l3<false>(S.gA, nullptr, ws+IB[18], 0, fb3, nullptr, S.cfH, wg, l);
  __syncthreads();

  // ph13: P2 + P3 (wave 0, lanes 0-31)
  if (w == 0 && l < 32) {
    const int ml = l;
    float qdv[7];
    #pragma unroll
    for (int i = 0; i < 7; ++i) qdv[i] = qdg[(s0 + ml)*7 + i];
    float lv[28];
    #pragma unroll
    for (int u = 0; u < 28; ++u) lv[u] = ctread(S.cTm, u, ml);
    float wvv[7] = {0,0,0,0,0,0,0};
    #pragma unroll
    for (int u = 0; u < 28; ++u) wvv[TJ_[u]] = fmaf(lv[u], qdv[TI_[u]], wvv[TJ_[u]]);
    float cor[7] = {0,0,0,0,0,0,0}, t2[7] = {0,0,0,0,0,0,0};
    #pragma unroll
    for (int u = 0; u < 28; ++u) {
      const float dv = (DG_[u] ? lv[u] : 1.f) * b2f(S.dcH[u*32 + ml]);
      cor[TI_[u]] = fmaf(dv, wvv[TJ_[u]], cor[TI_[u]]);
      t2[TJ_[u]]  = fmaf(dv, qdv[TI_[u]], t2[TJ_[u]]);
    }
    #pragma unroll
    for (int u = 0; u < 28; ++u) cor[TI_[u]] = fmaf(lv[u], t2[TJ_[u]], cor[TI_[u]]);
    float r7[7];
    #pragma unroll
    for (int i = 0; i < 7; ++i)
      r7[i] = S.GQ1[ml*12 + i] - cor[i] - S.GQp[ml*12 + i] - 1e-3f*qdv[i];
    // friction
    float fv[28];
    #pragma unroll
    for (int u = 0; u < 28; ++u) {
      const float cv = b2f(S.cfH[u*32 + ml]);
      fv[u] = DG_[u] ? __expf(cv) : cv;
    }
    float wf[7] = {0,0,0,0,0,0,0};
    #pragma unroll
    for (int u = 0; u < 28; ++u) wf[TJ_[u]] = fmaf(fv[u], qdv[TI_[u]], wf[TJ_[u]]);
    #pragma unroll
    for (int u = 0; u < 28; ++u) r7[TI_[u]] -= fv[u]*wf[TJ_[u]];

    float L[7][7];
    #pragma unroll
    for (int i = 0; i < 7; ++i)
      #pragma unroll
      for (int j = 0; j < 7; ++j) L[i][j] = 0.f;
    #pragma unroll
    for (int u = 0; u < 28; ++u) L[TI_[u]][TJ_[u]] = lv[u];

    float M[7][7];
    #pragma unroll
    for (int i = 0; i < 7; ++i)
      #pragma unroll
      for (int j = 0; j < 7; ++j)
        if (j <= i) {
          float sum = (i == j) ? 1.1e-3f : 0.f;
          #pragma unroll
          for (int k = 0; k < 7; ++k) if (k <= j) sum = fmaf(L[i][k], L[j][k], sum);
          M[i][j] = sum;
        }
    float C[7][7];
    #pragma unroll
    for (int i = 0; i < 7; ++i)
      #pragma unroll
      for (int j = 0; j < 7; ++j)
        if (j <= i) {
          float sum = M[i][j];
          #pragma unroll
          for (int k = 0; k < 7; ++k) if (k < j) sum -= C[i][k] * C[j][k];
          if (j == i) C[i][j] = sqrtf(fmaxf(sum, 1e-12f));
          else        C[i][j] = sum / C[j][j];
        }
    float y[7];
    #pragma unroll
    for (int i = 0; i < 7; ++i) {
      float sum = r7[i];
      #pragma unroll
      for (int k = 0; k < 7; ++k) if (k < i) sum -= C[i][k] * y[k];
      y[i] = sum / C[i][i];
    }
    float x[7];
    #pragma unroll
    for (int i = 6; i >= 0; --i) {
      float sum = y[i];
      #pragma unroll
      for (int k = 0; k < 7; ++k) if (k > i) sum -= C[k][i] * x[k];
      x[i] = sum / C[i][i];
    }
    #pragma unroll
    for (int i = 0; i < 7; ++i) out[(s0 + ml)*7 + i] = x[i];
  }
}

extern "C" void kernel_launch(void* const* d_in, const int* in_sizes, int n_in,
                              void* d_out, int out_size, void* d_ws, size_t ws_size,
                              hipStream_t stream) {
  (void)in_sizes; (void)n_in; (void)out_size; (void)ws_size;
  const float* q   = (const float*)d_in[0];
  const float* qd  = (const float*)d_in[1];
  const float* mW0 = (const float*)d_in[2];  const float* mb0 = (const float*)d_in[3];
  const float* mW1 = (const float*)d_in[4];  const float* mb1 = (const float*)d_in[5];
  const float* mW2 = (const float*)d_in[6];  const float* mb2 = (const float*)d_in[7];
  const float* mW3 = (const float*)d_in[8];  const float* mb3 = (const float*)d_in[9];
  const float* pW0 = (const float*)d_in[10]; const float* pb0 = (const float*)d_in[11];
  const float* pW1 = (const float*)d_in[12]; const float* pb1 = (const float*)d_in[13];
  const float* pW2 = (const float*)d_in[14]; const float* pb2 = (const float*)d_in[15];
  const float* pW3 = (const float*)d_in[16]; const float* pb3 = (const float*)d_in[17];
  const float* fW0 = (const float*)d_in[18]; const float* fb0 = (const float*)d_in[19];
  const float* fW1 = (const float*)d_in[20]; const float* fb1 = (const float*)d_in[21];
  const float* fW2 = (const float*)d_in[22]; const float* fb2 = (const float*)d_in[23];
  const float* fW3 = (const float*)d_in[24]; const float* fb3 = (const float*)d_in[25];
  float* out = (float*)d_out;
  u16* ws = (u16*)d_ws;

  pack_kernel<<<dim3((TOTF16 + 255)/256), dim3(256), 0, stream>>>(
      mW0, mb0, mW1, mW2, mW3, pW0, pb0, pW1, pW2, pW3, fW0, fb0, fW1, fW2, fW3, ws);

  delan_kernel<<<dim3(NBLK), dim3(NT), 0, stream>>>(
      q, qd, mb1, mb2, mb3, pb1, pb2, pb3, fb1, fb2, fb3,
      (const char*)ws, out);
}

// Round 7
// 117.160 us; speedup vs baseline: 18.5556x; 1.1407x over previous
//
#include <hip/hip_runtime.h>

#define NT 512
#define TM 32
#define NBLK (65536/TM)

typedef unsigned int u32;
typedef unsigned short u16;
typedef __attribute__((ext_vector_type(4))) float f32x4;
typedef __attribute__((ext_vector_type(8))) _Float16 f16x8;
typedef __attribute__((ext_vector_type(4))) _Float16 f16x4;

namespace {
constexpr int TI_[28] = {0,1,1,2,2,2,3,3,3,3,4,4,4,4,4,5,5,5,5,5,5,6,6,6,6,6,6,6};
constexpr int TJ_[28] = {0,0,1,0,1,2,0,1,2,3,0,1,2,3,4,0,1,2,3,4,5,0,1,2,3,4,5,6};
constexpr bool DG_[28] = {1,0,1,0,0,1,0,0,0,1,0,0,0,0,1,0,0,0,0,0,1,0,0,0,0,0,0,1};

// 19 weight images in ws, byte offsets. Per image: [hi plane][lo plane],
// each plane = [K/8 slots][N][8 f16].  (unchanged from round 6)
constexpr int IB[20] = {0,16384,81920,147456,163840,180224,245760,311296,319488,
                        335872,401408,466944,475136,540672,606208,614400,630784,
                        696320,761856,778240};
constexpr int IN_[19]  = {128,128,128,32,128,128,128,16,128,128,128,16,128,128,16,128,128,128,32};
constexpr int ITY_[19] = {0,1,1,2,3,4,4,5,0,1,1,6,4,4,5,0,1,1,2};
constexpr int TOTF16 = 778240/2;
}

__device__ __forceinline__ float sp_f(float z) {
  float t = exp2f(-fabsf(z)*1.44269504f);
  return fmaxf(z, 0.f) + 0.69314718f*__log2f(1.f + t);
}
__device__ __forceinline__ float sigm_f(float z) {
  float t = exp2f(-z*1.44269504f);
  return __builtin_amdgcn_rcpf(1.f + t);
}
__device__ __forceinline__ float sig_a(float a) {  // sigmoid(z) from a=softplus(z)
  return 1.f - exp2f(-a*1.44269504f);
}

__device__ __forceinline__ u16 h2b(_Float16 h) { union{_Float16 f; u16 u;} c; c.f = h; return c.u; }
__device__ __forceinline__ u16 f16b(float x)   { return h2b((_Float16)x); }
__device__ __forceinline__ float b2f(u16 b)    { union{u16 u; _Float16 f;} c; c.u = b; return (float)c.f; }
__device__ __forceinline__ f16x8 fz8()         { return (f16x8)(_Float16)0.f; }

__device__ __forceinline__ f32x4 mm(f16x8 a, f16x8 b, f32x4 c) {
  return __builtin_amdgcn_mfma_f32_16x16x32_f16(a, b, c, 0, 0, 0);
}

// ---- f16 plane [32 m][128 n], 16 slots/row of 16B, slot XOR (row&7) ----
__device__ __forceinline__ f16x8 aread(const u16* P, int row, int s) {
  return *(const f16x8*)(P + row*128 + ((s ^ (row & 7)) << 3));
}
// 4-aligned quad access (n2 % 4 == 0)
__device__ __forceinline__ int aidx4(int mrow, int n2) {
  return mrow*128 + (((n2 >> 3) ^ (mrow & 7)) << 3) + (n2 & 7);
}
__device__ __forceinline__ void awrite4(u16* P, int mrow, int n2, f16x4 v) {
  *(f16x4*)(P + aidx4(mrow, n2)) = v;
}
__device__ __forceinline__ f16x4 aread4(const u16* P, int mrow, int n2) {
  return *(const f16x4*)(P + aidx4(mrow, n2));
}
// ---- [32][8] q-matrix plane: only k-group 0 real, others zero ----
__device__ __forceinline__ f16x8 aq8(const u16* P, int row, int g) {
  f16x8 v = *(const f16x8*)(P + row*8);
  return g ? fz8() : v;
}
// ---- [32][32] ub plane: 4 slots, XOR (row&3) ----
__device__ __forceinline__ f16x8 ubread(const u16* P, int row, int g) {
  return *(const f16x8*)(P + row*32 + ((g ^ (row & 3)) << 3));
}
// ---- weight fragment (A operand) from global image plane ----
__device__ __forceinline__ f16x8 bread(const char* img, int N, int sk, int n) {
  return *(const f16x8*)(img + ((sk*N + n) << 4));
}

struct __align__(16) Smem {
  u16 mh1[4096], mh2[4096], mh3[4096];   // mass act hi (sigma sources)
  u16 gA[4096], gB[4096];                // mass lo ping-pong / grad ping-pong / friction
  u16 pH1[4096], pH2[4096], pH3[4096];   // pot act hi / pot grads / jvp ping-pong
  u16 qmh[256], qml[256], qdb[256];      // [32][8]
  u16 ub[1024];                          // [32][32] cotangent (swizzled)
  float cTm[896];                        // c then vals, plain [28][32]
  u16 dcH[896], cfH[896];                // [28][32] plain f16
  float GQ1[384], GQp[384];              // [32][12]
  float V[32];
};
static_assert(sizeof(Smem) <= 81920, "need 2 blocks/CU");

// ---------- fwd hi/lo (mass): D = W^T X^T, 2 n2-tiles {wg, wg+4} x 2 m-tiles ----------
template<int KS, bool QSRC>
__device__ __forceinline__ void fwd_hl(const u16* Bh, const u16* Bl, u16* Oh, u16* Ol,
                                       const char* img, int hb, const float* bias,
                                       int wg, int l) {
  const int m = l & 15, g = l >> 4;
  f32x4 H[2][2], X[2][2];
  #pragma unroll
  for (int j=0;j<2;++j)
    #pragma unroll
    for (int mt=0;mt<2;++mt) { H[j][mt]=(f32x4){0,0,0,0}; X[j][mt]=(f32x4){0,0,0,0}; }
  #pragma unroll
  for (int ks=0; ks<KS; ++ks) {
    const int sk = ks*4 + g;
    f16x8 bh[2], bl[2];
    #pragma unroll
    for (int mt=0;mt<2;++mt) {
      const int row = mt*16+m;
      bh[mt] = QSRC ? aq8(Bh,row,g) : aread(Bh,row,sk);
      bl[mt] = QSRC ? aq8(Bl,row,g) : aread(Bl,row,sk);
    }
    #pragma unroll
    for (int j=0;j<2;++j) {
      const int n2t = wg + j*4;
      const f16x8 wh = bread(img,128,sk, n2t*16+m);
      const f16x8 wl = bread(img+hb,128,sk, n2t*16+m);
      #pragma unroll
      for (int mt=0;mt<2;++mt) {
        H[j][mt]=mm(wh,bh[mt],H[j][mt]);
        X[j][mt]=mm(wl,bh[mt],X[j][mt]);
        X[j][mt]=mm(wh,bl[mt],X[j][mt]);
      }
    }
  }
  #pragma unroll
  for (int j=0;j<2;++j) {
    const int n2 = (wg + j*4)*16 + 4*g;
    f32x4 bv = bias ? *(const f32x4*)(bias + n2) : (f32x4){0,0,0,0};
    #pragma unroll
    for (int mt=0;mt<2;++mt) {
      const int mrow = mt*16 + m;
      f16x4 vh, vl;
      #pragma unroll
      for (int r=0;r<4;++r) {
        const float o = sp_f(H[j][mt][r] + X[j][mt][r]*(1.f/4096.f) + bv[r]);
        const _Float16 hh = (_Float16)o;
        vh[r] = hh;
        vl[r] = (_Float16)((o - (float)hh)*4096.f);
      }
      awrite4(Oh, mrow, n2, vh);
      awrite4(Ol, mrow, n2, vl);
    }
  }
}

// ---------- fwd hi-only (pot/fric): TC n2-tiles {tile0 + j*tstep} ----------
template<int KS, bool QSRC, int TC>
__device__ __forceinline__ void fwd_h(const u16* Bh, u16* Oh, const char* img,
                                      const float* bias, int tile0, int tstep, int l) {
  const int m = l & 15, g = l >> 4;
  f32x4 H[TC][2];
  #pragma unroll
  for (int j=0;j<TC;++j)
    #pragma unroll
    for (int mt=0;mt<2;++mt) H[j][mt]=(f32x4){0,0,0,0};
  #pragma unroll
  for (int ks=0; ks<KS; ++ks) {
    const int sk = ks*4 + g;
    f16x8 bh[2];
    #pragma unroll
    for (int mt=0;mt<2;++mt) {
      const int row = mt*16+m;
      bh[mt] = QSRC ? aq8(Bh,row,g) : aread(Bh,row,sk);
    }
    #pragma unroll
    for (int j=0;j<TC;++j) {
      const f16x8 wh = bread(img,128,sk,(tile0 + j*tstep)*16+m);
      #pragma unroll
      for (int mt=0;mt<2;++mt) H[j][mt]=mm(wh,bh[mt],H[j][mt]);
    }
  }
  #pragma unroll
  for (int j=0;j<TC;++j) {
    const int n2 = (tile0 + j*tstep)*16 + 4*g;
    f32x4 bv = bias ? *(const f32x4*)(bias + n2) : (f32x4){0,0,0,0};
    #pragma unroll
    for (int mt=0;mt<2;++mt) {
      const int mrow = mt*16 + m;
      f16x4 vh;
      #pragma unroll
      for (int r=0;r<4;++r) vh[r] = (_Float16)sp_f(H[j][mt][r] + bv[r]);
      awrite4(Oh, mrow, n2, vh);
    }
  }
}

// ---------- grad K=128: out = sig_a(Sig) .* (W^T X^T); Out may == Sig ----------
__device__ __forceinline__ void grad128(const u16* Bin, const u16* Sig, u16* Out,
                                        const char* img, int wg, int l) {
  const int m = l & 15, g = l >> 4;
  f32x4 acc[2][2];
  #pragma unroll
  for (int j=0;j<2;++j)
    #pragma unroll
    for (int mt=0;mt<2;++mt) acc[j][mt]=(f32x4){0,0,0,0};
  #pragma unroll
  for (int ks=0; ks<4; ++ks) {
    const int sk = ks*4 + g;
    f16x8 bh[2];
    #pragma unroll
    for (int mt=0;mt<2;++mt) bh[mt] = aread(Bin, mt*16+m, sk);
    #pragma unroll
    for (int j=0;j<2;++j) {
      const f16x8 wh = bread(img,128,sk,(wg + j*4)*16+m);
      #pragma unroll
      for (int mt=0;mt<2;++mt) acc[j][mt]=mm(wh,bh[mt],acc[j][mt]);
    }
  }
  #pragma unroll
  for (int j=0;j<2;++j) {
    const int n2 = (wg + j*4)*16 + 4*g;
    #pragma unroll
    for (int mt=0;mt<2;++mt) {
      const int mrow = mt*16 + m;
      const f16x4 sg = aread4(Sig, mrow, n2);
      f16x4 o;
      #pragma unroll
      for (int r=0;r<4;++r) o[r] = (_Float16)(sig_a((float)sg[r]) * acc[j][mt][r]);
      awrite4(Out, mrow, n2, o);
    }
  }
}

// ---------- grad K=32: B from ub (ASRC=0) or q8 (ASRC=1) ----------
template<int ASRC>
__device__ __forceinline__ void grad32(const u16* Bin, const u16* Sig, u16* Out,
                                       const char* img, int wg, int l) {
  const int m = l & 15, g = l >> 4;
  f32x4 acc[2][2];
  #pragma unroll
  for (int j=0;j<2;++j)
    #pragma unroll
    for (int mt=0;mt<2;++mt) acc[j][mt]=(f32x4){0,0,0,0};
  {
    f16x8 bh[2];
    #pragma unroll
    for (int mt=0;mt<2;++mt) {
      const int row = mt*16+m;
      bh[mt] = (ASRC==0) ? ubread(Bin,row,g) : aq8(Bin,row,g);
    }
    #pragma unroll
    for (int j=0;j<2;++j) {
      const f16x8 wh = bread(img,128,g,(wg + j*4)*16+m);
      #pragma unroll
      for (int mt=0;mt<2;++mt) acc[j][mt]=mm(wh,bh[mt],acc[j][mt]);
    }
  }
  #pragma unroll
  for (int j=0;j<2;++j) {
    const int n2 = (wg + j*4)*16 + 4*g;
    #pragma unroll
    for (int mt=0;mt<2;++mt) {
      const int mrow = mt*16 + m;
      const f16x4 sg = aread4(Sig, mrow, n2);
      f16x4 o;
      #pragma unroll
      for (int r=0;r<4;++r) o[r] = (_Float16)(sig_a((float)sg[r]) * acc[j][mt][r]);
      awrite4(Out, mrow, n2, o);
    }
  }
}

// ---------- G2p: B = up[m]*sigma(a3p) on the fly; B image pre-scaled by W3p ----------
__device__ __forceinline__ void gradPotF(const u16* A3p, const float* V, float pb3v,
                                         const u16* Sig, u16* Out, const char* img,
                                         int wg, int l) {
  const int m = l & 15, g = l >> 4;
  float up[2];
  #pragma unroll
  for (int mt=0;mt<2;++mt) up[mt] = sigm_f(V[mt*16+m] + pb3v);
  f32x4 acc[2][2];
  #pragma unroll
  for (int j=0;j<2;++j)
    #pragma unroll
    for (int mt=0;mt<2;++mt) acc[j][mt]=(f32x4){0,0,0,0};
  #pragma unroll
  for (int ks=0; ks<4; ++ks) {
    const int sk = ks*4 + g;
    f16x8 bh[2];
    #pragma unroll
    for (int mt=0;mt<2;++mt) {
      const f16x8 a3 = aread(A3p, mt*16+m, sk);
      f16x8 t;
      #pragma unroll
      for (int e=0;e<8;++e) t[e] = (_Float16)(up[mt]*sig_a((float)a3[e]));
      bh[mt] = t;
    }
    #pragma unroll
    for (int j=0;j<2;++j) {
      const f16x8 wh = bread(img,128,sk,(wg + j*4)*16+m);
      #pragma unroll
      for (int mt=0;mt<2;++mt) acc[j][mt]=mm(wh,bh[mt],acc[j][mt]);
    }
  }
  #pragma unroll
  for (int j=0;j<2;++j) {
    const int n2 = (wg + j*4)*16 + 4*g;
    #pragma unroll
    for (int mt=0;mt<2;++mt) {
      const int mrow = mt*16 + m;
      const f16x4 sg = aread4(Sig, mrow, n2);
      f16x4 o;
      #pragma unroll
      for (int r=0;r<4;++r) o[r] = (_Float16)(sig_a((float)sg[r]) * acc[j][mt][r]);
      awrite4(Out, mrow, n2, o);
    }
  }
}

// ---------- l3 (28 outputs): wave wg: n2t = wg&1, mt = wg>>1 ----------
template<bool HL>
__device__ __forceinline__ void l3(const u16* Bh, const u16* Bl, const char* img, int hb,
                                   const float* b3, float* cT, u16* cH, int wg, int l) {
  const int m = l & 15, g = l >> 4;
  const int n2t = wg & 1, mt = wg >> 1;
  const int mrow = mt*16 + m;
  f32x4 H = {0,0,0,0}, X = {0,0,0,0};
  #pragma unroll
  for (int ks=0; ks<4; ++ks) {
    const int sk = ks*4 + g;
    const f16x8 bh = aread(Bh, mrow, sk);
    const f16x8 wh = bread(img,32,sk, n2t*16+m);
    H = mm(wh, bh, H);
    if (HL) {
      const f16x8 wl = bread(img+hb,32,sk, n2t*16+m);
      const f16x8 bl = aread(Bl, mrow, sk);
      X = mm(wl, bh, X);
      X = mm(wh, bl, X);
    }
  }
  const int u0 = n2t*16 + 4*g;
  if (u0 < 28) {
    f32x4 bv = b3 ? *(const f32x4*)(b3 + u0) : (f32x4){0,0,0,0};
    #pragma unroll
    for (int r=0;r<4;++r) {
      const float v = H[r] + (HL ? X[r]*(1.f/4096.f) : 0.f) + bv[r];
      if (HL) cT[(u0+r)*32 + mrow] = v;
      else    cH[(u0+r)*32 + mrow] = f16b(v);
    }
  }
}

// ---------- n16: head (-> V) or gq (-> GQ[32][12]); mt = m-tile ----------
template<bool HEAD>
__device__ __forceinline__ void n16(const u16* Bin, const char* img,
                                    float* GQ, float* V, int mt, int l) {
  const int m = l & 15, g = l >> 4;
  const int mrow = mt*16 + m;
  f32x4 acc = {0,0,0,0};
  #pragma unroll
  for (int ks=0; ks<4; ++ks) {
    const int sk = ks*4 + g;
    const f16x8 bh = aread(Bin, mrow, sk);
    const f16x8 wh = bread(img,16,sk,m);
    acc = mm(wh, bh, acc);
  }
  if (HEAD) {
    if (g == 0) V[mrow] = acc[0];
  } else {
    if (g < 2) {
      #pragma unroll
      for (int r=0;r<4;++r) GQ[mrow*12 + 4*g + r] = acc[r];
    }
  }
}

// ================= pack kernel (unchanged) =================
__global__ __launch_bounds__(256)
void pack_kernel(const float* __restrict__ mW0, const float* __restrict__ mb0,
                 const float* __restrict__ mW1, const float* __restrict__ mW2,
                 const float* __restrict__ mW3,
                 const float* __restrict__ pW0, const float* __restrict__ pb0,
                 const float* __restrict__ pW1, const float* __restrict__ pW2,
                 const float* __restrict__ pW3,
                 const float* __restrict__ fW0, const float* __restrict__ fb0,
                 const float* __restrict__ fW1, const float* __restrict__ fW2,
                 const float* __restrict__ fW3,
                 u16* __restrict__ ws)
{
  const int idx = blockIdx.x*256 + threadIdx.x;
  if (idx >= TOTF16) return;
  int img = 0;
  #pragma unroll
  for (int i = 1; i < 19; ++i) if (idx >= IB[i]/2) img = i;
  const int rem = idx - IB[img]/2;
  const int N = IN_[img];
  const int psz = (IB[img+1] - IB[img]) / 4;   // f16 per plane = K*N
  const int plane = rem >= psz;
  const int e = plane ? rem - psz : rem;
  const int slot = e / (N*8);
  const int r1 = e - slot*(N*8);
  const int n = r1 >> 3, ee = r1 & 7;
  const int k = slot*8 + ee;

  const float* W = nullptr; const float* B = nullptr;
  switch (img) {
    case 0:  W = mW0; B = mb0; break;
    case 1:  W = mW1; break;   case 2:  W = mW2; break;
    case 3:  W = mW3; break;   case 4:  W = mW3; break;
    case 5:  W = mW2; break;   case 6:  W = mW1; break;
    case 7:  W = mW0; break;
    case 8:  W = pW0; B = pb0; break;
    case 9:  W = pW1; break;   case 10: W = pW2; break;
    case 11: W = pW3; break;   case 12: W = pW2; break;
    case 13: W = pW1; break;   case 14: W = pW0; break;
    case 15: W = fW0; B = fb0; break;
    case 16: W = fW1; break;   case 17: W = fW2; break;
    default: W = fW3; break;
  }
  float v = 0.f;
  switch (ITY_[img]) {
    case 0: v = (k < 7) ? W[k*128 + n] : (k == 7 ? B[n] : 0.f); break;
    case 1: v = W[k*128 + n]; break;
    case 2: v = (n < 28) ? W[k*28 + n] : 0.f; break;
    case 3: v = (k < 28) ? W[n*28 + k] : 0.f; break;
    case 4: v = W[n*128 + k]; break;
    case 5: v = (n < 7) ? W[n*128 + k] : 0.f; break;
    default: v = (n == 0) ? W[k] : 0.f; break;
  }
  if (img == 12) v *= pW3[k];   // fold diag(W3p) into G2p's image
  const _Float16 h = (_Float16)v;
  union { _Float16 f; u16 u; } c;
  c.f = plane ? (_Float16)((v - (float)h) * 4096.f) : h;
  ws[idx] = c.u;
}

// ================= main kernel =================
__global__ __launch_bounds__(NT, 4)
void delan_kernel(const float* __restrict__ qg, const float* __restrict__ qdg,
    const float* __restrict__ mb1, const float* __restrict__ mb2, const float* __restrict__ mb3,
    const float* __restrict__ pb1, const float* __restrict__ pb2, const float* __restrict__ pb3,
    const float* __restrict__ fb1, const float* __restrict__ fb2, const float* __restrict__ fb3,
    const char* __restrict__ ws, float* __restrict__ out)
{
  __shared__ Smem S;
  const int t = threadIdx.x;
  const int l = t & 63;
  const int w = __builtin_amdgcn_readfirstlane(t >> 6);
  const int wg = w & 3;
  const int s0 = blockIdx.x * TM;

  // ---- ph0: build q / qd matrices ----
  if (t < 256) {
    const int m = t >> 3, c = t & 7;
    const float v = (c < 7) ? qg[(s0 + m)*7 + c] : 1.f;   // col 7 = 1.0 bias hook
    const _Float16 hh = (_Float16)v;
    S.qmh[t] = h2b(hh);
    S.qml[t] = f16b((v - (float)hh)*4096.f);
  } else {
    const int idx = t - 256;
    const int m = idx >> 3, c = idx & 7;
    S.qdb[idx] = (c < 7) ? f16b(qdg[(s0 + m)*7 + c]) : (u16)0;
  }
  __syncthreads();

  // ph1: L0m | L0p
  if (w < 4) fwd_hl<1,true>(S.qmh,S.qml,S.mh1,S.gA, ws+IB[0],(IB[1]-IB[0])/2, nullptr, wg, l);
  else       fwd_h<1,true,2>(S.qmh, S.pH1, ws+IB[8], nullptr, wg, 4, l);
  __syncthreads();
  // ph2: L1m | L1p
  if (w < 4) fwd_hl<4,false>(S.mh1,S.gA,S.mh2,S.gB, ws+IB[1],(IB[2]-IB[1])/2, mb1, wg, l);
  else       fwd_h<4,false,2>(S.pH1, S.pH2, ws+IB[9], pb1, wg, 4, l);
  __syncthreads();
  // ph3: L2m | L2p
  if (w < 4) fwd_hl<4,false>(S.mh2,S.gB,S.mh3,S.gA, ws+IB[2],(IB[3]-IB[2])/2, mb2, wg, l);
  else       fwd_h<4,false,2>(S.pH2, S.pH3, ws+IB[10], pb2, wg, 4, l);
  __syncthreads();
  // ph4: L3m | head
  if (w < 4)      l3<true>(S.mh3, S.gA, ws+IB[3],(IB[4]-IB[3])/2, mb3, S.cTm, nullptr, wg, l);
  else if (w < 6) n16<true>(S.pH3, ws+IB[11], nullptr, S.V, w-4, l);
  __syncthreads();
  // ph5: P1 | G2p (in-place into pH2)
  if (w == 0 && l < 32) {
    const int ml = l;
    float qdv[7];
    #pragma unroll
    for (int i = 0; i < 7; ++i) qdv[i] = qdg[(s0 + ml)*7 + i];
    float vals[28], wvv[7] = {0,0,0,0,0,0,0};
    #pragma unroll
    for (int u = 0; u < 28; ++u) {
      const float cv = S.cTm[u*32 + ml];
      vals[u] = DG_[u] ? __expf(cv) : cv;
    }
    #pragma unroll
    for (int u = 0; u < 28; ++u) wvv[TJ_[u]] = fmaf(vals[u], qdv[TI_[u]], wvv[TJ_[u]]);
    #pragma unroll
    for (int u = 0; u < 28; ++u) S.cTm[u*32 + ml] = vals[u];   // c -> vals in place
    #pragma unroll
    for (int u = 0; u < 28; ++u) {
      const float uval = (DG_[u] ? vals[u] : 1.f) * qdv[TI_[u]] * wvv[TJ_[u]];
      S.ub[ml*32 + (((u >> 3) ^ (ml & 3)) << 3) + (u & 7)] = f16b(uval);
    }
    #pragma unroll
    for (int u = 28; u < 32; ++u)
      S.ub[ml*32 + (((u >> 3) ^ (ml & 3)) << 3) + (u & 7)] = 0;
  } else if (w >= 4) {
    gradPotF(S.pH3, S.V, pb3[0], S.pH2, S.pH2, ws+IB[12], wg, l);
  }
  __syncthreads();
  // ph6: G3 | G1p (in-place into pH1)
  if (w < 4) grad32<0>(S.ub, S.mh3, S.gB, ws+IB[4], wg, l);
  else       grad128(S.pH2, S.pH1, S.pH1, ws+IB[13], wg, l);
  __syncthreads();
  // ph7: G2 | gqp
  if (w < 4)      grad128(S.gB, S.mh2, S.gA, ws+IB[5], wg, l);
  else if (w < 6) n16<false>(S.pH1, ws+IB[14], S.GQp, nullptr, w-4, l);
  __syncthreads();
  // ph8: G1 | d1
  if (w < 4) grad128(S.gA, S.mh1, S.gB, ws+IB[6], wg, l);
  else       grad32<1>(S.qdb, S.mh1, S.pH2, ws+IB[0], wg, l);
  __syncthreads();
  // ph9: gq + L0f | d2
  if (w < 2)      n16<false>(S.gB, ws+IB[7], S.GQ1, nullptr, w, l);
  else if (w < 4) fwd_h<1,true,4>(S.qmh, S.gA, ws+IB[15], nullptr, w-2, 2, l);
  else            grad128(S.pH2, S.mh2, S.pH3, ws+IB[1], wg, l);
  __syncthreads();
  // ph10: L1f | d3
  if (w < 4) fwd_h<4,false,2>(S.gA, S.gB, ws+IB[16], fb1, wg, 4, l);
  else       grad128(S.pH3, S.mh3, S.pH2, ws+IB[2], wg, l);
  __syncthreads();
  // ph11: L2f | dc
  if (w < 4) fwd_h<4,false,2>(S.gB, S.gA, ws+IB[17], fb2, wg, 4, l);
  else       l3<false>(S.pH2, nullptr, ws+IB[3], 0, nullptr, nullptr, S.dcH, wg, l);
  __syncthreads();
  // ph12: L3f
  if (w < 4) l3<false>(S.gA, nullptr, ws+IB[18], 0, fb3, nullptr, S.cfH, wg, l);
  __syncthreads();

  // ph13: P2 + P3 (wave 0, lanes 0-31)
  if (w == 0 && l < 32) {
    const int ml = l;
    float qdv[7];
    #pragma unroll
    for (int i = 0; i < 7; ++i) qdv[i] = qdg[(s0 + ml)*7 + i];
    float lv[28];
    #pragma unroll
    for (int u = 0; u < 28; ++u) lv[u] = S.cTm[u*32 + ml];
    float wvv[7] = {0,0,0,0,0,0,0};
    #pragma unroll
    for (int u = 0; u < 28; ++u) wvv[TJ_[u]] = fmaf(lv[u], qdv[TI_[u]], wvv[TJ_[u]]);
    float cor[7] = {0,0,0,0,0,0,0}, t2[7] = {0,0,0,0,0,0,0};
    #pragma unroll
    for (int u = 0; u < 28; ++u) {
      const float dv = (DG_[u] ? lv[u] : 1.f) * b2f(S.dcH[u*32 + ml]);
      cor[TI_[u]] = fmaf(dv, wvv[TJ_[u]], cor[TI_[u]]);
      t2[TJ_[u]]  = fmaf(dv, qdv[TI_[u]], t2[TJ_[u]]);
    }
    #pragma unroll
    for (int u = 0; u < 28; ++u) cor[TI_[u]] = fmaf(lv[u], t2[TJ_[u]], cor[TI_[u]]);
    float r7[7];
    #pragma unroll
    for (int i = 0; i < 7; ++i)
      r7[i] = S.GQ1[ml*12 + i] - cor[i] - S.GQp[ml*12 + i] - 1e-3f*qdv[i];
    // friction
    float fv[28];
    #pragma unroll
    for (int u = 0; u < 28; ++u) {
      const float cv = b2f(S.cfH[u*32 + ml]);
      fv[u] = DG_[u] ? __expf(cv) : cv;
    }
    float wf[7] = {0,0,0,0,0,0,0};
    #pragma unroll
    for (int u = 0; u < 28; ++u) wf[TJ_[u]] = fmaf(fv[u], qdv[TI_[u]], wf[TJ_[u]]);
    #pragma unroll
    for (int u = 0; u < 28; ++u) r7[TI_[u]] -= fv[u]*wf[TJ_[u]];

    float L[7][7];
    #pragma unroll
    for (int i = 0; i < 7; ++i)
      #pragma unroll
      for (int j = 0; j < 7; ++j) L[i][j] = 0.f;
    #pragma unroll
    for (int u = 0; u < 28; ++u) L[TI_[u]][TJ_[u]] = lv[u];

    float M[7][7];
    #pragma unroll
    for (int i = 0; i < 7; ++i)
      #pragma unroll
      for (int j = 0; j < 7; ++j)
        if (j <= i) {
          float sum = (i == j) ? 1.1e-3f : 0.f;
          #pragma unroll
          for (int k = 0; k < 7; ++k) if (k <= j) sum = fmaf(L[i][k], L[j][k], sum);
          M[i][j] = sum;
        }
    float C[7][7];
    #pragma unroll
    for (int i = 0; i < 7; ++i)
      #pragma unroll
      for (int j = 0; j < 7; ++j)
        if (j <= i) {
          float sum = M[i][j];
          #pragma unroll
          for (int k = 0; k < 7; ++k) if (k < j) sum -= C[i][k] * C[j][k];
          if (j == i) C[i][j] = sqrtf(fmaxf(sum, 1e-12f));
          else        C[i][j] = sum / C[j][j];
        }
    float y[7];
    #pragma unroll
    for (int i = 0; i < 7; ++i) {
      float sum = r7[i];
      #pragma unroll
      for (int k = 0; k < 7; ++k) if (k < i) sum -= C[i][k] * y[k];
      y[i] = sum / C[i][i];
    }
    float x[7];
    #pragma unroll
    for (int i = 6; i >= 0; --i) {
      float sum = y[i];
      #pragma unroll
      for (int k = 0; k < 7; ++k) if (k > i) sum -= C[k][i] * x[k];
      x[i] = sum / C[i][i];
    }
    #pragma unroll
    for (int i = 0; i < 7; ++i) out[(s0 + ml)*7 + i] = x[i];
  }
}

extern "C" void kernel_launch(void* const* d_in, const int* in_sizes, int n_in,
                              void* d_out, int out_size, void* d_ws, size_t ws_size,
                              hipStream_t stream) {
  (void)in_sizes; (void)n_in; (void)out_size; (void)ws_size;
  const float* q   = (const float*)d_in[0];
  const float* qd  = (const float*)d_in[1];
  const float* mW0 = (const float*)d_in[2];  const float* mb0 = (const float*)d_in[3];
  const float* mW1 = (const float*)d_in[4];  const float* mb1 = (const float*)d_in[5];
  const float* mW2 = (const float*)d_in[6];  const float* mb2 = (const float*)d_in[7];
  const float* mW3 = (const float*)d_in[8];  const float* mb3 = (const float*)d_in[9];
  const float* pW0 = (const float*)d_in[10]; const float* pb0 = (const float*)d_in[11];
  const float* pW1 = (const float*)d_in[12]; const float* pb1 = (const float*)d_in[13];
  const float* pW2 = (const float*)d_in[14]; const float* pb2 = (const float*)d_in[15];
  const float* pW3 = (const float*)d_in[16]; const float* pb3 = (const float*)d_in[17];
  const float* fW0 = (const float*)d_in[18]; const float* fb0 = (const float*)d_in[19];
  const float* fW1 = (const float*)d_in[20]; const float* fb1 = (const float*)d_in[21];
  const float* fW2 = (const float*)d_in[22]; const float* fb2 = (const float*)d_in[23];
  const float* fW3 = (const float*)d_in[24]; const float* fb3 = (const float*)d_in[25];
  float* out = (float*)d_out;
  u16* ws = (u16*)d_ws;

  pack_kernel<<<dim3((TOTF16 + 255)/256), dim3(256), 0, stream>>>(
      mW0, mb0, mW1, mW2, mW3, pW0, pb0, pW1, pW2, pW3, fW0, fb0, fW1, fW2, fW3, ws);

  delan_kernel<<<dim3(NBLK), dim3(NT), 0, stream>>>(
      q, qd, mb1, mb2, mb3, pb1, pb2, pb3, fb1, fb2, fb3,
      (const char*)ws, out);
}